// Round 2
// baseline (2007.888 us; speedup 1.0000x reference)
//
#include <hip/hip_runtime.h>
#include <math.h>

#define SCALEQ 0.125f

// ---------------- shared GEMM core: C[128x128] per block, 256 thr, 8x8/thread ----------------
#define TK 16
#define LDT 132

__device__ __forceinline__ void gemm_core(const float* __restrict__ A, int lda,
                                          const float* __restrict__ B, int ldb,
                                          int K, int m0, int n0, bool btrans,
                                          float (&As)[TK][LDT], float (&Bs)[TK][LDT],
                                          float (&acc)[8][8]) {
  const int tid = threadIdx.x;
  const int tx = tid & 15, ty = tid >> 4;
  const int ar = tid >> 1;          // 0..127
  const int ah = (tid & 1) * 8;     // 0 or 8
  const int bk = tid >> 4;          // 0..15
  const int bc = (tid & 15) * 8;    // 0..120

  for (int kt = 0; kt < K; kt += TK) {
    float4 a0 = *(const float4*)(A + (size_t)(m0 + ar) * lda + kt + ah);
    float4 a1 = *(const float4*)(A + (size_t)(m0 + ar) * lda + kt + ah + 4);
    float4 b0, b1;
    if (btrans) {
      b0 = *(const float4*)(B + (size_t)(n0 + ar) * ldb + kt + ah);
      b1 = *(const float4*)(B + (size_t)(n0 + ar) * ldb + kt + ah + 4);
    } else {
      b0 = *(const float4*)(B + (size_t)(kt + bk) * ldb + n0 + bc);
      b1 = *(const float4*)(B + (size_t)(kt + bk) * ldb + n0 + bc + 4);
    }
    __syncthreads();
    As[ah + 0][ar] = a0.x; As[ah + 1][ar] = a0.y; As[ah + 2][ar] = a0.z; As[ah + 3][ar] = a0.w;
    As[ah + 4][ar] = a1.x; As[ah + 5][ar] = a1.y; As[ah + 6][ar] = a1.z; As[ah + 7][ar] = a1.w;
    if (btrans) {
      Bs[ah + 0][ar] = b0.x; Bs[ah + 1][ar] = b0.y; Bs[ah + 2][ar] = b0.z; Bs[ah + 3][ar] = b0.w;
      Bs[ah + 4][ar] = b1.x; Bs[ah + 5][ar] = b1.y; Bs[ah + 6][ar] = b1.z; Bs[ah + 7][ar] = b1.w;
    } else {
      *(float4*)&Bs[bk][bc] = b0;
      *(float4*)&Bs[bk][bc + 4] = b1;
    }
    __syncthreads();
#pragma unroll
    for (int kk = 0; kk < TK; ++kk) {
      float av[8], bv[8];
      float4 t;
      t = *(const float4*)&As[kk][ty * 4];      av[0] = t.x; av[1] = t.y; av[2] = t.z; av[3] = t.w;
      t = *(const float4*)&As[kk][64 + ty * 4]; av[4] = t.x; av[5] = t.y; av[6] = t.z; av[7] = t.w;
      t = *(const float4*)&Bs[kk][tx * 4];      bv[0] = t.x; bv[1] = t.y; bv[2] = t.z; bv[3] = t.w;
      t = *(const float4*)&Bs[kk][64 + tx * 4]; bv[4] = t.x; bv[5] = t.y; bv[6] = t.z; bv[7] = t.w;
#pragma unroll
      for (int i = 0; i < 8; ++i)
#pragma unroll
        for (int j = 0; j < 8; ++j) acc[i][j] = fmaf(av[i], bv[j], acc[i][j]);
    }
  }
}

#define EPI_ROW(i) (m0 + ((i) < 4 ? ty * 4 + (i) : 64 + ty * 4 + (i) - 4))
#define EPI_COL(j) (n0 + ((j) < 4 ? tx * 4 + (j) : 64 + tx * 4 + (j) - 4))

// ---------------- GEMM kernels ----------------
__global__ __launch_bounds__(256) void k_qkv(const float* __restrict__ x, const float* __restrict__ w,
                                             float* __restrict__ qb, float* __restrict__ kb, float* __restrict__ vb) {
  __shared__ float As[TK][LDT], Bs[TK][LDT];
  float acc[8][8] = {};
  const int m0 = blockIdx.y * 128, n0 = blockIdx.x * 128;
  gemm_core(x, 512, w, 512, 512, m0, n0, true, As, Bs, acc);
  const int tx = threadIdx.x & 15, ty = threadIdx.x >> 4;
#pragma unroll
  for (int i = 0; i < 8; ++i) {
    const int m = EPI_ROW(i);
    const int b = m >> 10, n = m & 1023;
#pragma unroll
    for (int j = 0; j < 8; ++j) {
      const int jj = EPI_COL(j);
      const int which = jj >> 9, rem = jj & 511, h = rem >> 6, d = rem & 63;
      float val = acc[i][j];
      float* dst = (which == 0) ? qb : (which == 1) ? kb : vb;
      if (which == 0) val *= SCALEQ;
      dst[(((size_t)b * 8 + h) * 1024 + n) * 64 + d] = val;
    }
  }
}

// Wh_l = x @ gat_W[l].T + gat_Wb[l]   -> [8192,1024]
__global__ __launch_bounds__(256) void k_wh(const float* __restrict__ x, const float* __restrict__ W,
                                            const float* __restrict__ Wb, float* __restrict__ Wh) {
  __shared__ float As[TK][LDT], Bs[TK][LDT];
  float acc[8][8] = {};
  const int m0 = blockIdx.y * 128, n0 = blockIdx.x * 128;
  gemm_core(x, 512, W, 512, 512, m0, n0, true, As, Bs, acc);
  const int tx = threadIdx.x & 15, ty = threadIdx.x >> 4;
#pragma unroll
  for (int i = 0; i < 8; ++i) {
    const int m = EPI_ROW(i);
#pragma unroll
    for (int j = 0; j < 8; ++j) {
      const int jj = EPI_COL(j);
      Wh[(size_t)m * 1024 + jj] = acc[i][j] + Wb[jj];
    }
  }
}

// hh_l = elu(att @ Wh_l)  -> [8192,1024]
__global__ __launch_bounds__(256) void k_hhat(const float* __restrict__ att, const float* __restrict__ Wh,
                                              float* __restrict__ hh) {
  __shared__ float As[TK][LDT], Bs[TK][LDT];
  float acc[8][8] = {};
  const int m0 = blockIdx.y * 128, n0 = blockIdx.x * 128;
  const int b = blockIdx.z;
  const float* A = att + ((size_t)b << 20);
  const float* B = Wh + ((size_t)b << 10) * 1024;
  gemm_core(A, 1024, B, 1024, 1024, m0, n0, false, As, Bs, acc);
  const int tx = threadIdx.x & 15, ty = threadIdx.x >> 4;
#pragma unroll
  for (int i = 0; i < 8; ++i) {
    const int m = EPI_ROW(i);
#pragma unroll
    for (int j = 0; j < 8; ++j) {
      const int jj = EPI_COL(j);
      float val = acc[i][j];
      val = val > 0.f ? val : (__expf(val) - 1.f);  // elu
      hh[((size_t)(b << 10) + m) * 1024 + jj] = val;
    }
  }
}

// Who (+)= hh_l @ out_W[:, l*1024:(l+1)*1024].T   (bias folded at l==0)
__global__ __launch_bounds__(256) void k_who_acc(const float* __restrict__ hh, const float* __restrict__ W,
                                                 const float* __restrict__ Wb, float* __restrict__ Who, int l) {
  __shared__ float As[TK][LDT], Bs[TK][LDT];
  float acc[8][8] = {};
  const int m0 = blockIdx.y * 128, n0 = blockIdx.x * 128;
  gemm_core(hh, 1024, W, 3072, 1024, m0, n0, true, As, Bs, acc);
  const int tx = threadIdx.x & 15, ty = threadIdx.x >> 4;
#pragma unroll
  for (int i = 0; i < 8; ++i) {
    const int m = EPI_ROW(i);
#pragma unroll
    for (int j = 0; j < 8; ++j) {
      const int jj = EPI_COL(j);
      const size_t idx = (size_t)m * 512 + jj;
      const float prev = (l == 0) ? Wb[jj] : Who[idx];
      Who[idx] = acc[i][j] + prev;
    }
  }
}

__global__ __launch_bounds__(256) void k_proj(const float* __restrict__ aout, const float* __restrict__ W,
                                              const float* __restrict__ Wb, float* __restrict__ out) {
  __shared__ float As[TK][LDT], Bs[TK][LDT];
  float acc[8][8] = {};
  const int m0 = blockIdx.y * 128, n0 = blockIdx.x * 128;
  gemm_core(aout, 512, W, 512, 512, m0, n0, true, As, Bs, acc);
  const int tx = threadIdx.x & 15, ty = threadIdx.x >> 4;
#pragma unroll
  for (int i = 0; i < 8; ++i) {
    const int m = EPI_ROW(i);
#pragma unroll
    for (int j = 0; j < 8; ++j) {
      const int jj = EPI_COL(j);
      out[(size_t)m * 512 + jj] = acc[i][j] + Wb[jj];
    }
  }
}

// ---------------- row reductions ----------------
// e1/e2 for one layer: rows of Wh_l [8192,1024] dotted with ai/aj[l]
__global__ __launch_bounds__(256) void k_e12(const float* __restrict__ Wh,
                                             const float* __restrict__ ai, const float* __restrict__ aib,
                                             const float* __restrict__ aj, const float* __restrict__ ajb,
                                             float* __restrict__ e1, float* __restrict__ e2, int l) {
  const int wid = threadIdx.x >> 6, lane = threadIdx.x & 63;
  const int row = blockIdx.x * 4 + wid;          // 0..8191
  const float* wr = Wh + (size_t)row * 1024;
  const float* av = ai + (l << 10);
  const float* bv = aj + (l << 10);
  float s1 = 0.f, s2 = 0.f;
#pragma unroll
  for (int c = 0; c < 4; ++c) {
    const int idx = c * 256 + lane * 4;
    float4 w4 = *(const float4*)&wr[idx];
    float4 a4 = *(const float4*)&av[idx];
    float4 b4 = *(const float4*)&bv[idx];
    s1 += w4.x * a4.x + w4.y * a4.y + w4.z * a4.z + w4.w * a4.w;
    s2 += w4.x * b4.x + w4.y * b4.y + w4.z * b4.z + w4.w * b4.w;
  }
#pragma unroll
  for (int off = 32; off > 0; off >>= 1) { s1 += __shfl_xor(s1, off); s2 += __shfl_xor(s2, off); }
  if (lane == 0) { e1[row] = s1 + aib[l]; e2[row] = s2 + ajb[l]; }
}

__global__ __launch_bounds__(256) void k_eo(const float* __restrict__ Who,
                                            const float* __restrict__ ai, const float* __restrict__ aib,
                                            const float* __restrict__ aj, const float* __restrict__ ajb,
                                            float* __restrict__ eo1, float* __restrict__ eo2) {
  const int wid = threadIdx.x >> 6, lane = threadIdx.x & 63;
  const int row = blockIdx.x * 4 + wid;          // 0..8191
  const float* wr = Who + (size_t)row * 512;
  float s1 = 0.f, s2 = 0.f;
#pragma unroll
  for (int c = 0; c < 2; ++c) {
    const int idx = c * 256 + lane * 4;
    float4 w4 = *(const float4*)&wr[idx];
    float4 a4 = *(const float4*)&ai[idx];
    float4 b4 = *(const float4*)&aj[idx];
    s1 += w4.x * a4.x + w4.y * a4.y + w4.z * a4.z + w4.w * a4.w;
    s2 += w4.x * b4.x + w4.y * b4.y + w4.z * b4.z + w4.w * b4.w;
  }
#pragma unroll
  for (int off = 32; off > 0; off >>= 1) { s1 += __shfl_xor(s1, off); s2 += __shfl_xor(s2, off); }
  if (lane == 0) { eo1[row] = s1 + aib[0]; eo2[row] = s2 + ajb[0]; }
}

// ---------------- block reduce helpers ----------------
__device__ __forceinline__ float block_max(float v, float* red) {
#pragma unroll
  for (int off = 32; off > 0; off >>= 1) v = fmaxf(v, __shfl_xor(v, off));
  __syncthreads();
  if ((threadIdx.x & 63) == 0) red[threadIdx.x >> 6] = v;
  __syncthreads();
  return fmaxf(fmaxf(red[0], red[1]), fmaxf(red[2], red[3]));
}
__device__ __forceinline__ float block_sum(float v, float* red) {
#pragma unroll
  for (int off = 32; off > 0; off >>= 1) v += __shfl_xor(v, off);
  __syncthreads();
  if ((threadIdx.x & 63) == 0) red[threadIdx.x >> 6] = v;
  __syncthreads();
  return red[0] + red[1] + red[2] + red[3];
}

// ---------------- GAT attention rows (one layer) ----------------
__global__ __launch_bounds__(256) void k_gat_att(const float* __restrict__ adj, const float* __restrict__ e1,
                                                 const float* __restrict__ e2, float* __restrict__ att) {
  __shared__ float red[4];
  const int row = blockIdx.x;                 // b*1024 + n
  const int b = row >> 10;
  const float* arow = adj + (size_t)row * 1024;
  const float e1v = e1[row];
  const float* e2r = e2 + (b << 10);
  float s[4];
  float mx = -1e30f;
#pragma unroll
  for (int c = 0; c < 4; ++c) {
    const int m = c * 256 + threadIdx.x;
    float e = e1v + e2r[m];
    e = e > 0.f ? e : 0.2f * e;
    s[c] = arow[m] * e;
    mx = fmaxf(mx, s[c]);
  }
  mx = block_max(mx, red);
  float sum = 0.f;
#pragma unroll
  for (int c = 0; c < 4; ++c) { float p = __expf(s[c] - mx); s[c] = p; sum += p; }
  sum = block_sum(sum, red);
  const float inv = 1.f / sum;
#pragma unroll
  for (int c = 0; c < 4; ++c) att[(size_t)row * 1024 + c * 256 + threadIdx.x] = s[c] * inv;
}

// ---------------- output-attention mask rows (double softmax, row-local) ----------------
__global__ __launch_bounds__(256) void k_mask(const float* __restrict__ adj, const float* __restrict__ eo1,
                                              const float* __restrict__ eo2, float* __restrict__ mask) {
  __shared__ float red[4];
  const int row = blockIdx.x;                 // b*1024 + n
  const int b = row >> 10;
  const float* arow = adj + (size_t)row * 1024;
  const float t1 = eo1[row];
  const float* eor = eo2 + (b << 10);
  float s[4];
  float mx = -1e30f;
#pragma unroll
  for (int c = 0; c < 4; ++c) {
    const int m = c * 256 + threadIdx.x;
    float e = t1 + eor[m];
    e = e > 0.f ? e : 0.2f * e;
    s[c] = arow[m] * e;
    mx = fmaxf(mx, s[c]);
  }
  mx = block_max(mx, red);
  float sum = 0.f;
#pragma unroll
  for (int c = 0; c < 4; ++c) { float p = __expf(s[c] - mx); s[c] = p; sum += p; }
  sum = block_sum(sum, red);
  const float inv = 1.f / sum;
  // gmask = elu(softmax) = softmax (positive); second softmax over the row
  float mx2 = -1e30f;
#pragma unroll
  for (int c = 0; c < 4; ++c) { s[c] *= inv; mx2 = fmaxf(mx2, s[c]); }
  mx2 = block_max(mx2, red);
  float sum2 = 0.f;
#pragma unroll
  for (int c = 0; c < 4; ++c) { float p = __expf(s[c] - mx2); s[c] = p; sum2 += p; }
  sum2 = block_sum(sum2, red);
  const float inv2 = 1.f / sum2;
#pragma unroll
  for (int c = 0; c < 4; ++c) mask[(size_t)row * 1024 + c * 256 + threadIdx.x] = s[c] * inv2;
}

// ---------------- flash-style masked attention ----------------
#define FP 68
__global__ __launch_bounds__(256) void k_flash(const float* __restrict__ qg, const float* __restrict__ kg,
                                               const float* __restrict__ vg, const float* __restrict__ mask,
                                               float* __restrict__ out) {
  __shared__ float qT[64][FP];
  __shared__ float kT[64][FP];   // reused as pT after scores are consumed
  __shared__ float vs[64][FP];
  const int nb = blockIdx.x, hh = blockIdx.y, bb = blockIdx.z;
  const int n0 = nb * 64;
  const size_t bh = ((size_t)bb * 8 + hh) * 1024 * 64;
  const int tid = threadIdx.x, tx = tid & 15, ty = tid >> 4;
  {
    const int r = tid >> 2, dg = (tid & 3) * 16;
    const float* src = qg + bh + (size_t)(n0 + r) * 64 + dg;
    float4 x0 = *(const float4*)(src);
    float4 x1 = *(const float4*)(src + 4);
    float4 x2 = *(const float4*)(src + 8);
    float4 x3 = *(const float4*)(src + 12);
    qT[dg + 0][r] = x0.x; qT[dg + 1][r] = x0.y; qT[dg + 2][r] = x0.z; qT[dg + 3][r] = x0.w;
    qT[dg + 4][r] = x1.x; qT[dg + 5][r] = x1.y; qT[dg + 6][r] = x1.z; qT[dg + 7][r] = x1.w;
    qT[dg + 8][r] = x2.x; qT[dg + 9][r] = x2.y; qT[dg + 10][r] = x2.z; qT[dg + 11][r] = x2.w;
    qT[dg + 12][r] = x3.x; qT[dg + 13][r] = x3.y; qT[dg + 14][r] = x3.z; qT[dg + 15][r] = x3.w;
  }
  float acc[4][4] = {};
  float mrun[4] = {-1e30f, -1e30f, -1e30f, -1e30f};
  float lrun[4] = {};
  for (int ms = 0; ms < 16; ++ms) {
    const int m0 = ms * 64;
    const int r = tid >> 2, dg = (tid & 3) * 16;
    const float* ksrc = kg + bh + (size_t)(m0 + r) * 64 + dg;
    const float* vsrc = vg + bh + (size_t)(m0 + r) * 64 + dg;
    float4 k0 = *(const float4*)(ksrc);
    float4 k1 = *(const float4*)(ksrc + 4);
    float4 k2 = *(const float4*)(ksrc + 8);
    float4 k3 = *(const float4*)(ksrc + 12);
    float4 v0 = *(const float4*)(vsrc);
    float4 v1 = *(const float4*)(vsrc + 4);
    float4 v2 = *(const float4*)(vsrc + 8);
    float4 v3 = *(const float4*)(vsrc + 12);
    __syncthreads();     // previous chunk's PV reads done
    kT[dg + 0][r] = k0.x; kT[dg + 1][r] = k0.y; kT[dg + 2][r] = k0.z; kT[dg + 3][r] = k0.w;
    kT[dg + 4][r] = k1.x; kT[dg + 5][r] = k1.y; kT[dg + 6][r] = k1.z; kT[dg + 7][r] = k1.w;
    kT[dg + 8][r] = k2.x; kT[dg + 9][r] = k2.y; kT[dg + 10][r] = k2.z; kT[dg + 11][r] = k2.w;
    kT[dg + 12][r] = k3.x; kT[dg + 13][r] = k3.y; kT[dg + 14][r] = k3.z; kT[dg + 15][r] = k3.w;
    *(float4*)&vs[r][dg] = v0;
    *(float4*)&vs[r][dg + 4] = v1;
    *(float4*)&vs[r][dg + 8] = v2;
    *(float4*)&vs[r][dg + 12] = v3;
    __syncthreads();
    float s[4][4] = {};
#pragma unroll
    for (int kk = 0; kk < 64; ++kk) {
      float4 a = *(const float4*)&qT[kk][ty * 4];
      float4 b = *(const float4*)&kT[kk][tx * 4];
      s[0][0] = fmaf(a.x, b.x, s[0][0]); s[0][1] = fmaf(a.x, b.y, s[0][1]); s[0][2] = fmaf(a.x, b.z, s[0][2]); s[0][3] = fmaf(a.x, b.w, s[0][3]);
      s[1][0] = fmaf(a.y, b.x, s[1][0]); s[1][1] = fmaf(a.y, b.y, s[1][1]); s[1][2] = fmaf(a.y, b.z, s[1][2]); s[1][3] = fmaf(a.y, b.w, s[1][3]);
      s[2][0] = fmaf(a.z, b.x, s[2][0]); s[2][1] = fmaf(a.z, b.y, s[2][1]); s[2][2] = fmaf(a.z, b.z, s[2][2]); s[2][3] = fmaf(a.z, b.w, s[2][3]);
      s[3][0] = fmaf(a.w, b.x, s[3][0]); s[3][1] = fmaf(a.w, b.y, s[3][1]); s[3][2] = fmaf(a.w, b.z, s[3][2]); s[3][3] = fmaf(a.w, b.w, s[3][3]);
    }
#pragma unroll
    for (int i = 0; i < 4; ++i) {
      float4 mv = *(const float4*)(mask + ((size_t)(bb << 10) + n0 + ty * 4 + i) * 1024 + m0 + tx * 4);
      s[i][0] *= mv.x; s[i][1] *= mv.y; s[i][2] *= mv.z; s[i][3] *= mv.w;
      float rm = fmaxf(fmaxf(s[i][0], s[i][1]), fmaxf(s[i][2], s[i][3]));
#pragma unroll
      for (int off = 1; off < 16; off <<= 1) rm = fmaxf(rm, __shfl_xor(rm, off));
      const float nm = fmaxf(mrun[i], rm);
      const float sc = __expf(mrun[i] - nm);
      mrun[i] = nm;
      float rs = 0.f;
#pragma unroll
      for (int j = 0; j < 4; ++j) { float p = __expf(s[i][j] - nm); s[i][j] = p; rs += p; }
#pragma unroll
      for (int off = 1; off < 16; off <<= 1) rs += __shfl_xor(rs, off);
      lrun[i] = lrun[i] * sc + rs;
#pragma unroll
      for (int j = 0; j < 4; ++j) acc[i][j] *= sc;
    }
    __syncthreads();     // everyone done reading kT as scores input
#pragma unroll
    for (int i = 0; i < 4; ++i)
#pragma unroll
      for (int j = 0; j < 4; ++j) kT[tx * 4 + j][ty * 4 + i] = s[i][j];   // pT[m][row]
    __syncthreads();
#pragma unroll
    for (int kk = 0; kk < 64; ++kk) {
      float4 pa = *(const float4*)&kT[kk][ty * 4];
      float4 vb = *(const float4*)&vs[kk][tx * 4];
      acc[0][0] = fmaf(pa.x, vb.x, acc[0][0]); acc[0][1] = fmaf(pa.x, vb.y, acc[0][1]); acc[0][2] = fmaf(pa.x, vb.z, acc[0][2]); acc[0][3] = fmaf(pa.x, vb.w, acc[0][3]);
      acc[1][0] = fmaf(pa.y, vb.x, acc[1][0]); acc[1][1] = fmaf(pa.y, vb.y, acc[1][1]); acc[1][2] = fmaf(pa.y, vb.z, acc[1][2]); acc[1][3] = fmaf(pa.y, vb.w, acc[1][3]);
      acc[2][0] = fmaf(pa.z, vb.x, acc[2][0]); acc[2][1] = fmaf(pa.z, vb.y, acc[2][1]); acc[2][2] = fmaf(pa.z, vb.z, acc[2][2]); acc[2][3] = fmaf(pa.z, vb.w, acc[2][3]);
      acc[3][0] = fmaf(pa.w, vb.x, acc[3][0]); acc[3][1] = fmaf(pa.w, vb.y, acc[3][1]); acc[3][2] = fmaf(pa.w, vb.z, acc[3][2]); acc[3][3] = fmaf(pa.w, vb.w, acc[3][3]);
    }
  }
#pragma unroll
  for (int i = 0; i < 4; ++i) {
    const int row = n0 + ty * 4 + i;
    const float inv = 1.f / lrun[i];
#pragma unroll
    for (int j = 0; j < 4; ++j)
      out[((size_t)(bb << 10) + row) * 512 + hh * 64 + tx * 4 + j] = acc[i][j] * inv;
  }
}

// ---------------- launcher ----------------
extern "C" void kernel_launch(void* const* d_in, const int* in_sizes, int n_in,
                              void* d_out, int out_size, void* d_ws, size_t ws_size,
                              hipStream_t stream) {
  (void)in_sizes; (void)n_in; (void)out_size; (void)ws_size;
  const float* x        = (const float*)d_in[0];
  const float* adj      = (const float*)d_in[1];
  const float* qkv_w    = (const float*)d_in[2];
  const float* proj_w   = (const float*)d_in[3];
  const float* proj_b   = (const float*)d_in[4];
  const float* gat_W    = (const float*)d_in[5];
  const float* gat_Wb   = (const float*)d_in[6];
  const float* gat_ai   = (const float*)d_in[7];
  const float* gat_ai_b = (const float*)d_in[8];
  const float* gat_aj   = (const float*)d_in[9];
  const float* gat_aj_b = (const float*)d_in[10];
  const float* out_W    = (const float*)d_in[11];
  const float* out_Wb   = (const float*)d_in[12];
  const float* out_ai   = (const float*)d_in[13];
  const float* out_ai_b = (const float*)d_in[14];
  const float* out_aj   = (const float*)d_in[15];
  const float* out_aj_b = (const float*)d_in[16];

  // Workspace layout (floats). Peak = 41,975,808 floats = 160.1 MiB.
  float* ws   = (float*)d_ws;
  float* qb   = ws;                       // [8,8,1024,64]  (16 MB)
  float* kb   = qb + 4194304;             // [8,8,1024,64]  (16 MB)
  float* vb   = kb + 4194304;             // [8,8,1024,64]  (16 MB)
  float* WhL  = vb + 4194304;             // [8192,1024] per-layer (32 MB); later reused as aout
  float* att  = WhL + 8388608;            // [8,1024,1024] per-layer (32 MB); later reused as mask
  float* hhL  = att + 8388608;            // [8192,1024] per-layer (32 MB)
  float* Who  = hhL + 8388608;            // [8192,512]  (16 MB)
  float* e1   = Who + 4194304;            // [8192]
  float* e2   = e1 + 8192;                // [8192]
  float* eo1  = e2 + 8192;                // [8192]
  float* eo2  = eo1 + 8192;               // [8192]
  float* mask = att;                      // alias (att dead after GAT loop)
  float* aout = WhL;                      // alias (WhL dead after GAT loop)

  const dim3 blk(256);
  k_qkv<<<dim3(12, 64), blk, 0, stream>>>(x, qkv_w, qb, kb, vb);
  for (int l = 0; l < 3; ++l) {
    k_wh<<<dim3(8, 64), blk, 0, stream>>>(x, gat_W + (size_t)l * 1024 * 512, gat_Wb + l * 1024, WhL);
    k_e12<<<2048, blk, 0, stream>>>(WhL, gat_ai, gat_ai_b, gat_aj, gat_aj_b, e1, e2, l);
    k_gat_att<<<8192, blk, 0, stream>>>(adj, e1, e2, att);
    k_hhat<<<dim3(8, 8, 8), blk, 0, stream>>>(att, WhL, hhL);
    k_who_acc<<<dim3(4, 64), blk, 0, stream>>>(hhL, out_W + l * 1024, out_Wb, Who, l);
  }
  k_eo<<<2048, blk, 0, stream>>>(Who, out_ai, out_ai_b, out_aj, out_aj_b, eo1, eo2);
  k_mask<<<8192, blk, 0, stream>>>(adj, eo1, eo2, mask);
  k_flash<<<dim3(16, 8, 8), blk, 0, stream>>>(qb, kb, vb, mask, aout);
  k_proj<<<dim3(4, 64), blk, 0, stream>>>(aout, proj_w, proj_b, (float*)d_out);
}

// Round 3
// 790.126 us; speedup vs baseline: 2.5412x; 2.5412x over previous
//
#include <hip/hip_runtime.h>
#include <math.h>
#include <stdint.h>

#define SCALEQ 0.125f

typedef __bf16 bf16_t;
typedef __bf16 bf16x8 __attribute__((ext_vector_type(8)));
typedef float f32x4 __attribute__((ext_vector_type(4)));

// global -> LDS async copy, 16B per lane. LDS dest must be wave-uniform base;
// HW writes lane i at base + i*16 bytes. (CK-style addrspace casts via uintptr.)
#define GLOAD_LDS16(gsrc, ldst)                                                   \
  __builtin_amdgcn_global_load_lds(                                               \
      (const __attribute__((address_space(1))) void*)(uintptr_t)(const void*)(gsrc), \
      (__attribute__((address_space(3))) void*)(uintptr_t)(void*)(ldst), 16, 0, 0)

// ---------------- bf16 MFMA GEMM core ----------------
// C[128x128] per block, 256 thr = 4 waves, BK=64.
// A [M,K] row-major bf16 (lda=K-ish), B given as B^T: [N,K] row-major bf16.
// Wave w -> 64x64 quadrant (wr=w>>1, wc=w&1), 4x4 fragments of 16x16.
// A-frag: lane holds A[fr][fq*8..+7]; B-frag: lane holds B^T[fr][fq*8..+7];
// C: col=lane&15, row=(lane>>4)*4+reg  (m89-verified layout).
__device__ __forceinline__ void mm_bf16(const bf16_t* __restrict__ A, int lda,
                                        const bf16_t* __restrict__ B, int ldb,
                                        int K, int m0, int n0,
                                        bf16_t* As, bf16_t* Bs, f32x4 (&acc)[4][4]) {
  const int tid = threadIdx.x, lane = tid & 63, w = tid >> 6;
  const int wr = (w >> 1) * 64, wc = (w & 1) * 64;
  const int fr = lane & 15, fq = lane >> 4;
  for (int kt = 0; kt < K; kt += 64) {
    __syncthreads();   // previous tile's reads complete
#pragma unroll
    for (int t = 0; t < 4; ++t) {
      const int rl = t * 32 + w * 8 + (lane >> 3);     // row within 128-tile
      const int c8 = (lane & 7) * 8;                   // k-offset (8 bf16 = 16B)
      GLOAD_LDS16(A + (size_t)(m0 + rl) * lda + kt + c8, As + (t * 32 + w * 8) * 64);
      GLOAD_LDS16(B + (size_t)(n0 + rl) * ldb + kt + c8, Bs + (t * 32 + w * 8) * 64);
    }
    __syncthreads();   // staging complete (sync drains vmcnt)
#pragma unroll
    for (int ks = 0; ks < 2; ++ks) {
      bf16x8 af[4], bfv[4];
#pragma unroll
      for (int mf = 0; mf < 4; ++mf)
        af[mf] = *(const bf16x8*)(As + (wr + mf * 16 + fr) * 64 + ks * 32 + fq * 8);
#pragma unroll
      for (int nf = 0; nf < 4; ++nf)
        bfv[nf] = *(const bf16x8*)(Bs + (wc + nf * 16 + fr) * 64 + ks * 32 + fq * 8);
#pragma unroll
      for (int mf = 0; mf < 4; ++mf)
#pragma unroll
        for (int nf = 0; nf < 4; ++nf)
          acc[mf][nf] = __builtin_amdgcn_mfma_f32_16x16x32_bf16(af[mf], bfv[nf], acc[mf][nf], 0, 0, 0);
    }
  }
}

#define MM_PROLOGUE()                                  \
  __shared__ __align__(16) bf16_t As[128 * 64];        \
  __shared__ __align__(16) bf16_t Bs[128 * 64];        \
  f32x4 acc[4][4];                                     \
  _Pragma("unroll") for (int i_ = 0; i_ < 4; ++i_)     \
  _Pragma("unroll") for (int j_ = 0; j_ < 4; ++j_) acc[i_][j_] = (f32x4)0.0f;

#define MM_EPI_SETUP(M0, N0)                                   \
  const int lane = threadIdx.x & 63, w = threadIdx.x >> 6;     \
  const int fr = lane & 15, fq = lane >> 4;                    \
  const int mb = (M0) + (w >> 1) * 64, nb = (N0) + (w & 1) * 64;

// ---------------- GEMM kernels ----------------
__global__ __launch_bounds__(256) void k_qkv(const bf16_t* __restrict__ xb, const bf16_t* __restrict__ wb,
                                             float* __restrict__ qb, float* __restrict__ kb, float* __restrict__ vb) {
  MM_PROLOGUE();
  const int m0 = blockIdx.y * 128, n0 = blockIdx.x * 128;
  mm_bf16(xb, 512, wb, 512, 512, m0, n0, As, Bs, acc);
  MM_EPI_SETUP(m0, n0);
#pragma unroll
  for (int mf = 0; mf < 4; ++mf)
#pragma unroll
    for (int nf = 0; nf < 4; ++nf) {
      const int n = nb + nf * 16 + fr;
      const int which = n >> 9, rem = n & 511, hd = rem >> 6, d = rem & 63;
      float* dst = which == 0 ? qb : which == 1 ? kb : vb;
      const float sc = which == 0 ? SCALEQ : 1.f;
#pragma unroll
      for (int r = 0; r < 4; ++r) {
        const int m = mb + mf * 16 + fq * 4 + r;
        const int b = m >> 10, tok = m & 1023;
        dst[(((size_t)b * 8 + hd) * 1024 + tok) * 64 + d] = acc[mf][nf][r] * sc;
      }
    }
}

// Wh_l^T (per batch): WhT[b][h][m] = x@W_l.T + b, written transposed+bf16
__global__ __launch_bounds__(256) void k_wh(const bf16_t* __restrict__ xb, const bf16_t* __restrict__ Wl,
                                            const float* __restrict__ Wb, bf16_t* __restrict__ WhT) {
  MM_PROLOGUE();
  const int m0 = blockIdx.y * 128, n0 = blockIdx.x * 128;
  mm_bf16(xb, 512, Wl, 512, 512, m0, n0, As, Bs, acc);
  MM_EPI_SETUP(m0, n0);
#pragma unroll
  for (int mf = 0; mf < 4; ++mf)
#pragma unroll
    for (int nf = 0; nf < 4; ++nf) {
      const int h = nb + nf * 16 + fr;
      const float bias = Wb[h];
      const int m_ = mb + mf * 16 + fq * 4;          // 4-aligned, never crosses batch
      const int b = m_ >> 10, ml = m_ & 1023;
      union { ushort4 u; bf16_t q[4]; } pk;
#pragma unroll
      for (int r = 0; r < 4; ++r) pk.q[r] = (bf16_t)(acc[mf][nf][r] + bias);
      *(ushort4*)(WhT + (((size_t)b << 10) + h) * 1024 + ml) = pk.u;
    }
}

// hh = elu(att_b @ Wh_b) per batch; A=att bf16 [n,m], B^T=WhT [h,m]
__global__ __launch_bounds__(256) void k_hhat(const bf16_t* __restrict__ att, const bf16_t* __restrict__ WhT,
                                              bf16_t* __restrict__ hh) {
  MM_PROLOGUE();
  const int m0 = blockIdx.y * 128, n0 = blockIdx.x * 128, bz = blockIdx.z;
  mm_bf16(att + ((size_t)bz << 20), 1024, WhT + ((size_t)bz << 20), 1024, 1024, m0, n0, As, Bs, acc);
  MM_EPI_SETUP(m0, n0);
#pragma unroll
  for (int mf = 0; mf < 4; ++mf)
#pragma unroll
    for (int nf = 0; nf < 4; ++nf) {
      const int n = nb + nf * 16 + fr;
#pragma unroll
      for (int r = 0; r < 4; ++r) {
        const int m = mb + mf * 16 + fq * 4 + r;
        float v = acc[mf][nf][r];
        v = v > 0.f ? v : (__expf(v) - 1.f);
        hh[((size_t)(bz << 10) + m) * 1024 + n] = (bf16_t)v;
      }
    }
}

// Who (+)= hh @ out_W[:, l*1024:+1024].T  (bias folded at l==0); ldb=3072
__global__ __launch_bounds__(256) void k_who_acc(const bf16_t* __restrict__ hh, const bf16_t* __restrict__ Wl,
                                                 const float* __restrict__ Wb, float* __restrict__ Who, int l) {
  MM_PROLOGUE();
  const int m0 = blockIdx.y * 128, n0 = blockIdx.x * 128;
  mm_bf16(hh, 1024, Wl, 3072, 1024, m0, n0, As, Bs, acc);
  MM_EPI_SETUP(m0, n0);
#pragma unroll
  for (int mf = 0; mf < 4; ++mf)
#pragma unroll
    for (int nf = 0; nf < 4; ++nf) {
      const int n = nb + nf * 16 + fr;
#pragma unroll
      for (int r = 0; r < 4; ++r) {
        const int m = mb + mf * 16 + fq * 4 + r;
        const size_t idx = (size_t)m * 512 + n;
        Who[idx] = acc[mf][nf][r] + (l == 0 ? Wb[n] : Who[idx]);
      }
    }
}

__global__ __launch_bounds__(256) void k_proj(const bf16_t* __restrict__ aout, const bf16_t* __restrict__ Wp,
                                              const float* __restrict__ Wb, float* __restrict__ out) {
  MM_PROLOGUE();
  const int m0 = blockIdx.y * 128, n0 = blockIdx.x * 128;
  mm_bf16(aout, 512, Wp, 512, 512, m0, n0, As, Bs, acc);
  MM_EPI_SETUP(m0, n0);
#pragma unroll
  for (int mf = 0; mf < 4; ++mf)
#pragma unroll
    for (int nf = 0; nf < 4; ++nf) {
      const int n = nb + nf * 16 + fr;
#pragma unroll
      for (int r = 0; r < 4; ++r) {
        const int m = mb + mf * 16 + fq * 4 + r;
        out[(size_t)m * 512 + n] = acc[mf][nf][r] + Wb[n];
      }
    }
}

// ---------------- cast f32 -> bf16 ----------------
__global__ __launch_bounds__(256) void k_cast(const float* __restrict__ in, bf16_t* __restrict__ out, int n4) {
  const int i = blockIdx.x * 256 + threadIdx.x;
  if (i < n4) {
    float4 v = ((const float4*)in)[i];
    union { ushort4 u; bf16_t b[4]; } p;
    p.b[0] = (bf16_t)v.x; p.b[1] = (bf16_t)v.y; p.b[2] = (bf16_t)v.z; p.b[3] = (bf16_t)v.w;
    ((ushort4*)out)[i] = p.u;
  }
}

// ---------------- e1/e2 from WhT (coalesced along m) ----------------
__global__ __launch_bounds__(256) void k_e12(const bf16_t* __restrict__ WhT,
                                             const float* __restrict__ ai, const float* __restrict__ aib,
                                             const float* __restrict__ aj, const float* __restrict__ ajb,
                                             float* __restrict__ e1, float* __restrict__ e2, int l) {
  const int b = blockIdx.x >> 2, c = blockIdx.x & 3;
  const int m = c * 256 + threadIdx.x;
  const bf16_t* base = WhT + ((size_t)b << 20) + m;
  const float* av = ai + (l << 10);
  const float* bv = aj + (l << 10);
  float s1 = 0.f, s2 = 0.f;
#pragma unroll 8
  for (int h = 0; h < 1024; ++h) {
    const float v = (float)base[(size_t)h << 10];
    s1 = fmaf(v, av[h], s1);
    s2 = fmaf(v, bv[h], s2);
  }
  e1[(b << 10) + m] = s1 + aib[l];
  e2[(b << 10) + m] = s2 + ajb[l];
}

__global__ __launch_bounds__(256) void k_eo(const float* __restrict__ Who,
                                            const float* __restrict__ ai, const float* __restrict__ aib,
                                            const float* __restrict__ aj, const float* __restrict__ ajb,
                                            float* __restrict__ eo1, float* __restrict__ eo2) {
  const int wid = threadIdx.x >> 6, lane = threadIdx.x & 63;
  const int row = blockIdx.x * 4 + wid;
  const float* wr = Who + (size_t)row * 512;
  float s1 = 0.f, s2 = 0.f;
#pragma unroll
  for (int c = 0; c < 2; ++c) {
    const int idx = c * 256 + lane * 4;
    float4 w4 = *(const float4*)&wr[idx];
    float4 a4 = *(const float4*)&ai[idx];
    float4 b4 = *(const float4*)&aj[idx];
    s1 += w4.x * a4.x + w4.y * a4.y + w4.z * a4.z + w4.w * a4.w;
    s2 += w4.x * b4.x + w4.y * b4.y + w4.z * b4.z + w4.w * b4.w;
  }
#pragma unroll
  for (int off = 32; off > 0; off >>= 1) { s1 += __shfl_xor(s1, off); s2 += __shfl_xor(s2, off); }
  if (lane == 0) { eo1[row] = s1 + aib[0]; eo2[row] = s2 + ajb[0]; }
}

// ---------------- block reduce helpers ----------------
__device__ __forceinline__ float block_max(float v, float* red) {
#pragma unroll
  for (int off = 32; off > 0; off >>= 1) v = fmaxf(v, __shfl_xor(v, off));
  __syncthreads();
  if ((threadIdx.x & 63) == 0) red[threadIdx.x >> 6] = v;
  __syncthreads();
  return fmaxf(fmaxf(red[0], red[1]), fmaxf(red[2], red[3]));
}
__device__ __forceinline__ float block_sum(float v, float* red) {
#pragma unroll
  for (int off = 32; off > 0; off >>= 1) v += __shfl_xor(v, off);
  __syncthreads();
  if ((threadIdx.x & 63) == 0) red[threadIdx.x >> 6] = v;
  __syncthreads();
  return red[0] + red[1] + red[2] + red[3];
}

// ---------------- GAT attention rows (one layer) -> bf16 att ----------------
__global__ __launch_bounds__(256) void k_gat_att(const float* __restrict__ adj, const float* __restrict__ e1,
                                                 const float* __restrict__ e2, bf16_t* __restrict__ att) {
  __shared__ float red[4];
  const int row = blockIdx.x;
  const int b = row >> 10;
  const float* arow = adj + (size_t)row * 1024;
  const float e1v = e1[row];
  const float* e2r = e2 + (b << 10);
  float s[4];
  float mx = -1e30f;
#pragma unroll
  for (int c = 0; c < 4; ++c) {
    const int m = c * 256 + threadIdx.x;
    float e = e1v + e2r[m];
    e = e > 0.f ? e : 0.2f * e;
    s[c] = arow[m] * e;
    mx = fmaxf(mx, s[c]);
  }
  mx = block_max(mx, red);
  float sum = 0.f;
#pragma unroll
  for (int c = 0; c < 4; ++c) { float p = __expf(s[c] - mx); s[c] = p; sum += p; }
  sum = block_sum(sum, red);
  const float inv = 1.f / sum;
#pragma unroll
  for (int c = 0; c < 4; ++c) att[(size_t)row * 1024 + c * 256 + threadIdx.x] = (bf16_t)(s[c] * inv);
}

// ---------------- output-attention mask rows (double softmax) -> bf16 ----------------
__global__ __launch_bounds__(256) void k_mask(const float* __restrict__ adj, const float* __restrict__ eo1,
                                              const float* __restrict__ eo2, bf16_t* __restrict__ mask) {
  __shared__ float red[4];
  const int row = blockIdx.x;
  const int b = row >> 10;
  const float* arow = adj + (size_t)row * 1024;
  const float t1 = eo1[row];
  const float* eor = eo2 + (b << 10);
  float s[4];
  float mx = -1e30f;
#pragma unroll
  for (int c = 0; c < 4; ++c) {
    const int m = c * 256 + threadIdx.x;
    float e = t1 + eor[m];
    e = e > 0.f ? e : 0.2f * e;
    s[c] = arow[m] * e;
    mx = fmaxf(mx, s[c]);
  }
  mx = block_max(mx, red);
  float sum = 0.f;
#pragma unroll
  for (int c = 0; c < 4; ++c) { float p = __expf(s[c] - mx); s[c] = p; sum += p; }
  sum = block_sum(sum, red);
  const float inv = 1.f / sum;
  float mx2 = -1e30f;
#pragma unroll
  for (int c = 0; c < 4; ++c) { s[c] *= inv; mx2 = fmaxf(mx2, s[c]); }
  mx2 = block_max(mx2, red);
  float sum2 = 0.f;
#pragma unroll
  for (int c = 0; c < 4; ++c) { float p = __expf(s[c] - mx2); s[c] = p; sum2 += p; }
  sum2 = block_sum(sum2, red);
  const float inv2 = 1.f / sum2;
#pragma unroll
  for (int c = 0; c < 4; ++c) mask[(size_t)row * 1024 + c * 256 + threadIdx.x] = (bf16_t)(s[c] * inv2);
}

// ---------------- flash-style masked attention (f32 compute, bf16 mask/out) ----------------
#define FP 68
__global__ __launch_bounds__(256) void k_flash(const float* __restrict__ qg, const float* __restrict__ kg,
                                               const float* __restrict__ vg, const bf16_t* __restrict__ maskb,
                                               bf16_t* __restrict__ outb) {
  __shared__ float qT[64][FP];
  __shared__ float kT[64][FP];   // reused as pT
  __shared__ float vs[64][FP];
  const int nb = blockIdx.x, hh = blockIdx.y, bb = blockIdx.z;
  const int n0 = nb * 64;
  const size_t bh = ((size_t)bb * 8 + hh) * 1024 * 64;
  const int tid = threadIdx.x, tx = tid & 15, ty = tid >> 4;
  {
    const int r = tid >> 2, dg = (tid & 3) * 16;
    const float* src = qg + bh + (size_t)(n0 + r) * 64 + dg;
    float4 x0 = *(const float4*)(src);
    float4 x1 = *(const float4*)(src + 4);
    float4 x2 = *(const float4*)(src + 8);
    float4 x3 = *(const float4*)(src + 12);
    qT[dg + 0][r] = x0.x; qT[dg + 1][r] = x0.y; qT[dg + 2][r] = x0.z; qT[dg + 3][r] = x0.w;
    qT[dg + 4][r] = x1.x; qT[dg + 5][r] = x1.y; qT[dg + 6][r] = x1.z; qT[dg + 7][r] = x1.w;
    qT[dg + 8][r] = x2.x; qT[dg + 9][r] = x2.y; qT[dg + 10][r] = x2.z; qT[dg + 11][r] = x2.w;
    qT[dg + 12][r] = x3.x; qT[dg + 13][r] = x3.y; qT[dg + 14][r] = x3.z; qT[dg + 15][r] = x3.w;
  }
  float acc[4][4] = {};
  float mrun[4] = {-1e30f, -1e30f, -1e30f, -1e30f};
  float lrun[4] = {};
  for (int ms = 0; ms < 16; ++ms) {
    const int m0 = ms * 64;
    const int r = tid >> 2, dg = (tid & 3) * 16;
    const float* ksrc = kg + bh + (size_t)(m0 + r) * 64 + dg;
    const float* vsrc = vg + bh + (size_t)(m0 + r) * 64 + dg;
    float4 k0 = *(const float4*)(ksrc);
    float4 k1 = *(const float4*)(ksrc + 4);
    float4 k2 = *(const float4*)(ksrc + 8);
    float4 k3 = *(const float4*)(ksrc + 12);
    float4 v0 = *(const float4*)(vsrc);
    float4 v1 = *(const float4*)(vsrc + 4);
    float4 v2 = *(const float4*)(vsrc + 8);
    float4 v3 = *(const float4*)(vsrc + 12);
    __syncthreads();
    kT[dg + 0][r] = k0.x; kT[dg + 1][r] = k0.y; kT[dg + 2][r] = k0.z; kT[dg + 3][r] = k0.w;
    kT[dg + 4][r] = k1.x; kT[dg + 5][r] = k1.y; kT[dg + 6][r] = k1.z; kT[dg + 7][r] = k1.w;
    kT[dg + 8][r] = k2.x; kT[dg + 9][r] = k2.y; kT[dg + 10][r] = k2.z; kT[dg + 11][r] = k2.w;
    kT[dg + 12][r] = k3.x; kT[dg + 13][r] = k3.y; kT[dg + 14][r] = k3.z; kT[dg + 15][r] = k3.w;
    *(float4*)&vs[r][dg] = v0;
    *(float4*)&vs[r][dg + 4] = v1;
    *(float4*)&vs[r][dg + 8] = v2;
    *(float4*)&vs[r][dg + 12] = v3;
    __syncthreads();
    float s[4][4] = {};
#pragma unroll
    for (int kk = 0; kk < 64; ++kk) {
      float4 a = *(const float4*)&qT[kk][ty * 4];
      float4 b = *(const float4*)&kT[kk][tx * 4];
      s[0][0] = fmaf(a.x, b.x, s[0][0]); s[0][1] = fmaf(a.x, b.y, s[0][1]); s[0][2] = fmaf(a.x, b.z, s[0][2]); s[0][3] = fmaf(a.x, b.w, s[0][3]);
      s[1][0] = fmaf(a.y, b.x, s[1][0]); s[1][1] = fmaf(a.y, b.y, s[1][1]); s[1][2] = fmaf(a.y, b.z, s[1][2]); s[1][3] = fmaf(a.y, b.w, s[1][3]);
      s[2][0] = fmaf(a.z, b.x, s[2][0]); s[2][1] = fmaf(a.z, b.y, s[2][1]); s[2][2] = fmaf(a.z, b.z, s[2][2]); s[2][3] = fmaf(a.z, b.w, s[2][3]);
      s[3][0] = fmaf(a.w, b.x, s[3][0]); s[3][1] = fmaf(a.w, b.y, s[3][1]); s[3][2] = fmaf(a.w, b.z, s[3][2]); s[3][3] = fmaf(a.w, b.w, s[3][3]);
    }
#pragma unroll
    for (int i = 0; i < 4; ++i) {
      union { ushort4 u; bf16_t h[4]; } mv;
      mv.u = *(const ushort4*)(maskb + ((size_t)(bb << 10) + n0 + ty * 4 + i) * 1024 + m0 + tx * 4);
      s[i][0] *= (float)mv.h[0]; s[i][1] *= (float)mv.h[1]; s[i][2] *= (float)mv.h[2]; s[i][3] *= (float)mv.h[3];
      float rm = fmaxf(fmaxf(s[i][0], s[i][1]), fmaxf(s[i][2], s[i][3]));
#pragma unroll
      for (int off = 1; off < 16; off <<= 1) rm = fmaxf(rm, __shfl_xor(rm, off));
      const float nm = fmaxf(mrun[i], rm);
      const float sc = __expf(mrun[i] - nm);
      mrun[i] = nm;
      float rs = 0.f;
#pragma unroll
      for (int j = 0; j < 4; ++j) { float p = __expf(s[i][j] - nm); s[i][j] = p; rs += p; }
#pragma unroll
      for (int off = 1; off < 16; off <<= 1) rs += __shfl_xor(rs, off);
      lrun[i] = lrun[i] * sc + rs;
#pragma unroll
      for (int j = 0; j < 4; ++j) acc[i][j] *= sc;
    }
    __syncthreads();
#pragma unroll
    for (int i = 0; i < 4; ++i)
#pragma unroll
      for (int j = 0; j < 4; ++j) kT[tx * 4 + j][ty * 4 + i] = s[i][j];
    __syncthreads();
#pragma unroll
    for (int kk = 0; kk < 64; ++kk) {
      float4 pa = *(const float4*)&kT[kk][ty * 4];
      float4 vb = *(const float4*)&vs[kk][tx * 4];
      acc[0][0] = fmaf(pa.x, vb.x, acc[0][0]); acc[0][1] = fmaf(pa.x, vb.y, acc[0][1]); acc[0][2] = fmaf(pa.x, vb.z, acc[0][2]); acc[0][3] = fmaf(pa.x, vb.w, acc[0][3]);
      acc[1][0] = fmaf(pa.y, vb.x, acc[1][0]); acc[1][1] = fmaf(pa.y, vb.y, acc[1][1]); acc[1][2] = fmaf(pa.y, vb.z, acc[1][2]); acc[1][3] = fmaf(pa.y, vb.w, acc[1][3]);
      acc[2][0] = fmaf(pa.z, vb.x, acc[2][0]); acc[2][1] = fmaf(pa.z, vb.y, acc[2][1]); acc[2][2] = fmaf(pa.z, vb.z, acc[2][2]); acc[2][3] = fmaf(pa.z, vb.w, acc[2][3]);
      acc[3][0] = fmaf(pa.w, vb.x, acc[3][0]); acc[3][1] = fmaf(pa.w, vb.y, acc[3][1]); acc[3][2] = fmaf(pa.w, vb.z, acc[3][2]); acc[3][3] = fmaf(pa.w, vb.w, acc[3][3]);
    }
  }
#pragma unroll
  for (int i = 0; i < 4; ++i) {
    const int row = n0 + ty * 4 + i;
    const float inv = 1.f / lrun[i];
    union { ushort4 u; bf16_t h[4]; } pv;
#pragma unroll
    for (int j = 0; j < 4; ++j) pv.h[j] = (bf16_t)(acc[i][j] * inv);
    *(ushort4*)(outb + ((size_t)(bb << 10) + row) * 512 + hh * 64 + tx * 4) = pv.u;
  }
}

// ---------------- launcher ----------------
extern "C" void kernel_launch(void* const* d_in, const int* in_sizes, int n_in,
                              void* d_out, int out_size, void* d_ws, size_t ws_size,
                              hipStream_t stream) {
  (void)in_sizes; (void)n_in; (void)out_size; (void)ws_size;
  const float* x        = (const float*)d_in[0];
  const float* adj      = (const float*)d_in[1];
  const float* qkv_w    = (const float*)d_in[2];
  const float* proj_w   = (const float*)d_in[3];
  const float* proj_b   = (const float*)d_in[4];
  const float* gat_W    = (const float*)d_in[5];
  const float* gat_Wb   = (const float*)d_in[6];
  const float* gat_ai   = (const float*)d_in[7];
  const float* gat_ai_b = (const float*)d_in[8];
  const float* gat_aj   = (const float*)d_in[9];
  const float* gat_aj_b = (const float*)d_in[10];
  const float* out_W    = (const float*)d_in[11];
  const float* out_Wb   = (const float*)d_in[12];
  const float* out_ai   = (const float*)d_in[13];
  const float* out_ai_b = (const float*)d_in[14];
  const float* out_aj   = (const float*)d_in[15];
  const float* out_aj_b = (const float*)d_in[16];

  // Workspace layout, ~143 MiB total (fits the 160 MiB known-good budget).
  char* p = (char*)d_ws;
  auto alloc = [&](size_t bytes) { char* r = p; p += (bytes + 255) & ~(size_t)255; return r; };
  bf16_t* xb     = (bf16_t*)alloc(8192ull * 512 * 2);        // 8 MB
  bf16_t* qkvwb  = (bf16_t*)alloc(1536ull * 512 * 2);        // 1.5 MB
  bf16_t* gatwb  = (bf16_t*)alloc(3072ull * 512 * 2);        // 3 MB
  bf16_t* outwb  = (bf16_t*)alloc(512ull * 3072 * 2);        // 3 MB
  bf16_t* projwb = (bf16_t*)alloc(512ull * 512 * 2);         // 0.5 MB
  float*  qb     = (float*)alloc(8ull * 8 * 1024 * 64 * 4);  // 16 MB
  float*  kb     = (float*)alloc(8ull * 8 * 1024 * 64 * 4);  // 16 MB
  float*  vb     = (float*)alloc(8ull * 8 * 1024 * 64 * 4);  // 16 MB
  bf16_t* WhT    = (bf16_t*)alloc(8ull * 1024 * 1024 * 2);   // 16 MB  [b][h][m]
  bf16_t* att    = (bf16_t*)alloc(8ull * 1024 * 1024 * 2);   // 16 MB  (reused as mask)
  bf16_t* hh     = (bf16_t*)alloc(8192ull * 1024 * 2);       // 16 MB
  float*  Who    = (float*)alloc(8192ull * 512 * 4);         // 16 MB
  bf16_t* aout   = (bf16_t*)alloc(8192ull * 512 * 2);        // 8 MB
  float*  e1     = (float*)alloc(8192 * 4);
  float*  e2     = (float*)alloc(8192 * 4);
  float*  eo1    = (float*)alloc(8192 * 4);
  float*  eo2    = (float*)alloc(8192 * 4);
  bf16_t* mask   = att;

  const dim3 blk(256);
  k_cast<<<4096, blk, 0, stream>>>(x, xb, 1048576);
  k_cast<<<768,  blk, 0, stream>>>(qkv_w, qkvwb, 196608);
  k_cast<<<1536, blk, 0, stream>>>(gat_W, gatwb, 393216);
  k_cast<<<1536, blk, 0, stream>>>(out_W, outwb, 393216);
  k_cast<<<256,  blk, 0, stream>>>(proj_w, projwb, 65536);

  k_qkv<<<dim3(12, 64), blk, 0, stream>>>(xb, qkvwb, qb, kb, vb);
  for (int l = 0; l < 3; ++l) {
    k_wh<<<dim3(8, 64), blk, 0, stream>>>(xb, gatwb + (size_t)l * 1024 * 512, gat_Wb + l * 1024, WhT);
    k_e12<<<32, blk, 0, stream>>>(WhT, gat_ai, gat_ai_b, gat_aj, gat_aj_b, e1, e2, l);
    k_gat_att<<<8192, blk, 0, stream>>>(adj, e1, e2, att);
    k_hhat<<<dim3(8, 8, 8), blk, 0, stream>>>(att, WhT, hh);
    k_who_acc<<<dim3(4, 64), blk, 0, stream>>>(hh, outwb + l * 1024, out_Wb, Who, l);
  }
  k_eo<<<2048, blk, 0, stream>>>(Who, out_ai, out_ai_b, out_aj, out_aj_b, eo1, eo2);
  k_mask<<<8192, blk, 0, stream>>>(adj, eo1, eo2, mask);
  k_flash<<<dim3(16, 8, 8), blk, 0, stream>>>(qb, kb, vb, mask, aout);
  k_proj<<<dim3(4, 64), blk, 0, stream>>>(aout, projwb, proj_b, (float*)d_out);
}

// Round 4
// 579.835 us; speedup vs baseline: 3.4629x; 1.3627x over previous
//
#include <hip/hip_runtime.h>
#include <math.h>
#include <stdint.h>

#define SCALEQ 0.125f

typedef __bf16 bf16_t;
typedef __bf16 bf16x8 __attribute__((ext_vector_type(8)));
typedef float f32x4 __attribute__((ext_vector_type(4)));

// global -> LDS async copy, 16B per lane. LDS dest is wave-uniform base + lane*16.
#define GLOAD_LDS16(gsrc, ldst)                                                   \
  __builtin_amdgcn_global_load_lds(                                               \
      (const __attribute__((address_space(1))) void*)(uintptr_t)(const void*)(gsrc), \
      (__attribute__((address_space(3))) void*)(uintptr_t)(void*)(ldst), 16, 0, 0)

// ---------------- bf16 MFMA GEMM core ----------------
// C[128x128] per block, 256 thr = 4 waves, BK=64. B given as B^T [N,K] row-major.
// Wave quadrant (wr=w>>1, wc=w&1); A/B frag: lane holds row fr=lane&15, 8 k at fq*8.
// C: col=lane&15, row=(lane>>4)*4+reg.
__device__ __forceinline__ void mm_bf16(const bf16_t* __restrict__ A, int lda,
                                        const bf16_t* __restrict__ B, int ldb,
                                        int K, int m0, int n0,
                                        bf16_t* As, bf16_t* Bs, f32x4 (&acc)[4][4]) {
  const int tid = threadIdx.x, lane = tid & 63, w = tid >> 6;
  const int wr = (w >> 1) * 64, wc = (w & 1) * 64;
  const int fr = lane & 15, fq = lane >> 4;
  for (int kt = 0; kt < K; kt += 64) {
    __syncthreads();
#pragma unroll
    for (int t = 0; t < 4; ++t) {
      const int rl = t * 32 + w * 8 + (lane >> 3);
      const int c8 = (lane & 7) * 8;
      GLOAD_LDS16(A + (size_t)(m0 + rl) * lda + kt + c8, As + (t * 32 + w * 8) * 64);
      GLOAD_LDS16(B + (size_t)(n0 + rl) * ldb + kt + c8, Bs + (t * 32 + w * 8) * 64);
    }
    __syncthreads();
#pragma unroll
    for (int ks = 0; ks < 2; ++ks) {
      bf16x8 af[4], bfv[4];
#pragma unroll
      for (int mf = 0; mf < 4; ++mf)
        af[mf] = *(const bf16x8*)(As + (wr + mf * 16 + fr) * 64 + ks * 32 + fq * 8);
#pragma unroll
      for (int nf = 0; nf < 4; ++nf)
        bfv[nf] = *(const bf16x8*)(Bs + (wc + nf * 16 + fr) * 64 + ks * 32 + fq * 8);
#pragma unroll
      for (int mf = 0; mf < 4; ++mf)
#pragma unroll
        for (int nf = 0; nf < 4; ++nf)
          acc[mf][nf] = __builtin_amdgcn_mfma_f32_16x16x32_bf16(af[mf], bfv[nf], acc[mf][nf], 0, 0, 0);
    }
  }
}

#define MM_PROLOGUE()                                  \
  __shared__ __align__(16) bf16_t As[128 * 64];        \
  __shared__ __align__(16) bf16_t Bs[128 * 64];        \
  f32x4 acc[4][4];                                     \
  _Pragma("unroll") for (int i_ = 0; i_ < 4; ++i_)     \
  _Pragma("unroll") for (int j_ = 0; j_ < 4; ++j_) acc[i_][j_] = (f32x4)0.0f;

#define MM_EPI_SETUP(M0, N0)                                   \
  const int lane = threadIdx.x & 63, w = threadIdx.x >> 6;     \
  const int fr = lane & 15, fq = lane >> 4;                    \
  const int mb = (M0) + (w >> 1) * 64, nb = (N0) + (w & 1) * 64;

// ---------------- GEMM kernels ----------------
// qkv: q,k -> bf16 [b,h,tok,64] (q pre-scaled); v -> bf16 transposed [b,h,64,tok]
__global__ __launch_bounds__(256) void k_qkv(const bf16_t* __restrict__ xb, const bf16_t* __restrict__ wb,
                                             bf16_t* __restrict__ qb, bf16_t* __restrict__ kb,
                                             bf16_t* __restrict__ vT) {
  MM_PROLOGUE();
  const int m0 = blockIdx.y * 128, n0 = blockIdx.x * 128;
  mm_bf16(xb, 512, wb, 512, 512, m0, n0, As, Bs, acc);
  MM_EPI_SETUP(m0, n0);
#pragma unroll
  for (int mf = 0; mf < 4; ++mf)
#pragma unroll
    for (int nf = 0; nf < 4; ++nf) {
      const int n = nb + nf * 16 + fr;
      const int which = n >> 9, hd = (n >> 6) & 7, d = n & 63;
      const int m_ = mb + mf * 16 + fq * 4;
      const int b = m_ >> 10, tok0 = m_ & 1023;
      if (which == 2) {
        union { ushort4 u; bf16_t q[4]; } pk;
#pragma unroll
        for (int r = 0; r < 4; ++r) pk.q[r] = (bf16_t)acc[mf][nf][r];
        *(ushort4*)(vT + (((size_t)b * 8 + hd) * 64 + d) * 1024 + tok0) = pk.u;
      } else {
        bf16_t* dst = which ? kb : qb;
        const float sc = which ? 1.f : SCALEQ;
#pragma unroll
        for (int r = 0; r < 4; ++r)
          dst[(((size_t)b * 8 + hd) * 1024 + tok0 + r) * 64 + d] = (bf16_t)(acc[mf][nf][r] * sc);
      }
    }
}

// Wh_l^T (per batch): WhT[b][h][m], bf16
__global__ __launch_bounds__(256) void k_wh(const bf16_t* __restrict__ xb, const bf16_t* __restrict__ Wl,
                                            const float* __restrict__ Wb, bf16_t* __restrict__ WhT) {
  MM_PROLOGUE();
  const int m0 = blockIdx.y * 128, n0 = blockIdx.x * 128;
  mm_bf16(xb, 512, Wl, 512, 512, m0, n0, As, Bs, acc);
  MM_EPI_SETUP(m0, n0);
#pragma unroll
  for (int mf = 0; mf < 4; ++mf)
#pragma unroll
    for (int nf = 0; nf < 4; ++nf) {
      const int h = nb + nf * 16 + fr;
      const float bias = Wb[h];
      const int m_ = mb + mf * 16 + fq * 4;
      const int b = m_ >> 10, ml = m_ & 1023;
      union { ushort4 u; bf16_t q[4]; } pk;
#pragma unroll
      for (int r = 0; r < 4; ++r) pk.q[r] = (bf16_t)(acc[mf][nf][r] + bias);
      *(ushort4*)(WhT + (((size_t)b << 10) + h) * 1024 + ml) = pk.u;
    }
}

// hh = elu(att_b @ Wh_b) per batch
__global__ __launch_bounds__(256) void k_hhat(const bf16_t* __restrict__ att, const bf16_t* __restrict__ WhT,
                                              bf16_t* __restrict__ hh) {
  MM_PROLOGUE();
  const int m0 = blockIdx.y * 128, n0 = blockIdx.x * 128, bz = blockIdx.z;
  mm_bf16(att + ((size_t)bz << 20), 1024, WhT + ((size_t)bz << 20), 1024, 1024, m0, n0, As, Bs, acc);
  MM_EPI_SETUP(m0, n0);
#pragma unroll
  for (int mf = 0; mf < 4; ++mf)
#pragma unroll
    for (int nf = 0; nf < 4; ++nf) {
      const int n = nb + nf * 16 + fr;
#pragma unroll
      for (int r = 0; r < 4; ++r) {
        const int m = mb + mf * 16 + fq * 4 + r;
        float v = acc[mf][nf][r];
        v = v > 0.f ? v : (__expf(v) - 1.f);
        hh[((size_t)(bz << 10) + m) * 1024 + n] = (bf16_t)v;
      }
    }
}

// Who (+)= hh @ out_W[:, l*1024:+1024].T (bias folded at l==0)
__global__ __launch_bounds__(256) void k_who_acc(const bf16_t* __restrict__ hh, const bf16_t* __restrict__ Wl,
                                                 const float* __restrict__ Wb, float* __restrict__ Who, int l) {
  MM_PROLOGUE();
  const int m0 = blockIdx.y * 128, n0 = blockIdx.x * 128;
  mm_bf16(hh, 1024, Wl, 3072, 1024, m0, n0, As, Bs, acc);
  MM_EPI_SETUP(m0, n0);
#pragma unroll
  for (int mf = 0; mf < 4; ++mf)
#pragma unroll
    for (int nf = 0; nf < 4; ++nf) {
      const int n = nb + nf * 16 + fr;
#pragma unroll
      for (int r = 0; r < 4; ++r) {
        const int m = mb + mf * 16 + fq * 4 + r;
        const size_t idx = (size_t)m * 512 + n;
        Who[idx] = acc[mf][nf][r] + (l == 0 ? Wb[n] : Who[idx]);
      }
    }
}

__global__ __launch_bounds__(256) void k_proj(const bf16_t* __restrict__ aout, const bf16_t* __restrict__ Wp,
                                              const float* __restrict__ Wb, float* __restrict__ out) {
  MM_PROLOGUE();
  const int m0 = blockIdx.y * 128, n0 = blockIdx.x * 128;
  mm_bf16(aout, 512, Wp, 512, 512, m0, n0, As, Bs, acc);
  MM_EPI_SETUP(m0, n0);
#pragma unroll
  for (int mf = 0; mf < 4; ++mf)
#pragma unroll
    for (int nf = 0; nf < 4; ++nf) {
      const int n = nb + nf * 16 + fr;
#pragma unroll
      for (int r = 0; r < 4; ++r) {
        const int m = mb + mf * 16 + fq * 4 + r;
        out[(size_t)m * 512 + n] = acc[mf][nf][r] + Wb[n];
      }
    }
}

// ---------------- cast f32 -> bf16 ----------------
__global__ __launch_bounds__(256) void k_cast(const float* __restrict__ in, bf16_t* __restrict__ out, int n4) {
  const int i = blockIdx.x * 256 + threadIdx.x;
  if (i < n4) {
    float4 v = ((const float4*)in)[i];
    union { ushort4 u; bf16_t b[4]; } p;
    p.b[0] = (bf16_t)v.x; p.b[1] = (bf16_t)v.y; p.b[2] = (bf16_t)v.z; p.b[3] = (bf16_t)v.w;
    ((ushort4*)out)[i] = p.u;
  }
}

// ---------------- e1/e2 from WhT (coalesced along m) ----------------
__global__ __launch_bounds__(256) void k_e12(const bf16_t* __restrict__ WhT,
                                             const float* __restrict__ ai, const float* __restrict__ aib,
                                             const float* __restrict__ aj, const float* __restrict__ ajb,
                                             float* __restrict__ e1, float* __restrict__ e2, int l) {
  const int b = blockIdx.x >> 2, c = blockIdx.x & 3;
  const int m = c * 256 + threadIdx.x;
  const bf16_t* base = WhT + ((size_t)b << 20) + m;
  const float* av = ai + (l << 10);
  const float* bv = aj + (l << 10);
  float s1 = 0.f, s2 = 0.f;
#pragma unroll 8
  for (int h = 0; h < 1024; ++h) {
    const float v = (float)base[(size_t)h << 10];
    s1 = fmaf(v, av[h], s1);
    s2 = fmaf(v, bv[h], s2);
  }
  e1[(b << 10) + m] = s1 + aib[l];
  e2[(b << 10) + m] = s2 + ajb[l];
}

__global__ __launch_bounds__(256) void k_eo(const float* __restrict__ Who,
                                            const float* __restrict__ ai, const float* __restrict__ aib,
                                            const float* __restrict__ aj, const float* __restrict__ ajb,
                                            float* __restrict__ eo1, float* __restrict__ eo2) {
  const int wid = threadIdx.x >> 6, lane = threadIdx.x & 63;
  const int row = blockIdx.x * 4 + wid;
  const float* wr = Who + (size_t)row * 512;
  float s1 = 0.f, s2 = 0.f;
#pragma unroll
  for (int c = 0; c < 2; ++c) {
    const int idx = c * 256 + lane * 4;
    float4 w4 = *(const float4*)&wr[idx];
    float4 a4 = *(const float4*)&ai[idx];
    float4 b4 = *(const float4*)&aj[idx];
    s1 += w4.x * a4.x + w4.y * a4.y + w4.z * a4.z + w4.w * a4.w;
    s2 += w4.x * b4.x + w4.y * b4.y + w4.z * b4.z + w4.w * b4.w;
  }
#pragma unroll
  for (int off = 32; off > 0; off >>= 1) { s1 += __shfl_xor(s1, off); s2 += __shfl_xor(s2, off); }
  if (lane == 0) { eo1[row] = s1 + aib[0]; eo2[row] = s2 + ajb[0]; }
}

// ---------------- block reduce helpers ----------------
__device__ __forceinline__ float block_max(float v, float* red) {
#pragma unroll
  for (int off = 32; off > 0; off >>= 1) v = fmaxf(v, __shfl_xor(v, off));
  __syncthreads();
  if ((threadIdx.x & 63) == 0) red[threadIdx.x >> 6] = v;
  __syncthreads();
  return fmaxf(fmaxf(red[0], red[1]), fmaxf(red[2], red[3]));
}
__device__ __forceinline__ float block_sum(float v, float* red) {
#pragma unroll
  for (int off = 32; off > 0; off >>= 1) v += __shfl_xor(v, off);
  __syncthreads();
  if ((threadIdx.x & 63) == 0) red[threadIdx.x >> 6] = v;
  __syncthreads();
  return red[0] + red[1] + red[2] + red[3];
}

// ---------------- GAT attention rows ----------------
__global__ __launch_bounds__(256) void k_gat_att(const float* __restrict__ adj, const float* __restrict__ e1,
                                                 const float* __restrict__ e2, bf16_t* __restrict__ att) {
  __shared__ float red[4];
  const int row = blockIdx.x;
  const int b = row >> 10;
  const float* arow = adj + (size_t)row * 1024;
  const float e1v = e1[row];
  const float* e2r = e2 + (b << 10);
  float s[4];
  float mx = -1e30f;
#pragma unroll
  for (int c = 0; c < 4; ++c) {
    const int m = c * 256 + threadIdx.x;
    float e = e1v + e2r[m];
    e = e > 0.f ? e : 0.2f * e;
    s[c] = arow[m] * e;
    mx = fmaxf(mx, s[c]);
  }
  mx = block_max(mx, red);
  float sum = 0.f;
#pragma unroll
  for (int c = 0; c < 4; ++c) { float p = __expf(s[c] - mx); s[c] = p; sum += p; }
  sum = block_sum(sum, red);
  const float inv = 1.f / sum;
#pragma unroll
  for (int c = 0; c < 4; ++c) att[(size_t)row * 1024 + c * 256 + threadIdx.x] = (bf16_t)(s[c] * inv);
}

// ---------------- output-attention mask rows (double softmax) ----------------
__global__ __launch_bounds__(256) void k_mask(const float* __restrict__ adj, const float* __restrict__ eo1,
                                              const float* __restrict__ eo2, bf16_t* __restrict__ mask) {
  __shared__ float red[4];
  const int row = blockIdx.x;
  const int b = row >> 10;
  const float* arow = adj + (size_t)row * 1024;
  const float t1 = eo1[row];
  const float* eor = eo2 + (b << 10);
  float s[4];
  float mx = -1e30f;
#pragma unroll
  for (int c = 0; c < 4; ++c) {
    const int m = c * 256 + threadIdx.x;
    float e = t1 + eor[m];
    e = e > 0.f ? e : 0.2f * e;
    s[c] = arow[m] * e;
    mx = fmaxf(mx, s[c]);
  }
  mx = block_max(mx, red);
  float sum = 0.f;
#pragma unroll
  for (int c = 0; c < 4; ++c) { float p = __expf(s[c] - mx); s[c] = p; sum += p; }
  sum = block_sum(sum, red);
  const float inv = 1.f / sum;
  float mx2 = -1e30f;
#pragma unroll
  for (int c = 0; c < 4; ++c) { s[c] *= inv; mx2 = fmaxf(mx2, s[c]); }
  mx2 = block_max(mx2, red);
  float sum2 = 0.f;
#pragma unroll
  for (int c = 0; c < 4; ++c) { float p = __expf(s[c] - mx2); s[c] = p; sum2 += p; }
  sum2 = block_sum(sum2, red);
  const float inv2 = 1.f / sum2;
#pragma unroll
  for (int c = 0; c < 4; ++c) mask[(size_t)row * 1024 + c * 256 + threadIdx.x] = (bf16_t)(s[c] * inv2);
}

// ---------------- MFMA flash attention ----------------
// Block: 128 q-rows of one (b,h). 4 waves, wave w owns rows w*32..w*32+31 x all keys.
// Chunk = 64 keys. Padded LDS (stride 72 bf16 = 144B, 16B-aligned rows).
#define LP 72
__global__ __launch_bounds__(256) void k_flash(const bf16_t* __restrict__ qg, const bf16_t* __restrict__ kg,
                                               const bf16_t* __restrict__ vTg, const bf16_t* __restrict__ maskb,
                                               bf16_t* __restrict__ aout) {
  __shared__ __align__(16) bf16_t Ks[64][LP];
  __shared__ __align__(16) bf16_t Vs[64][LP];
  __shared__ __align__(16) bf16_t Ms[128][LP];
  __shared__ __align__(16) bf16_t PL[4][32][LP];
  const int tid = threadIdx.x, lane = tid & 63, w = tid >> 6;
  const int fr = lane & 15, fq = lane >> 4;
  const int n0 = blockIdx.x * 128, hh = blockIdx.y, bb = blockIdx.z;
  const size_t bh = ((size_t)bb * 8 + hh) << 16;
  const bf16_t* q = qg + bh;
  const bf16_t* kk = kg + bh;
  const bf16_t* vT = vTg + bh;
  const bf16_t* mk = maskb + ((size_t)bb << 20);

  // Q fragments in registers (wave-private rows)
  bf16x8 qf[2][2];
#pragma unroll
  for (int mf = 0; mf < 2; ++mf)
#pragma unroll
    for (int ks = 0; ks < 2; ++ks)
      qf[mf][ks] = *(const bf16x8*)(q + (size_t)(n0 + w * 32 + mf * 16 + fr) * 64 + ks * 32 + fq * 8);

  f32x4 o[2][4];
#pragma unroll
  for (int mf = 0; mf < 2; ++mf)
#pragma unroll
    for (int nf = 0; nf < 4; ++nf) o[mf][nf] = (f32x4)0.0f;
  float mrun[2][4], lrun[2][4];
#pragma unroll
  for (int mf = 0; mf < 2; ++mf)
#pragma unroll
    for (int r = 0; r < 4; ++r) { mrun[mf][r] = -1e30f; lrun[mf][r] = 0.f; }

  const int srow = tid >> 2, scol = (tid & 3) * 16;   // K/V staging: 64x64
  const int mrow = tid >> 1, mcol = (tid & 1) * 32;   // mask staging: 128x64

  for (int c = 0; c < 16; ++c) {
    const int k0 = c * 64;
    // issue global loads early (latency hides under prev chunk's tail)
    bf16x8 kv0 = *(const bf16x8*)(kk + (size_t)(k0 + srow) * 64 + scol);
    bf16x8 kv1 = *(const bf16x8*)(kk + (size_t)(k0 + srow) * 64 + scol + 8);
    bf16x8 vv0 = *(const bf16x8*)(vT + (size_t)srow * 1024 + k0 + scol);
    bf16x8 vv1 = *(const bf16x8*)(vT + (size_t)srow * 1024 + k0 + scol + 8);
    const bf16_t* mrowp = mk + (size_t)(n0 + mrow) * 1024 + k0 + mcol;
    bf16x8 mv0 = *(const bf16x8*)(mrowp);
    bf16x8 mv1 = *(const bf16x8*)(mrowp + 8);
    bf16x8 mv2 = *(const bf16x8*)(mrowp + 16);
    bf16x8 mv3 = *(const bf16x8*)(mrowp + 24);
    __syncthreads();   // prev chunk fully consumed
    *(bf16x8*)&Ks[srow][scol] = kv0; *(bf16x8*)&Ks[srow][scol + 8] = kv1;
    *(bf16x8*)&Vs[srow][scol] = vv0; *(bf16x8*)&Vs[srow][scol + 8] = vv1;
    *(bf16x8*)&Ms[mrow][mcol] = mv0;      *(bf16x8*)&Ms[mrow][mcol + 8] = mv1;
    *(bf16x8*)&Ms[mrow][mcol + 16] = mv2; *(bf16x8*)&Ms[mrow][mcol + 24] = mv3;
    __syncthreads();

    // S = Q K^T  (wave rows x 64 keys)
    f32x4 s[2][4];
#pragma unroll
    for (int mf = 0; mf < 2; ++mf)
#pragma unroll
      for (int nf = 0; nf < 4; ++nf) s[mf][nf] = (f32x4)0.0f;
#pragma unroll
    for (int ks = 0; ks < 2; ++ks) {
      bf16x8 kf[4];
#pragma unroll
      for (int nf = 0; nf < 4; ++nf)
        kf[nf] = *(const bf16x8*)&Ks[nf * 16 + fr][ks * 32 + fq * 8];
#pragma unroll
      for (int mf = 0; mf < 2; ++mf)
#pragma unroll
        for (int nf = 0; nf < 4; ++nf)
          s[mf][nf] = __builtin_amdgcn_mfma_f32_16x16x32_bf16(qf[mf][ks], kf[nf], s[mf][nf], 0, 0, 0);
    }

    // mask * S, online softmax (rows: mf*16+fq*4+r, cols: nf*16+fr)
#pragma unroll
    for (int mf = 0; mf < 2; ++mf) {
#pragma unroll
      for (int nf = 0; nf < 4; ++nf)
#pragma unroll
        for (int r = 0; r < 4; ++r)
          s[mf][nf][r] *= (float)Ms[mf * 16 + fq * 4 + r][nf * 16 + fr];
#pragma unroll
      for (int r = 0; r < 4; ++r) {
        float rm = fmaxf(fmaxf(s[mf][0][r], s[mf][1][r]), fmaxf(s[mf][2][r], s[mf][3][r]));
        rm = fmaxf(rm, __shfl_xor(rm, 1));
        rm = fmaxf(rm, __shfl_xor(rm, 2));
        rm = fmaxf(rm, __shfl_xor(rm, 4));
        rm = fmaxf(rm, __shfl_xor(rm, 8));
        const float nm = fmaxf(mrun[mf][r], rm);
        const float sc = __expf(mrun[mf][r] - nm);
        mrun[mf][r] = nm;
        float p0 = __expf(s[mf][0][r] - nm);
        float p1 = __expf(s[mf][1][r] - nm);
        float p2 = __expf(s[mf][2][r] - nm);
        float p3 = __expf(s[mf][3][r] - nm);
        float rs = (p0 + p1) + (p2 + p3);
        rs += __shfl_xor(rs, 1);
        rs += __shfl_xor(rs, 2);
        rs += __shfl_xor(rs, 4);
        rs += __shfl_xor(rs, 8);
        lrun[mf][r] = lrun[mf][r] * sc + rs;
#pragma unroll
        for (int nfo = 0; nfo < 4; ++nfo) o[mf][nfo][r] *= sc;
        const int prow = mf * 16 + fq * 4 + r;
        PL[w][prow][fr] = (bf16_t)p0;
        PL[w][prow][16 + fr] = (bf16_t)p1;
        PL[w][prow][32 + fr] = (bf16_t)p2;
        PL[w][prow][48 + fr] = (bf16_t)p3;
      }
    }

    // O += P V   (wave-private PL; same-wave LDS dependency, no barrier needed)
#pragma unroll
    for (int ks = 0; ks < 2; ++ks) {
      bf16x8 pf[2], vf[4];
#pragma unroll
      for (int mf = 0; mf < 2; ++mf)
        pf[mf] = *(const bf16x8*)&PL[w][mf * 16 + fr][ks * 32 + fq * 8];
#pragma unroll
      for (int nfo = 0; nfo < 4; ++nfo)
        vf[nfo] = *(const bf16x8*)&Vs[nfo * 16 + fr][ks * 32 + fq * 8];
#pragma unroll
      for (int mf = 0; mf < 2; ++mf)
#pragma unroll
        for (int nfo = 0; nfo < 4; ++nfo)
          o[mf][nfo] = __builtin_amdgcn_mfma_f32_16x16x32_bf16(pf[mf], vf[nfo], o[mf][nfo], 0, 0, 0);
    }
  }

  // epilogue: aout[b*1024+tok][hh*64 + d]
#pragma unroll
  for (int mf = 0; mf < 2; ++mf)
#pragma unroll
    for (int r = 0; r < 4; ++r) {
      const int tok = n0 + w * 32 + mf * 16 + fq * 4 + r;
      const float inv = 1.f / lrun[mf][r];
#pragma unroll
      for (int nfo = 0; nfo < 4; ++nfo)
        aout[((size_t)(bb << 10) + tok) * 512 + hh * 64 + nfo * 16 + fr] = (bf16_t)(o[mf][nfo][r] * inv);
    }
}

// ---------------- launcher ----------------
extern "C" void kernel_launch(void* const* d_in, const int* in_sizes, int n_in,
                              void* d_out, int out_size, void* d_ws, size_t ws_size,
                              hipStream_t stream) {
  (void)in_sizes; (void)n_in; (void)out_size; (void)ws_size;
  const float* x        = (const float*)d_in[0];
  const float* adj      = (const float*)d_in[1];
  const float* qkv_w    = (const float*)d_in[2];
  const float* proj_w   = (const float*)d_in[3];
  const float* proj_b   = (const float*)d_in[4];
  const float* gat_W    = (const float*)d_in[5];
  const float* gat_Wb   = (const float*)d_in[6];
  const float* gat_ai   = (const float*)d_in[7];
  const float* gat_ai_b = (const float*)d_in[8];
  const float* gat_aj   = (const float*)d_in[9];
  const float* gat_aj_b = (const float*)d_in[10];
  const float* out_W    = (const float*)d_in[11];
  const float* out_Wb   = (const float*)d_in[12];
  const float* out_ai   = (const float*)d_in[13];
  const float* out_ai_b = (const float*)d_in[14];
  const float* out_aj   = (const float*)d_in[15];
  const float* out_aj_b = (const float*)d_in[16];

  char* p = (char*)d_ws;
  auto alloc = [&](size_t bytes) { char* r = p; p += (bytes + 255) & ~(size_t)255; return r; };
  bf16_t* xb     = (bf16_t*)alloc(8192ull * 512 * 2);
  bf16_t* qkvwb  = (bf16_t*)alloc(1536ull * 512 * 2);
  bf16_t* gatwb  = (bf16_t*)alloc(3072ull * 512 * 2);
  bf16_t* outwb  = (bf16_t*)alloc(512ull * 3072 * 2);
  bf16_t* projwb = (bf16_t*)alloc(512ull * 512 * 2);
  bf16_t* qb     = (bf16_t*)alloc(8ull * 8 * 1024 * 64 * 2);   // [b,h,tok,64]
  bf16_t* kb     = (bf16_t*)alloc(8ull * 8 * 1024 * 64 * 2);   // [b,h,tok,64]
  bf16_t* vT     = (bf16_t*)alloc(8ull * 8 * 64 * 1024 * 2);   // [b,h,64,tok]
  bf16_t* WhT    = (bf16_t*)alloc(8ull * 1024 * 1024 * 2);     // [b][h][m]
  bf16_t* att    = (bf16_t*)alloc(8ull * 1024 * 1024 * 2);     // reused as mask
  bf16_t* hh     = (bf16_t*)alloc(8192ull * 1024 * 2);
  float*  Who    = (float*)alloc(8192ull * 512 * 4);
  bf16_t* aout   = (bf16_t*)alloc(8192ull * 512 * 2);
  float*  e1     = (float*)alloc(8192 * 4);
  float*  e2     = (float*)alloc(8192 * 4);
  float*  eo1    = (float*)alloc(8192 * 4);
  float*  eo2    = (float*)alloc(8192 * 4);
  bf16_t* mask   = att;

  const dim3 blk(256);
  k_cast<<<4096, blk, 0, stream>>>(x, xb, 1048576);
  k_cast<<<768,  blk, 0, stream>>>(qkv_w, qkvwb, 196608);
  k_cast<<<1536, blk, 0, stream>>>(gat_W, gatwb, 393216);
  k_cast<<<1536, blk, 0, stream>>>(out_W, outwb, 393216);
  k_cast<<<256,  blk, 0, stream>>>(proj_w, projwb, 65536);

  k_qkv<<<dim3(12, 64), blk, 0, stream>>>(xb, qkvwb, qb, kb, vT);
  for (int l = 0; l < 3; ++l) {
    k_wh<<<dim3(8, 64), blk, 0, stream>>>(xb, gatwb + (size_t)l * 1024 * 512, gat_Wb + l * 1024, WhT);
    k_e12<<<32, blk, 0, stream>>>(WhT, gat_ai, gat_ai_b, gat_aj, gat_aj_b, e1, e2, l);
    k_gat_att<<<8192, blk, 0, stream>>>(adj, e1, e2, att);
    k_hhat<<<dim3(8, 8, 8), blk, 0, stream>>>(att, WhT, hh);
    k_who_acc<<<dim3(4, 64), blk, 0, stream>>>(hh, outwb + l * 1024, out_Wb, Who, l);
  }
  k_eo<<<2048, blk, 0, stream>>>(Who, out_ai, out_ai_b, out_aj, out_aj_b, eo1, eo2);
  k_mask<<<8192, blk, 0, stream>>>(adj, eo1, eo2, mask);
  k_flash<<<dim3(8, 8, 8), blk, 0, stream>>>(qb, kb, vT, mask, aout);
  k_proj<<<dim3(4, 64), blk, 0, stream>>>(aout, projwb, proj_b, (float*)d_out);
}

// Round 5
// 569.578 us; speedup vs baseline: 3.5252x; 1.0180x over previous
//
#include <hip/hip_runtime.h>
#include <math.h>
#include <stdint.h>

#define SCALEQ 0.125f

typedef __bf16 bf16_t;
typedef __bf16 bf16x8 __attribute__((ext_vector_type(8)));
typedef float f32x4 __attribute__((ext_vector_type(4)));

// global -> LDS async copy, 16B per lane. LDS dest is wave-uniform base + lane*16.
#define GLOAD_LDS16(gsrc, ldst)                                                   \
  __builtin_amdgcn_global_load_lds(                                               \
      (const __attribute__((address_space(1))) void*)(uintptr_t)(const void*)(gsrc), \
      (__attribute__((address_space(3))) void*)(uintptr_t)(void*)(ldst), 16, 0, 0)

// ---------------- bf16 MFMA GEMM core ----------------
// C[128x128] per block, 256 thr = 4 waves, BK=64. B given as B^T [N,K] row-major.
// Wave quadrant (wr=w>>1, wc=w&1); A/B frag: lane holds row fr=lane&15, 8 k at fq*8.
// C: col=lane&15, row=(lane>>4)*4+reg.
__device__ __forceinline__ void mm_bf16(const bf16_t* __restrict__ A, int lda,
                                        const bf16_t* __restrict__ B, int ldb,
                                        int K, int m0, int n0,
                                        bf16_t* As, bf16_t* Bs, f32x4 (&acc)[4][4]) {
  const int tid = threadIdx.x, lane = tid & 63, w = tid >> 6;
  const int wr = (w >> 1) * 64, wc = (w & 1) * 64;
  const int fr = lane & 15, fq = lane >> 4;
  for (int kt = 0; kt < K; kt += 64) {
    __syncthreads();
#pragma unroll
    for (int t = 0; t < 4; ++t) {
      const int rl = t * 32 + w * 8 + (lane >> 3);
      const int c8 = (lane & 7) * 8;
      GLOAD_LDS16(A + (size_t)(m0 + rl) * lda + kt + c8, As + (t * 32 + w * 8) * 64);
      GLOAD_LDS16(B + (size_t)(n0 + rl) * ldb + kt + c8, Bs + (t * 32 + w * 8) * 64);
    }
    __syncthreads();
#pragma unroll
    for (int ks = 0; ks < 2; ++ks) {
      bf16x8 af[4], bfv[4];
#pragma unroll
      for (int mf = 0; mf < 4; ++mf)
        af[mf] = *(const bf16x8*)(As + (wr + mf * 16 + fr) * 64 + ks * 32 + fq * 8);
#pragma unroll
      for (int nf = 0; nf < 4; ++nf)
        bfv[nf] = *(const bf16x8*)(Bs + (wc + nf * 16 + fr) * 64 + ks * 32 + fq * 8);
#pragma unroll
      for (int mf = 0; mf < 4; ++mf)
#pragma unroll
        for (int nf = 0; nf < 4; ++nf)
          acc[mf][nf] = __builtin_amdgcn_mfma_f32_16x16x32_bf16(af[mf], bfv[nf], acc[mf][nf], 0, 0, 0);
    }
  }
}

#define MM_PROLOGUE()                                  \
  __shared__ __align__(16) bf16_t As[128 * 64];        \
  __shared__ __align__(16) bf16_t Bs[128 * 64];        \
  f32x4 acc[4][4];                                     \
  _Pragma("unroll") for (int i_ = 0; i_ < 4; ++i_)     \
  _Pragma("unroll") for (int j_ = 0; j_ < 4; ++j_) acc[i_][j_] = (f32x4)0.0f;

#define MM_EPI_SETUP(M0, N0)                                   \
  const int lane = threadIdx.x & 63, w = threadIdx.x >> 6;     \
  const int fr = lane & 15, fq = lane >> 4;                    \
  const int mb = (M0) + (w >> 1) * 64, nb = (N0) + (w & 1) * 64;

// ---------------- GEMM kernels ----------------
// qkv: q,k -> bf16 [b,h,tok,64] (q pre-scaled); v -> bf16 transposed [b,h,64,tok]
__global__ __launch_bounds__(256) void k_qkv(const bf16_t* __restrict__ xb, const bf16_t* __restrict__ wb,
                                             bf16_t* __restrict__ qb, bf16_t* __restrict__ kb,
                                             bf16_t* __restrict__ vT) {
  MM_PROLOGUE();
  const int m0 = blockIdx.y * 128, n0 = blockIdx.x * 128;
  mm_bf16(xb, 512, wb, 512, 512, m0, n0, As, Bs, acc);
  MM_EPI_SETUP(m0, n0);
#pragma unroll
  for (int mf = 0; mf < 4; ++mf)
#pragma unroll
    for (int nf = 0; nf < 4; ++nf) {
      const int n = nb + nf * 16 + fr;
      const int which = n >> 9, hd = (n >> 6) & 7, d = n & 63;
      const int m_ = mb + mf * 16 + fq * 4;
      const int b = m_ >> 10, tok0 = m_ & 1023;
      if (which == 2) {
        union { ushort4 u; bf16_t q[4]; } pk;
#pragma unroll
        for (int r = 0; r < 4; ++r) pk.q[r] = (bf16_t)acc[mf][nf][r];
        *(ushort4*)(vT + (((size_t)b * 8 + hd) * 64 + d) * 1024 + tok0) = pk.u;
      } else {
        bf16_t* dst = which ? kb : qb;
        const float sc = which ? 1.f : SCALEQ;
#pragma unroll
        for (int r = 0; r < 4; ++r)
          dst[(((size_t)b * 8 + hd) * 1024 + tok0 + r) * 64 + d] = (bf16_t)(acc[mf][nf][r] * sc);
      }
    }
}

// Wh_l^T (per batch): WhT[b][h][m], bf16
__global__ __launch_bounds__(256) void k_wh(const bf16_t* __restrict__ xb, const bf16_t* __restrict__ Wl,
                                            const float* __restrict__ Wb, bf16_t* __restrict__ WhT) {
  MM_PROLOGUE();
  const int m0 = blockIdx.y * 128, n0 = blockIdx.x * 128;
  mm_bf16(xb, 512, Wl, 512, 512, m0, n0, As, Bs, acc);
  MM_EPI_SETUP(m0, n0);
#pragma unroll
  for (int mf = 0; mf < 4; ++mf)
#pragma unroll
    for (int nf = 0; nf < 4; ++nf) {
      const int h = nb + nf * 16 + fr;
      const float bias = Wb[h];
      const int m_ = mb + mf * 16 + fq * 4;
      const int b = m_ >> 10, ml = m_ & 1023;
      union { ushort4 u; bf16_t q[4]; } pk;
#pragma unroll
      for (int r = 0; r < 4; ++r) pk.q[r] = (bf16_t)(acc[mf][nf][r] + bias);
      *(ushort4*)(WhT + (((size_t)b << 10) + h) * 1024 + ml) = pk.u;
    }
}

// hh = elu(att_b @ Wh_b) per batch
__global__ __launch_bounds__(256) void k_hhat(const bf16_t* __restrict__ att, const bf16_t* __restrict__ WhT,
                                              bf16_t* __restrict__ hh) {
  MM_PROLOGUE();
  const int m0 = blockIdx.y * 128, n0 = blockIdx.x * 128, bz = blockIdx.z;
  mm_bf16(att + ((size_t)bz << 20), 1024, WhT + ((size_t)bz << 20), 1024, 1024, m0, n0, As, Bs, acc);
  MM_EPI_SETUP(m0, n0);
#pragma unroll
  for (int mf = 0; mf < 4; ++mf)
#pragma unroll
    for (int nf = 0; nf < 4; ++nf) {
      const int n = nb + nf * 16 + fr;
#pragma unroll
      for (int r = 0; r < 4; ++r) {
        const int m = mb + mf * 16 + fq * 4 + r;
        float v = acc[mf][nf][r];
        v = v > 0.f ? v : (__expf(v) - 1.f);
        hh[((size_t)(bz << 10) + m) * 1024 + n] = (bf16_t)v;
      }
    }
}

// Who (+)= hh @ out_W[:, l*1024:+1024].T (bias folded at l==0)
__global__ __launch_bounds__(256) void k_who_acc(const bf16_t* __restrict__ hh, const bf16_t* __restrict__ Wl,
                                                 const float* __restrict__ Wb, float* __restrict__ Who, int l) {
  MM_PROLOGUE();
  const int m0 = blockIdx.y * 128, n0 = blockIdx.x * 128;
  mm_bf16(hh, 1024, Wl, 3072, 1024, m0, n0, As, Bs, acc);
  MM_EPI_SETUP(m0, n0);
#pragma unroll
  for (int mf = 0; mf < 4; ++mf)
#pragma unroll
    for (int nf = 0; nf < 4; ++nf) {
      const int n = nb + nf * 16 + fr;
#pragma unroll
      for (int r = 0; r < 4; ++r) {
        const int m = mb + mf * 16 + fq * 4 + r;
        const size_t idx = (size_t)m * 512 + n;
        Who[idx] = acc[mf][nf][r] + (l == 0 ? Wb[n] : Who[idx]);
      }
    }
}

__global__ __launch_bounds__(256) void k_proj(const bf16_t* __restrict__ aout, const bf16_t* __restrict__ Wp,
                                              const float* __restrict__ Wb, float* __restrict__ out) {
  MM_PROLOGUE();
  const int m0 = blockIdx.y * 128, n0 = blockIdx.x * 128;
  mm_bf16(aout, 512, Wp, 512, 512, m0, n0, As, Bs, acc);
  MM_EPI_SETUP(m0, n0);
#pragma unroll
  for (int mf = 0; mf < 4; ++mf)
#pragma unroll
    for (int nf = 0; nf < 4; ++nf) {
      const int n = nb + nf * 16 + fr;
#pragma unroll
      for (int r = 0; r < 4; ++r) {
        const int m = mb + mf * 16 + fq * 4 + r;
        out[(size_t)m * 512 + n] = acc[mf][nf][r] + Wb[n];
      }
    }
}

// ---------------- cast f32 -> bf16 ----------------
__global__ __launch_bounds__(256) void k_cast(const float* __restrict__ in, bf16_t* __restrict__ out, int n4) {
  const int i = blockIdx.x * 256 + threadIdx.x;
  if (i < n4) {
    float4 v = ((const float4*)in)[i];
    union { ushort4 u; bf16_t b[4]; } p;
    p.b[0] = (bf16_t)v.x; p.b[1] = (bf16_t)v.y; p.b[2] = (bf16_t)v.z; p.b[3] = (bf16_t)v.w;
    ((ushort4*)out)[i] = p.u;
  }
}

// ---------------- e1/e2 from WhT (coalesced along m) ----------------
__global__ __launch_bounds__(256) void k_e12(const bf16_t* __restrict__ WhT,
                                             const float* __restrict__ ai, const float* __restrict__ aib,
                                             const float* __restrict__ aj, const float* __restrict__ ajb,
                                             float* __restrict__ e1, float* __restrict__ e2, int l) {
  const int b = blockIdx.x >> 2, c = blockIdx.x & 3;
  const int m = c * 256 + threadIdx.x;
  const bf16_t* base = WhT + ((size_t)b << 20) + m;
  const float* av = ai + (l << 10);
  const float* bv = aj + (l << 10);
  float s1 = 0.f, s2 = 0.f;
#pragma unroll 8
  for (int h = 0; h < 1024; ++h) {
    const float v = (float)base[(size_t)h << 10];
    s1 = fmaf(v, av[h], s1);
    s2 = fmaf(v, bv[h], s2);
  }
  e1[(b << 10) + m] = s1 + aib[l];
  e2[(b << 10) + m] = s2 + ajb[l];
}

__global__ __launch_bounds__(256) void k_eo(const float* __restrict__ Who,
                                            const float* __restrict__ ai, const float* __restrict__ aib,
                                            const float* __restrict__ aj, const float* __restrict__ ajb,
                                            float* __restrict__ eo1, float* __restrict__ eo2) {
  const int wid = threadIdx.x >> 6, lane = threadIdx.x & 63;
  const int row = blockIdx.x * 4 + wid;
  const float* wr = Who + (size_t)row * 512;
  float s1 = 0.f, s2 = 0.f;
#pragma unroll
  for (int c = 0; c < 2; ++c) {
    const int idx = c * 256 + lane * 4;
    float4 w4 = *(const float4*)&wr[idx];
    float4 a4 = *(const float4*)&ai[idx];
    float4 b4 = *(const float4*)&aj[idx];
    s1 += w4.x * a4.x + w4.y * a4.y + w4.z * a4.z + w4.w * a4.w;
    s2 += w4.x * b4.x + w4.y * b4.y + w4.z * b4.z + w4.w * b4.w;
  }
#pragma unroll
  for (int off = 32; off > 0; off >>= 1) { s1 += __shfl_xor(s1, off); s2 += __shfl_xor(s2, off); }
  if (lane == 0) { eo1[row] = s1 + aib[0]; eo2[row] = s2 + ajb[0]; }
}

// ---------------- block reduce helpers ----------------
__device__ __forceinline__ float block_max(float v, float* red) {
#pragma unroll
  for (int off = 32; off > 0; off >>= 1) v = fmaxf(v, __shfl_xor(v, off));
  __syncthreads();
  if ((threadIdx.x & 63) == 0) red[threadIdx.x >> 6] = v;
  __syncthreads();
  return fmaxf(fmaxf(red[0], red[1]), fmaxf(red[2], red[3]));
}
__device__ __forceinline__ float block_sum(float v, float* red) {
#pragma unroll
  for (int off = 32; off > 0; off >>= 1) v += __shfl_xor(v, off);
  __syncthreads();
  if ((threadIdx.x & 63) == 0) red[threadIdx.x >> 6] = v;
  __syncthreads();
  return red[0] + red[1] + red[2] + red[3];
}

// ---------------- GAT attention rows ----------------
__global__ __launch_bounds__(256) void k_gat_att(const float* __restrict__ adj, const float* __restrict__ e1,
                                                 const float* __restrict__ e2, bf16_t* __restrict__ att) {
  __shared__ float red[4];
  const int row = blockIdx.x;
  const int b = row >> 10;
  const float* arow = adj + (size_t)row * 1024;
  const float e1v = e1[row];
  const float* e2r = e2 + (b << 10);
  float s[4];
  float mx = -1e30f;
#pragma unroll
  for (int c = 0; c < 4; ++c) {
    const int m = c * 256 + threadIdx.x;
    float e = e1v + e2r[m];
    e = e > 0.f ? e : 0.2f * e;
    s[c] = arow[m] * e;
    mx = fmaxf(mx, s[c]);
  }
  mx = block_max(mx, red);
  float sum = 0.f;
#pragma unroll
  for (int c = 0; c < 4; ++c) { float p = __expf(s[c] - mx); s[c] = p; sum += p; }
  sum = block_sum(sum, red);
  const float inv = 1.f / sum;
#pragma unroll
  for (int c = 0; c < 4; ++c) att[(size_t)row * 1024 + c * 256 + threadIdx.x] = (bf16_t)(s[c] * inv);
}

// ---------------- output-attention mask rows (double softmax) ----------------
__global__ __launch_bounds__(256) void k_mask(const float* __restrict__ adj, const float* __restrict__ eo1,
                                              const float* __restrict__ eo2, bf16_t* __restrict__ mask) {
  __shared__ float red[4];
  const int row = blockIdx.x;
  const int b = row >> 10;
  const float* arow = adj + (size_t)row * 1024;
  const float t1 = eo1[row];
  const float* eor = eo2 + (b << 10);
  float s[4];
  float mx = -1e30f;
#pragma unroll
  for (int c = 0; c < 4; ++c) {
    const int m = c * 256 + threadIdx.x;
    float e = t1 + eor[m];
    e = e > 0.f ? e : 0.2f * e;
    s[c] = arow[m] * e;
    mx = fmaxf(mx, s[c]);
  }
  mx = block_max(mx, red);
  float sum = 0.f;
#pragma unroll
  for (int c = 0; c < 4; ++c) { float p = __expf(s[c] - mx); s[c] = p; sum += p; }
  sum = block_sum(sum, red);
  const float inv = 1.f / sum;
  float mx2 = -1e30f;
#pragma unroll
  for (int c = 0; c < 4; ++c) { s[c] *= inv; mx2 = fmaxf(mx2, s[c]); }
  mx2 = block_max(mx2, red);
  float sum2 = 0.f;
#pragma unroll
  for (int c = 0; c < 4; ++c) { float p = __expf(s[c] - mx2); s[c] = p; sum2 += p; }
  sum2 = block_sum(sum2, red);
  const float inv2 = 1.f / sum2;
#pragma unroll
  for (int c = 0; c < 4; ++c) mask[(size_t)row * 1024 + c * 256 + threadIdx.x] = (bf16_t)(s[c] * inv2);
}

// ---------------- mask transpose: maskT[b][k][q] = mask[b][q][k] ----------------
__global__ __launch_bounds__(256) void k_mtr(const bf16_t* __restrict__ in, bf16_t* __restrict__ out) {
  __shared__ bf16_t T[64][72];
  const int q0 = blockIdx.x * 64, k0 = blockIdx.y * 64, b = blockIdx.z;
  const bf16_t* src = in + ((size_t)b << 20);
  bf16_t* dst = out + ((size_t)b << 20);
  const int r = threadIdx.x >> 2, c = (threadIdx.x & 3) * 16;
  bf16x8 a0 = *(const bf16x8*)(src + (size_t)(q0 + r) * 1024 + k0 + c);
  bf16x8 a1 = *(const bf16x8*)(src + (size_t)(q0 + r) * 1024 + k0 + c + 8);
  *(bf16x8*)&T[r][c] = a0;
  *(bf16x8*)&T[r][c + 8] = a1;
  __syncthreads();
  union { bf16x8 v[2]; bf16_t e[16]; } o;
#pragma unroll
  for (int j = 0; j < 16; ++j) o.e[j] = T[c + j][r];
  *(bf16x8*)(dst + (size_t)(k0 + r) * 1024 + q0 + c) = o.v[0];
  *(bf16x8*)(dst + (size_t)(k0 + r) * 1024 + q0 + c + 8) = o.v[1];
}

// ---------------- MFMA flash attention v3 ----------------
// Block: 64 q-rows of one (b,h); 4 waves, wave w owns rows w*16..+15.
// No max-tracking (masked logits bounded ~|8|): p = exp(mask*S), sums reduced once
// at the end. Mask read fragment-direct from maskT (global, L2-resident).
#define LP 72
__global__ __launch_bounds__(256) void k_flash(const bf16_t* __restrict__ qg, const bf16_t* __restrict__ kg,
                                               const bf16_t* __restrict__ vTg, const bf16_t* __restrict__ maskT,
                                               bf16_t* __restrict__ aout) {
  __shared__ __align__(16) bf16_t Ks[64][LP];
  __shared__ __align__(16) bf16_t Vs[64][LP];
  __shared__ __align__(16) bf16_t PL[4][16][LP];
  const int tid = threadIdx.x, lane = tid & 63, w = tid >> 6;
  const int fr = lane & 15, fq = lane >> 4;
  const int n0 = blockIdx.x * 64, hh = blockIdx.y, bb = blockIdx.z;
  const size_t bh = ((size_t)bb * 8 + hh) << 16;
  const bf16_t* q = qg + bh;
  const bf16_t* kk = kg + bh;
  const bf16_t* vT = vTg + bh;
  const bf16_t* mT = maskT + ((size_t)bb << 20);

  // Q fragments in registers (wave rows n0+w*16 .. +15)
  bf16x8 qf[2];
#pragma unroll
  for (int ks = 0; ks < 2; ++ks)
    qf[ks] = *(const bf16x8*)(q + (size_t)(n0 + w * 16 + fr) * 64 + ks * 32 + fq * 8);

  f32x4 o[4];
#pragma unroll
  for (int nf = 0; nf < 4; ++nf) o[nf] = (f32x4)0.0f;
  float psum[4] = {0.f, 0.f, 0.f, 0.f};

  const int srow = tid >> 2, scol = (tid & 3) * 16;   // 64x64 staging

  for (int c = 0; c < 16; ++c) {
    const int k0 = c * 64;
    // issue global loads early
    bf16x8 kv0 = *(const bf16x8*)(kk + (size_t)(k0 + srow) * 64 + scol);
    bf16x8 kv1 = *(const bf16x8*)(kk + (size_t)(k0 + srow) * 64 + scol + 8);
    bf16x8 vv0 = *(const bf16x8*)(vT + (size_t)srow * 1024 + k0 + scol);
    bf16x8 vv1 = *(const bf16x8*)(vT + (size_t)srow * 1024 + k0 + scol + 8);
    union { ushort4 u; bf16_t h[4]; } mfr[4];
#pragma unroll
    for (int nf = 0; nf < 4; ++nf)
      mfr[nf].u = *(const ushort4*)(mT + (size_t)(k0 + nf * 16 + fr) * 1024 + n0 + w * 16 + fq * 4);
    __syncthreads();   // prev chunk fully consumed
    *(bf16x8*)&Ks[srow][scol] = kv0; *(bf16x8*)&Ks[srow][scol + 8] = kv1;
    *(bf16x8*)&Vs[srow][scol] = vv0; *(bf16x8*)&Vs[srow][scol + 8] = vv1;
    __syncthreads();

    // S = Q K^T
    f32x4 s[4];
#pragma unroll
    for (int nf = 0; nf < 4; ++nf) s[nf] = (f32x4)0.0f;
#pragma unroll
    for (int ks = 0; ks < 2; ++ks) {
      bf16x8 kf[4];
#pragma unroll
      for (int nf = 0; nf < 4; ++nf)
        kf[nf] = *(const bf16x8*)&Ks[nf * 16 + fr][ks * 32 + fq * 8];
#pragma unroll
      for (int nf = 0; nf < 4; ++nf)
        s[nf] = __builtin_amdgcn_mfma_f32_16x16x32_bf16(qf[ks], kf[nf], s[nf], 0, 0, 0);
    }

    // p = exp(mask * S); accumulate per-lane partial row-sums; stage P
#pragma unroll
    for (int nf = 0; nf < 4; ++nf)
#pragma unroll
      for (int r = 0; r < 4; ++r) {
        const float p = __expf(s[nf][r] * (float)mfr[nf].h[r]);
        psum[r] += p;
        PL[w][fq * 4 + r][nf * 16 + fr] = (bf16_t)p;
      }

    // O += P V (wave-private PL, same-wave dependency)
#pragma unroll
    for (int ks = 0; ks < 2; ++ks) {
      bf16x8 pf = *(const bf16x8*)&PL[w][fr][ks * 32 + fq * 8];
      bf16x8 vf[4];
#pragma unroll
      for (int nfo = 0; nfo < 4; ++nfo)
        vf[nfo] = *(const bf16x8*)&Vs[nfo * 16 + fr][ks * 32 + fq * 8];
#pragma unroll
      for (int nfo = 0; nfo < 4; ++nfo)
        o[nfo] = __builtin_amdgcn_mfma_f32_16x16x32_bf16(pf, vf[nfo], o[nfo], 0, 0, 0);
    }
  }

  // row-sum reduce across the 16 fr lanes (once)
#pragma unroll
  for (int r = 0; r < 4; ++r) {
    psum[r] += __shfl_xor(psum[r], 1);
    psum[r] += __shfl_xor(psum[r], 2);
    psum[r] += __shfl_xor(psum[r], 4);
    psum[r] += __shfl_xor(psum[r], 8);
  }
#pragma unroll
  for (int r = 0; r < 4; ++r) {
    const int tok = n0 + w * 16 + fq * 4 + r;
    const float inv = 1.f / psum[r];
#pragma unroll
    for (int nfo = 0; nfo < 4; ++nfo)
      aout[((size_t)(bb << 10) + tok) * 512 + hh * 64 + nfo * 16 + fr] = (bf16_t)(o[nfo][r] * inv);
  }
}

// ---------------- launcher ----------------
extern "C" void kernel_launch(void* const* d_in, const int* in_sizes, int n_in,
                              void* d_out, int out_size, void* d_ws, size_t ws_size,
                              hipStream_t stream) {
  (void)in_sizes; (void)n_in; (void)out_size; (void)ws_size;
  const float* x        = (const float*)d_in[0];
  const float* adj      = (const float*)d_in[1];
  const float* qkv_w    = (const float*)d_in[2];
  const float* proj_w   = (const float*)d_in[3];
  const float* proj_b   = (const float*)d_in[4];
  const float* gat_W    = (const float*)d_in[5];
  const float* gat_Wb   = (const float*)d_in[6];
  const float* gat_ai   = (const float*)d_in[7];
  const float* gat_ai_b = (const float*)d_in[8];
  const float* gat_aj   = (const float*)d_in[9];
  const float* gat_aj_b = (const float*)d_in[10];
  const float* out_W    = (const float*)d_in[11];
  const float* out_Wb   = (const float*)d_in[12];
  const float* out_ai   = (const float*)d_in[13];
  const float* out_ai_b = (const float*)d_in[14];
  const float* out_aj   = (const float*)d_in[15];
  const float* out_aj_b = (const float*)d_in[16];

  char* p = (char*)d_ws;
  auto alloc = [&](size_t bytes) { char* r = p; p += (bytes + 255) & ~(size_t)255; return r; };
  bf16_t* xb     = (bf16_t*)alloc(8192ull * 512 * 2);
  bf16_t* qkvwb  = (bf16_t*)alloc(1536ull * 512 * 2);
  bf16_t* gatwb  = (bf16_t*)alloc(3072ull * 512 * 2);
  bf16_t* outwb  = (bf16_t*)alloc(512ull * 3072 * 2);
  bf16_t* projwb = (bf16_t*)alloc(512ull * 512 * 2);
  bf16_t* qb     = (bf16_t*)alloc(8ull * 8 * 1024 * 64 * 2);   // [b,h,tok,64]
  bf16_t* kb     = (bf16_t*)alloc(8ull * 8 * 1024 * 64 * 2);   // [b,h,tok,64]
  bf16_t* vT     = (bf16_t*)alloc(8ull * 8 * 64 * 1024 * 2);   // [b,h,64,tok]
  bf16_t* WhT    = (bf16_t*)alloc(8ull * 1024 * 1024 * 2);     // [b][h][m]
  bf16_t* att    = (bf16_t*)alloc(8ull * 1024 * 1024 * 2);     // reused as mask
  bf16_t* hh     = (bf16_t*)alloc(8192ull * 1024 * 2);
  float*  Who    = (float*)alloc(8192ull * 512 * 4);
  bf16_t* aout   = (bf16_t*)alloc(8192ull * 512 * 2);
  bf16_t* maskT  = (bf16_t*)alloc(8ull * 1024 * 1024 * 2);     // [b][k][q]
  float*  e1     = (float*)alloc(8192 * 4);
  float*  e2     = (float*)alloc(8192 * 4);
  float*  eo1    = (float*)alloc(8192 * 4);
  float*  eo2    = (float*)alloc(8192 * 4);
  bf16_t* mask   = att;

  const dim3 blk(256);
  k_cast<<<4096, blk, 0, stream>>>(x, xb, 1048576);
  k_cast<<<768,  blk, 0, stream>>>(qkv_w, qkvwb, 196608);
  k_cast<<<1536, blk, 0, stream>>>(gat_W, gatwb, 393216);
  k_cast<<<1536, blk, 0, stream>>>(out_W, outwb, 393216);
  k_cast<<<256,  blk, 0, stream>>>(proj_w, projwb, 65536);

  k_qkv<<<dim3(12, 64), blk, 0, stream>>>(xb, qkvwb, qb, kb, vT);
  for (int l = 0; l < 3; ++l) {
    k_wh<<<dim3(8, 64), blk, 0, stream>>>(xb, gatwb + (size_t)l * 1024 * 512, gat_Wb + l * 1024, WhT);
    k_e12<<<32, blk, 0, stream>>>(WhT, gat_ai, gat_ai_b, gat_aj, gat_aj_b, e1, e2, l);
    k_gat_att<<<8192, blk, 0, stream>>>(adj, e1, e2, att);
    k_hhat<<<dim3(8, 8, 8), blk, 0, stream>>>(att, WhT, hh);
    k_who_acc<<<dim3(4, 64), blk, 0, stream>>>(hh, outwb + l * 1024, out_Wb, Who, l);
  }
  k_eo<<<2048, blk, 0, stream>>>(Who, out_ai, out_ai_b, out_aj, out_aj_b, eo1, eo2);
  k_mask<<<8192, blk, 0, stream>>>(adj, eo1, eo2, mask);
  k_mtr<<<dim3(16, 16, 8), blk, 0, stream>>>(mask, maskT);
  k_flash<<<dim3(16, 8, 8), blk, 0, stream>>>(qb, kb, vT, maskT, aout);
  k_proj<<<dim3(4, 64), blk, 0, stream>>>(aout, projwb, proj_b, (float*)d_out);
}

// Round 6
// 434.610 us; speedup vs baseline: 4.6200x; 1.3105x over previous
//
#include <hip/hip_runtime.h>
#include <math.h>
#include <stdint.h>

#define SCALEQ 0.125f

typedef __bf16 bf16_t;
typedef __bf16 bf16x8 __attribute__((ext_vector_type(8)));
typedef float f32x4 __attribute__((ext_vector_type(4)));

// global -> LDS async copy, 16B per lane. LDS dest is wave-uniform base + lane*16.
#define GLOAD_LDS16(gsrc, ldst)                                                   \
  __builtin_amdgcn_global_load_lds(                                               \
      (const __attribute__((address_space(1))) void*)(uintptr_t)(const void*)(gsrc), \
      (__attribute__((address_space(3))) void*)(uintptr_t)(void*)(ldst), 16, 0, 0)

// ---------------- bf16 MFMA GEMM core ----------------
// C[128x128] per block, 256 thr = 4 waves, BK=64. B given as B^T [N,K] row-major.
// Wave quadrant (wr=w>>1, wc=w&1); A/B frag: lane holds row fr=lane&15, 8 k at fq*8.
// C: col=lane&15, row=(lane>>4)*4+reg.
__device__ __forceinline__ void mm_bf16(const bf16_t* __restrict__ A, int lda,
                                        const bf16_t* __restrict__ B, int ldb,
                                        int K, int m0, int n0,
                                        bf16_t* As, bf16_t* Bs, f32x4 (&acc)[4][4]) {
  const int tid = threadIdx.x, lane = tid & 63, w = tid >> 6;
  const int wr = (w >> 1) * 64, wc = (w & 1) * 64;
  const int fr = lane & 15, fq = lane >> 4;
  for (int kt = 0; kt < K; kt += 64) {
    __syncthreads();
#pragma unroll
    for (int t = 0; t < 4; ++t) {
      const int rl = t * 32 + w * 8 + (lane >> 3);
      const int c8 = (lane & 7) * 8;
      GLOAD_LDS16(A + (size_t)(m0 + rl) * lda + kt + c8, As + (t * 32 + w * 8) * 64);
      GLOAD_LDS16(B + (size_t)(n0 + rl) * ldb + kt + c8, Bs + (t * 32 + w * 8) * 64);
    }
    __syncthreads();
#pragma unroll
    for (int ks = 0; ks < 2; ++ks) {
      bf16x8 af[4], bfv[4];
#pragma unroll
      for (int mf = 0; mf < 4; ++mf)
        af[mf] = *(const bf16x8*)(As + (wr + mf * 16 + fr) * 64 + ks * 32 + fq * 8);
#pragma unroll
      for (int nf = 0; nf < 4; ++nf)
        bfv[nf] = *(const bf16x8*)(Bs + (wc + nf * 16 + fr) * 64 + ks * 32 + fq * 8);
#pragma unroll
      for (int mf = 0; mf < 4; ++mf)
#pragma unroll
        for (int nf = 0; nf < 4; ++nf)
          acc[mf][nf] = __builtin_amdgcn_mfma_f32_16x16x32_bf16(af[mf], bfv[nf], acc[mf][nf], 0, 0, 0);
    }
  }
}

#define MM_PROLOGUE()                                  \
  __shared__ __align__(16) bf16_t As[128 * 64];        \
  __shared__ __align__(16) bf16_t Bs[128 * 64];        \
  f32x4 acc[4][4];                                     \
  _Pragma("unroll") for (int i_ = 0; i_ < 4; ++i_)     \
  _Pragma("unroll") for (int j_ = 0; j_ < 4; ++j_) acc[i_][j_] = (f32x4)0.0f;

#define MM_EPI_SETUP(M0, N0)                                   \
  const int lane = threadIdx.x & 63, w = threadIdx.x >> 6;     \
  const int fr = lane & 15, fq = lane >> 4;                    \
  const int mb = (M0) + (w >> 1) * 64, nb = (N0) + (w & 1) * 64;

// ---------------- GEMM kernels ----------------
// qkv: q,k -> bf16 [b,h,tok,64] (q pre-scaled); v -> bf16 transposed [b,h,64,tok]
__global__ __launch_bounds__(256) void k_qkv(const bf16_t* __restrict__ xb, const bf16_t* __restrict__ wb,
                                             bf16_t* __restrict__ qb, bf16_t* __restrict__ kb,
                                             bf16_t* __restrict__ vT) {
  MM_PROLOGUE();
  const int m0 = blockIdx.y * 128, n0 = blockIdx.x * 128;
  mm_bf16(xb, 512, wb, 512, 512, m0, n0, As, Bs, acc);
  MM_EPI_SETUP(m0, n0);
#pragma unroll
  for (int mf = 0; mf < 4; ++mf)
#pragma unroll
    for (int nf = 0; nf < 4; ++nf) {
      const int n = nb + nf * 16 + fr;
      const int which = n >> 9, hd = (n >> 6) & 7, d = n & 63;
      const int m_ = mb + mf * 16 + fq * 4;
      const int b = m_ >> 10, tok0 = m_ & 1023;
      if (which == 2) {
        union { ushort4 u; bf16_t q[4]; } pk;
#pragma unroll
        for (int r = 0; r < 4; ++r) pk.q[r] = (bf16_t)acc[mf][nf][r];
        *(ushort4*)(vT + (((size_t)b * 8 + hd) * 64 + d) * 1024 + tok0) = pk.u;
      } else {
        bf16_t* dst = which ? kb : qb;
        const float sc = which ? 1.f : SCALEQ;
#pragma unroll
        for (int r = 0; r < 4; ++r)
          dst[(((size_t)b * 8 + hd) * 1024 + tok0 + r) * 64 + d] = (bf16_t)(acc[mf][nf][r] * sc);
      }
    }
}

// Wh_l^T (per batch): WhT[b][h][m], bf16
__global__ __launch_bounds__(256) void k_wh(const bf16_t* __restrict__ xb, const bf16_t* __restrict__ Wl,
                                            const float* __restrict__ Wb, bf16_t* __restrict__ WhT) {
  MM_PROLOGUE();
  const int m0 = blockIdx.y * 128, n0 = blockIdx.x * 128;
  mm_bf16(xb, 512, Wl, 512, 512, m0, n0, As, Bs, acc);
  MM_EPI_SETUP(m0, n0);
#pragma unroll
  for (int mf = 0; mf < 4; ++mf)
#pragma unroll
    for (int nf = 0; nf < 4; ++nf) {
      const int h = nb + nf * 16 + fr;
      const float bias = Wb[h];
      const int m_ = mb + mf * 16 + fq * 4;
      const int b = m_ >> 10, ml = m_ & 1023;
      union { ushort4 u; bf16_t q[4]; } pk;
#pragma unroll
      for (int r = 0; r < 4; ++r) pk.q[r] = (bf16_t)(acc[mf][nf][r] + bias);
      *(ushort4*)(WhT + (((size_t)b << 10) + h) * 1024 + ml) = pk.u;
    }
}

// hh = elu(att_b @ Wh_b) per batch
__global__ __launch_bounds__(256) void k_hhat(const bf16_t* __restrict__ att, const bf16_t* __restrict__ WhT,
                                              bf16_t* __restrict__ hh) {
  MM_PROLOGUE();
  const int m0 = blockIdx.y * 128, n0 = blockIdx.x * 128, bz = blockIdx.z;
  mm_bf16(att + ((size_t)bz << 20), 1024, WhT + ((size_t)bz << 20), 1024, 1024, m0, n0, As, Bs, acc);
  MM_EPI_SETUP(m0, n0);
#pragma unroll
  for (int mf = 0; mf < 4; ++mf)
#pragma unroll
    for (int nf = 0; nf < 4; ++nf) {
      const int n = nb + nf * 16 + fr;
#pragma unroll
      for (int r = 0; r < 4; ++r) {
        const int m = mb + mf * 16 + fq * 4 + r;
        float v = acc[mf][nf][r];
        v = v > 0.f ? v : (__expf(v) - 1.f);
        hh[((size_t)(bz << 10) + m) * 1024 + n] = (bf16_t)v;
      }
    }
}

// Who (+)= hh @ out_W[:, l*1024:+1024].T (bias folded at l==0)
__global__ __launch_bounds__(256) void k_who_acc(const bf16_t* __restrict__ hh, const bf16_t* __restrict__ Wl,
                                                 const float* __restrict__ Wb, float* __restrict__ Who, int l) {
  MM_PROLOGUE();
  const int m0 = blockIdx.y * 128, n0 = blockIdx.x * 128;
  mm_bf16(hh, 1024, Wl, 3072, 1024, m0, n0, As, Bs, acc);
  MM_EPI_SETUP(m0, n0);
#pragma unroll
  for (int mf = 0; mf < 4; ++mf)
#pragma unroll
    for (int nf = 0; nf < 4; ++nf) {
      const int n = nb + nf * 16 + fr;
#pragma unroll
      for (int r = 0; r < 4; ++r) {
        const int m = mb + mf * 16 + fq * 4 + r;
        const size_t idx = (size_t)m * 512 + n;
        Who[idx] = acc[mf][nf][r] + (l == 0 ? Wb[n] : Who[idx]);
      }
    }
}

__global__ __launch_bounds__(256) void k_proj(const bf16_t* __restrict__ aout, const bf16_t* __restrict__ Wp,
                                              const float* __restrict__ Wb, float* __restrict__ out) {
  MM_PROLOGUE();
  const int m0 = blockIdx.y * 128, n0 = blockIdx.x * 128;
  mm_bf16(aout, 512, Wp, 512, 512, m0, n0, As, Bs, acc);
  MM_EPI_SETUP(m0, n0);
#pragma unroll
  for (int mf = 0; mf < 4; ++mf)
#pragma unroll
    for (int nf = 0; nf < 4; ++nf) {
      const int n = nb + nf * 16 + fr;
#pragma unroll
      for (int r = 0; r < 4; ++r) {
        const int m = mb + mf * 16 + fq * 4 + r;
        out[(size_t)m * 512 + n] = acc[mf][nf][r] + Wb[n];
      }
    }
}

// ---------------- cast f32 -> bf16 ----------------
__global__ __launch_bounds__(256) void k_cast(const float* __restrict__ in, bf16_t* __restrict__ out, int n4) {
  const int i = blockIdx.x * 256 + threadIdx.x;
  if (i < n4) {
    float4 v = ((const float4*)in)[i];
    union { ushort4 u; bf16_t b[4]; } p;
    p.b[0] = (bf16_t)v.x; p.b[1] = (bf16_t)v.y; p.b[2] = (bf16_t)v.z; p.b[3] = (bf16_t)v.w;
    ((ushort4*)out)[i] = p.u;
  }
}

// ---------------- algebraic e1/e2: wv[v] = W_l^T @ avec, con[v] = dot(Wb_l,avec)+bias ----------------
// v = 2*l + (0:ai, 1:aj)
__global__ __launch_bounds__(256) void k_wvec(const bf16_t* __restrict__ gatwb,
                                              const float* __restrict__ gWb,
                                              const float* __restrict__ ai, const float* __restrict__ aib,
                                              const float* __restrict__ aj, const float* __restrict__ ajb,
                                              float* __restrict__ wv, float* __restrict__ con) {
  __shared__ float sred[4][64];
  __shared__ float cred[256];
  const int v = blockIdx.y, l = v >> 1;
  const float* avec = ((v & 1) ? aj : ai) + (l << 10);
  const bf16_t* W = gatwb + ((size_t)(l << 10)) * 512;
  const int tid = threadIdx.x, hg = tid >> 6, cc = tid & 63;
  const int c = blockIdx.x * 64 + cc;
  float p = 0.f;
  for (int i = 0; i < 256; ++i) {
    const int h = hg * 256 + i;
    p = fmaf((float)W[(size_t)h * 512 + c], avec[h], p);
  }
  sred[hg][cc] = p;
  float cp = 0.f;
#pragma unroll
  for (int i = 0; i < 4; ++i) cp = fmaf(gWb[(l << 10) + tid + i * 256], avec[tid + i * 256], cp);
  cred[tid] = cp;
  __syncthreads();
  if (tid < 64) wv[v * 512 + blockIdx.x * 64 + tid] = sred[0][tid] + sred[1][tid] + sred[2][tid] + sred[3][tid];
  for (int s = 128; s > 0; s >>= 1) {
    if (tid < s) cred[tid] += cred[tid + s];
    __syncthreads();
  }
  if (tid == 0 && blockIdx.x == 0) con[v] = cred[0] + ((v & 1) ? ajb[l] : aib[l]);
}

// ev[v][row] = x[row] . wv[v] + con[v]   (wave per row, all 6 vectors at once)
__global__ __launch_bounds__(256) void k_e12v(const bf16_t* __restrict__ xb,
                                              const float* __restrict__ wv, const float* __restrict__ con,
                                              float* __restrict__ ev) {
  const int tid = threadIdx.x, lane = tid & 63, wid = tid >> 6;
  const int row = blockIdx.x * 4 + wid;
  bf16x8 xv = *(const bf16x8*)(xb + (size_t)row * 512 + lane * 8);
  float xf[8];
#pragma unroll
  for (int j = 0; j < 8; ++j) xf[j] = (float)xv[j];
  float s[6];
#pragma unroll
  for (int v = 0; v < 6; ++v) {
    const float* wp = wv + v * 512 + lane * 8;
    float a = 0.f;
#pragma unroll
    for (int j = 0; j < 8; ++j) a = fmaf(xf[j], wp[j], a);
    s[v] = a;
  }
#pragma unroll
  for (int v = 0; v < 6; ++v)
#pragma unroll
    for (int off = 32; off > 0; off >>= 1) s[v] += __shfl_xor(s[v], off);
  if (lane == 0) {
#pragma unroll
    for (int v = 0; v < 6; ++v) ev[v * 8192 + row] = s[v] + con[v];
  }
}

__global__ __launch_bounds__(256) void k_eo(const float* __restrict__ Who,
                                            const float* __restrict__ ai, const float* __restrict__ aib,
                                            const float* __restrict__ aj, const float* __restrict__ ajb,
                                            float* __restrict__ eo1, float* __restrict__ eo2) {
  const int wid = threadIdx.x >> 6, lane = threadIdx.x & 63;
  const int row = blockIdx.x * 4 + wid;
  const float* wr = Who + (size_t)row * 512;
  float s1 = 0.f, s2 = 0.f;
#pragma unroll
  for (int c = 0; c < 2; ++c) {
    const int idx = c * 256 + lane * 4;
    float4 w4 = *(const float4*)&wr[idx];
    float4 a4 = *(const float4*)&ai[idx];
    float4 b4 = *(const float4*)&aj[idx];
    s1 += w4.x * a4.x + w4.y * a4.y + w4.z * a4.z + w4.w * a4.w;
    s2 += w4.x * b4.x + w4.y * b4.y + w4.z * b4.z + w4.w * b4.w;
  }
#pragma unroll
  for (int off = 32; off > 0; off >>= 1) { s1 += __shfl_xor(s1, off); s2 += __shfl_xor(s2, off); }
  if (lane == 0) { eo1[row] = s1 + aib[0]; eo2[row] = s2 + ajb[0]; }
}

// ---------------- block reduce helpers ----------------
__device__ __forceinline__ float block_max(float v, float* red) {
#pragma unroll
  for (int off = 32; off > 0; off >>= 1) v = fmaxf(v, __shfl_xor(v, off));
  __syncthreads();
  if ((threadIdx.x & 63) == 0) red[threadIdx.x >> 6] = v;
  __syncthreads();
  return fmaxf(fmaxf(red[0], red[1]), fmaxf(red[2], red[3]));
}
__device__ __forceinline__ float block_sum(float v, float* red) {
#pragma unroll
  for (int off = 32; off > 0; off >>= 1) v += __shfl_xor(v, off);
  __syncthreads();
  if ((threadIdx.x & 63) == 0) red[threadIdx.x >> 6] = v;
  __syncthreads();
  return red[0] + red[1] + red[2] + red[3];
}

// ---------------- GAT attention rows ----------------
__global__ __launch_bounds__(256) void k_gat_att(const float* __restrict__ adj, const float* __restrict__ e1,
                                                 const float* __restrict__ e2, bf16_t* __restrict__ att) {
  __shared__ float red[4];
  const int row = blockIdx.x;
  const int b = row >> 10;
  const float* arow = adj + (size_t)row * 1024;
  const float e1v = e1[row];
  const float* e2r = e2 + (b << 10);
  float s[4];
  float mx = -1e30f;
#pragma unroll
  for (int c = 0; c < 4; ++c) {
    const int m = c * 256 + threadIdx.x;
    float e = e1v + e2r[m];
    e = e > 0.f ? e : 0.2f * e;
    s[c] = arow[m] * e;
    mx = fmaxf(mx, s[c]);
  }
  mx = block_max(mx, red);
  float sum = 0.f;
#pragma unroll
  for (int c = 0; c < 4; ++c) { float p = __expf(s[c] - mx); s[c] = p; sum += p; }
  sum = block_sum(sum, red);
  const float inv = 1.f / sum;
#pragma unroll
  for (int c = 0; c < 4; ++c) att[(size_t)row * 1024 + c * 256 + threadIdx.x] = (bf16_t)(s[c] * inv);
}

// ---------------- output-attention mask rows (double softmax) ----------------
__global__ __launch_bounds__(256) void k_mask(const float* __restrict__ adj, const float* __restrict__ eo1,
                                              const float* __restrict__ eo2, bf16_t* __restrict__ mask) {
  __shared__ float red[4];
  const int row = blockIdx.x;
  const int b = row >> 10;
  const float* arow = adj + (size_t)row * 1024;
  const float t1 = eo1[row];
  const float* eor = eo2 + (b << 10);
  float s[4];
  float mx = -1e30f;
#pragma unroll
  for (int c = 0; c < 4; ++c) {
    const int m = c * 256 + threadIdx.x;
    float e = t1 + eor[m];
    e = e > 0.f ? e : 0.2f * e;
    s[c] = arow[m] * e;
    mx = fmaxf(mx, s[c]);
  }
  mx = block_max(mx, red);
  float sum = 0.f;
#pragma unroll
  for (int c = 0; c < 4; ++c) { float p = __expf(s[c] - mx); s[c] = p; sum += p; }
  sum = block_sum(sum, red);
  const float inv = 1.f / sum;
  float mx2 = -1e30f;
#pragma unroll
  for (int c = 0; c < 4; ++c) { s[c] *= inv; mx2 = fmaxf(mx2, s[c]); }
  mx2 = block_max(mx2, red);
  float sum2 = 0.f;
#pragma unroll
  for (int c = 0; c < 4; ++c) { float p = __expf(s[c] - mx2); s[c] = p; sum2 += p; }
  sum2 = block_sum(sum2, red);
  const float inv2 = 1.f / sum2;
#pragma unroll
  for (int c = 0; c < 4; ++c) mask[(size_t)row * 1024 + c * 256 + threadIdx.x] = (bf16_t)(s[c] * inv2);
}

// ---------------- mask transpose: maskT[b][k][q] = mask[b][q][k] ----------------
__global__ __launch_bounds__(256) void k_mtr(const bf16_t* __restrict__ in, bf16_t* __restrict__ out) {
  __shared__ bf16_t T[64][72];
  const int q0 = blockIdx.x * 64, k0 = blockIdx.y * 64, b = blockIdx.z;
  const bf16_t* src = in + ((size_t)b << 20);
  bf16_t* dst = out + ((size_t)b << 20);
  const int r = threadIdx.x >> 2, c = (threadIdx.x & 3) * 16;
  bf16x8 a0 = *(const bf16x8*)(src + (size_t)(q0 + r) * 1024 + k0 + c);
  bf16x8 a1 = *(const bf16x8*)(src + (size_t)(q0 + r) * 1024 + k0 + c + 8);
  *(bf16x8*)&T[r][c] = a0;
  *(bf16x8*)&T[r][c + 8] = a1;
  __syncthreads();
  union { bf16x8 v[2]; bf16_t e[16]; } o;
#pragma unroll
  for (int j = 0; j < 16; ++j) o.e[j] = T[c + j][r];
  *(bf16x8*)(dst + (size_t)(k0 + r) * 1024 + q0 + c) = o.v[0];
  *(bf16x8*)(dst + (size_t)(k0 + r) * 1024 + q0 + c + 8) = o.v[1];
}

// ---------------- MFMA flash attention v3 ----------------
// Block: 64 q-rows of one (b,h); 4 waves, wave w owns rows w*16..+15.
// No max-tracking (masked logits bounded ~|8|): p = exp(mask*S), sums reduced once
// at the end. Mask read fragment-direct from maskT (global, L2-resident).
#define LP 72
__global__ __launch_bounds__(256) void k_flash(const bf16_t* __restrict__ qg, const bf16_t* __restrict__ kg,
                                               const bf16_t* __restrict__ vTg, const bf16_t* __restrict__ maskT,
                                               bf16_t* __restrict__ aout) {
  __shared__ __align__(16) bf16_t Ks[64][LP];
  __shared__ __align__(16) bf16_t Vs[64][LP];
  __shared__ __align__(16) bf16_t PL[4][16][LP];
  const int tid = threadIdx.x, lane = tid & 63, w = tid >> 6;
  const int fr = lane & 15, fq = lane >> 4;
  const int n0 = blockIdx.x * 64, hh = blockIdx.y, bb = blockIdx.z;
  const size_t bh = ((size_t)bb * 8 + hh) << 16;
  const bf16_t* q = qg + bh;
  const bf16_t* kk = kg + bh;
  const bf16_t* vT = vTg + bh;
  const bf16_t* mT = maskT + ((size_t)bb << 20);

  bf16x8 qf[2];
#pragma unroll
  for (int ks = 0; ks < 2; ++ks)
    qf[ks] = *(const bf16x8*)(q + (size_t)(n0 + w * 16 + fr) * 64 + ks * 32 + fq * 8);

  f32x4 o[4];
#pragma unroll
  for (int nf = 0; nf < 4; ++nf) o[nf] = (f32x4)0.0f;
  float psum[4] = {0.f, 0.f, 0.f, 0.f};

  const int srow = tid >> 2, scol = (tid & 3) * 16;

  for (int c = 0; c < 16; ++c) {
    const int k0 = c * 64;
    bf16x8 kv0 = *(const bf16x8*)(kk + (size_t)(k0 + srow) * 64 + scol);
    bf16x8 kv1 = *(const bf16x8*)(kk + (size_t)(k0 + srow) * 64 + scol + 8);
    bf16x8 vv0 = *(const bf16x8*)(vT + (size_t)srow * 1024 + k0 + scol);
    bf16x8 vv1 = *(const bf16x8*)(vT + (size_t)srow * 1024 + k0 + scol + 8);
    union { ushort4 u; bf16_t h[4]; } mfr[4];
#pragma unroll
    for (int nf = 0; nf < 4; ++nf)
      mfr[nf].u = *(const ushort4*)(mT + (size_t)(k0 + nf * 16 + fr) * 1024 + n0 + w * 16 + fq * 4);
    __syncthreads();
    *(bf16x8*)&Ks[srow][scol] = kv0; *(bf16x8*)&Ks[srow][scol + 8] = kv1;
    *(bf16x8*)&Vs[srow][scol] = vv0; *(bf16x8*)&Vs[srow][scol + 8] = vv1;
    __syncthreads();

    f32x4 s[4];
#pragma unroll
    for (int nf = 0; nf < 4; ++nf) s[nf] = (f32x4)0.0f;
#pragma unroll
    for (int ks = 0; ks < 2; ++ks) {
      bf16x8 kf[4];
#pragma unroll
      for (int nf = 0; nf < 4; ++nf)
        kf[nf] = *(const bf16x8*)&Ks[nf * 16 + fr][ks * 32 + fq * 8];
#pragma unroll
      for (int nf = 0; nf < 4; ++nf)
        s[nf] = __builtin_amdgcn_mfma_f32_16x16x32_bf16(qf[ks], kf[nf], s[nf], 0, 0, 0);
    }

#pragma unroll
    for (int nf = 0; nf < 4; ++nf)
#pragma unroll
      for (int r = 0; r < 4; ++r) {
        const float p = __expf(s[nf][r] * (float)mfr[nf].h[r]);
        psum[r] += p;
        PL[w][fq * 4 + r][nf * 16 + fr] = (bf16_t)p;
      }

#pragma unroll
    for (int ks = 0; ks < 2; ++ks) {
      bf16x8 pf = *(const bf16x8*)&PL[w][fr][ks * 32 + fq * 8];
      bf16x8 vf[4];
#pragma unroll
      for (int nfo = 0; nfo < 4; ++nfo)
        vf[nfo] = *(const bf16x8*)&Vs[nfo * 16 + fr][ks * 32 + fq * 8];
#pragma unroll
      for (int nfo = 0; nfo < 4; ++nfo)
        o[nfo] = __builtin_amdgcn_mfma_f32_16x16x32_bf16(pf, vf[nfo], o[nfo], 0, 0, 0);
    }
  }

#pragma unroll
  for (int r = 0; r < 4; ++r) {
    psum[r] += __shfl_xor(psum[r], 1);
    psum[r] += __shfl_xor(psum[r], 2);
    psum[r] += __shfl_xor(psum[r], 4);
    psum[r] += __shfl_xor(psum[r], 8);
  }
#pragma unroll
  for (int r = 0; r < 4; ++r) {
    const int tok = n0 + w * 16 + fq * 4 + r;
    const float inv = 1.f / psum[r];
#pragma unroll
    for (int nfo = 0; nfo < 4; ++nfo)
      aout[((size_t)(bb << 10) + tok) * 512 + hh * 64 + nfo * 16 + fr] = (bf16_t)(o[nfo][r] * inv);
  }
}

// ---------------- launcher ----------------
extern "C" void kernel_launch(void* const* d_in, const int* in_sizes, int n_in,
                              void* d_out, int out_size, void* d_ws, size_t ws_size,
                              hipStream_t stream) {
  (void)in_sizes; (void)n_in; (void)out_size; (void)ws_size;
  const float* x        = (const float*)d_in[0];
  const float* adj      = (const float*)d_in[1];
  const float* qkv_w    = (const float*)d_in[2];
  const float* proj_w   = (const float*)d_in[3];
  const float* proj_b   = (const float*)d_in[4];
  const float* gat_W    = (const float*)d_in[5];
  const float* gat_Wb   = (const float*)d_in[6];
  const float* gat_ai   = (const float*)d_in[7];
  const float* gat_ai_b = (const float*)d_in[8];
  const float* gat_aj   = (const float*)d_in[9];
  const float* gat_aj_b = (const float*)d_in[10];
  const float* out_W    = (const float*)d_in[11];
  const float* out_Wb   = (const float*)d_in[12];
  const float* out_ai   = (const float*)d_in[13];
  const float* out_ai_b = (const float*)d_in[14];
  const float* out_aj   = (const float*)d_in[15];
  const float* out_aj_b = (const float*)d_in[16];

  char* p = (char*)d_ws;
  auto alloc = [&](size_t bytes) { char* r = p; p += (bytes + 255) & ~(size_t)255; return r; };
  bf16_t* xb     = (bf16_t*)alloc(8192ull * 512 * 2);
  bf16_t* qkvwb  = (bf16_t*)alloc(1536ull * 512 * 2);
  bf16_t* gatwb  = (bf16_t*)alloc(3072ull * 512 * 2);
  bf16_t* outwb  = (bf16_t*)alloc(512ull * 3072 * 2);
  bf16_t* projwb = (bf16_t*)alloc(512ull * 512 * 2);
  bf16_t* qb     = (bf16_t*)alloc(8ull * 8 * 1024 * 64 * 2);   // [b,h,tok,64]
  bf16_t* kb     = (bf16_t*)alloc(8ull * 8 * 1024 * 64 * 2);   // [b,h,tok,64]
  bf16_t* vT     = (bf16_t*)alloc(8ull * 8 * 64 * 1024 * 2);   // [b,h,64,tok]
  bf16_t* WhT    = (bf16_t*)alloc(8ull * 1024 * 1024 * 2);     // [b][h][m]
  bf16_t* att    = (bf16_t*)alloc(8ull * 1024 * 1024 * 2);     // reused as mask
  bf16_t* hh     = (bf16_t*)alloc(8192ull * 1024 * 2);
  float*  Who    = (float*)alloc(8192ull * 512 * 4);
  bf16_t* aout   = (bf16_t*)alloc(8192ull * 512 * 2);
  bf16_t* maskT  = (bf16_t*)alloc(8ull * 1024 * 1024 * 2);     // [b][k][q]
  float*  wv     = (float*)alloc(6 * 512 * 4);
  float*  con    = (float*)alloc(6 * 4);
  float*  ev     = (float*)alloc(6 * 8192 * 4);
  float*  eo1    = (float*)alloc(8192 * 4);
  float*  eo2    = (float*)alloc(8192 * 4);
  bf16_t* mask   = att;

  const dim3 blk(256);
  k_cast<<<4096, blk, 0, stream>>>(x, xb, 1048576);
  k_cast<<<768,  blk, 0, stream>>>(qkv_w, qkvwb, 196608);
  k_cast<<<1536, blk, 0, stream>>>(gat_W, gatwb, 393216);
  k_cast<<<1536, blk, 0, stream>>>(out_W, outwb, 393216);
  k_cast<<<256,  blk, 0, stream>>>(proj_w, projwb, 65536);

  k_wvec<<<dim3(8, 6), blk, 0, stream>>>(gatwb, gat_Wb, gat_ai, gat_ai_b, gat_aj, gat_aj_b, wv, con);
  k_e12v<<<2048, blk, 0, stream>>>(xb, wv, con, ev);

  k_qkv<<<dim3(12, 64), blk, 0, stream>>>(xb, qkvwb, qb, kb, vT);
  for (int l = 0; l < 3; ++l) {
    k_wh<<<dim3(8, 64), blk, 0, stream>>>(xb, gatwb + (size_t)l * 1024 * 512, gat_Wb + l * 1024, WhT);
    k_gat_att<<<8192, blk, 0, stream>>>(adj, ev + (size_t)(2 * l) * 8192, ev + (size_t)(2 * l + 1) * 8192, att);
    k_hhat<<<dim3(8, 8, 8), blk, 0, stream>>>(att, WhT, hh);
    k_who_acc<<<dim3(4, 64), blk, 0, stream>>>(hh, outwb + l * 1024, out_Wb, Who, l);
  }
  k_eo<<<2048, blk, 0, stream>>>(Who, out_ai, out_ai_b, out_aj, out_aj_b, eo1, eo2);
  k_mask<<<8192, blk, 0, stream>>>(adj, eo1, eo2, mask);
  k_mtr<<<dim3(16, 16, 8), blk, 0, stream>>>(mask, maskT);
  k_flash<<<dim3(16, 8, 8), blk, 0, stream>>>(qb, kb, vT, maskT, aout);
  k_proj<<<dim3(4, 64), blk, 0, stream>>>(aout, projwb, proj_b, (float*)d_out);
}

// Round 7
// 383.372 us; speedup vs baseline: 5.2374x; 1.1336x over previous
//
#include <hip/hip_runtime.h>
#include <math.h>
#include <stdint.h>

#define SCALEQ 0.125f

typedef __bf16 bf16_t;
typedef __bf16 bf16x8 __attribute__((ext_vector_type(8)));
typedef float f32x4 __attribute__((ext_vector_type(4)));

// global -> LDS async copy, 16B per lane. LDS dest is wave-uniform base + lane*16.
#define GLOAD_LDS16(gsrc, ldst)                                                   \
  __builtin_amdgcn_global_load_lds(                                               \
      (const __attribute__((address_space(1))) void*)(uintptr_t)(const void*)(gsrc), \
      (__attribute__((address_space(3))) void*)(uintptr_t)(void*)(ldst), 16, 0, 0)

// ---------------- bf16 MFMA GEMM core (128x128 tile, 4 waves, BK=64) ----------------
__device__ __forceinline__ void mm_bf16(const bf16_t* __restrict__ A, int lda,
                                        const bf16_t* __restrict__ B, int ldb,
                                        int K, int m0, int n0,
                                        bf16_t* As, bf16_t* Bs, f32x4 (&acc)[4][4]) {
  const int tid = threadIdx.x, lane = tid & 63, w = tid >> 6;
  const int wr = (w >> 1) * 64, wc = (w & 1) * 64;
  const int fr = lane & 15, fq = lane >> 4;
  for (int kt = 0; kt < K; kt += 64) {
    __syncthreads();
#pragma unroll
    for (int t = 0; t < 4; ++t) {
      const int rl = t * 32 + w * 8 + (lane >> 3);
      const int c8 = (lane & 7) * 8;
      GLOAD_LDS16(A + (size_t)(m0 + rl) * lda + kt + c8, As + (t * 32 + w * 8) * 64);
      GLOAD_LDS16(B + (size_t)(n0 + rl) * ldb + kt + c8, Bs + (t * 32 + w * 8) * 64);
    }
    __syncthreads();
#pragma unroll
    for (int ks = 0; ks < 2; ++ks) {
      bf16x8 af[4], bfv[4];
#pragma unroll
      for (int mf = 0; mf < 4; ++mf)
        af[mf] = *(const bf16x8*)(As + (wr + mf * 16 + fr) * 64 + ks * 32 + fq * 8);
#pragma unroll
      for (int nf = 0; nf < 4; ++nf)
        bfv[nf] = *(const bf16x8*)(Bs + (wc + nf * 16 + fr) * 64 + ks * 32 + fq * 8);
#pragma unroll
      for (int mf = 0; mf < 4; ++mf)
#pragma unroll
        for (int nf = 0; nf < 4; ++nf)
          acc[mf][nf] = __builtin_amdgcn_mfma_f32_16x16x32_bf16(af[mf], bfv[nf], acc[mf][nf], 0, 0, 0);
    }
  }
}

#define MM_PROLOGUE()                                  \
  __shared__ __align__(16) bf16_t As[128 * 64];        \
  __shared__ __align__(16) bf16_t Bs[128 * 64];        \
  f32x4 acc[4][4];                                     \
  _Pragma("unroll") for (int i_ = 0; i_ < 4; ++i_)     \
  _Pragma("unroll") for (int j_ = 0; j_ < 4; ++j_) acc[i_][j_] = (f32x4)0.0f;

#define MM_EPI_SETUP(M0, N0)                                   \
  const int lane = threadIdx.x & 63, w = threadIdx.x >> 6;     \
  const int fr = lane & 15, fq = lane >> 4;                    \
  const int mb = (M0) + (w >> 1) * 64, nb = (N0) + (w & 1) * 64;

// ---------------- GEMM kernels ----------------
// qkv: q,k -> bf16 [b,h,tok,64] (q pre-scaled); v -> bf16 transposed [b,h,64,tok]
__global__ __launch_bounds__(256) void k_qkv(const bf16_t* __restrict__ xb, const bf16_t* __restrict__ wb,
                                             bf16_t* __restrict__ qb, bf16_t* __restrict__ kb,
                                             bf16_t* __restrict__ vT) {
  MM_PROLOGUE();
  const int m0 = blockIdx.y * 128, n0 = blockIdx.x * 128;
  mm_bf16(xb, 512, wb, 512, 512, m0, n0, As, Bs, acc);
  MM_EPI_SETUP(m0, n0);
#pragma unroll
  for (int mf = 0; mf < 4; ++mf)
#pragma unroll
    for (int nf = 0; nf < 4; ++nf) {
      const int n = nb + nf * 16 + fr;
      const int which = n >> 9, hd = (n >> 6) & 7, d = n & 63;
      const int m_ = mb + mf * 16 + fq * 4;
      const int b = m_ >> 10, tok0 = m_ & 1023;
      if (which == 2) {
        union { ushort4 u; bf16_t q[4]; } pk;
#pragma unroll
        for (int r = 0; r < 4; ++r) pk.q[r] = (bf16_t)acc[mf][nf][r];
        *(ushort4*)(vT + (((size_t)b * 8 + hd) * 64 + d) * 1024 + tok0) = pk.u;
      } else {
        bf16_t* dst = which ? kb : qb;
        const float sc = which ? 1.f : SCALEQ;
#pragma unroll
        for (int r = 0; r < 4; ++r)
          dst[(((size_t)b * 8 + hd) * 1024 + tok0 + r) * 64 + d] = (bf16_t)(acc[mf][nf][r] * sc);
      }
    }
}

// Wh_l^T (per batch): WhT[l][b][h][m], bf16. l = blockIdx.z (batched) or 0 (pre-offset bases).
__global__ __launch_bounds__(256) void k_wh(const bf16_t* __restrict__ xb, const bf16_t* __restrict__ gatw,
                                            const float* __restrict__ gWb, bf16_t* __restrict__ WhT) {
  MM_PROLOGUE();
  const int m0 = blockIdx.y * 128, n0 = blockIdx.x * 128, l = blockIdx.z;
  const bf16_t* Wl = gatw + (size_t)l * 524288;
  const float* Wb = gWb + l * 1024;
  bf16_t* out = WhT + (size_t)l * 8388608;
  mm_bf16(xb, 512, Wl, 512, 512, m0, n0, As, Bs, acc);
  MM_EPI_SETUP(m0, n0);
#pragma unroll
  for (int mf = 0; mf < 4; ++mf)
#pragma unroll
    for (int nf = 0; nf < 4; ++nf) {
      const int h = nb + nf * 16 + fr;
      const float bias = Wb[h];
      const int m_ = mb + mf * 16 + fq * 4;
      const int b = m_ >> 10, ml = m_ & 1023;
      union { ushort4 u; bf16_t q[4]; } pk;
#pragma unroll
      for (int r = 0; r < 4; ++r) pk.q[r] = (bf16_t)(acc[mf][nf][r] + bias);
      *(ushort4*)(out + (((size_t)b << 10) + h) * 1024 + ml) = pk.u;
    }
}

// hh = elu(att_lb @ Wh_lb); z -> (l = z>>3, b = z&7). Writes hh[(b*1024+m)*ldh + l*1024 + n].
__global__ __launch_bounds__(256) void k_hhat(const bf16_t* __restrict__ att, const bf16_t* __restrict__ WhT,
                                              bf16_t* __restrict__ hh, int ldh) {
  MM_PROLOGUE();
  const int m0 = blockIdx.y * 128, n0 = blockIdx.x * 128;
  const int l = blockIdx.z >> 3, bz = blockIdx.z & 7;
  const size_t off = ((size_t)(l * 8 + bz)) << 20;
  mm_bf16(att + off, 1024, WhT + off, 1024, 1024, m0, n0, As, Bs, acc);
  MM_EPI_SETUP(m0, n0);
#pragma unroll
  for (int mf = 0; mf < 4; ++mf)
#pragma unroll
    for (int nf = 0; nf < 4; ++nf) {
      const int n = nb + nf * 16 + fr;
#pragma unroll
      for (int r = 0; r < 4; ++r) {
        const int m = mb + mf * 16 + fq * 4 + r;
        float v = acc[mf][nf][r];
        v = v > 0.f ? v : (__expf(v) - 1.f);
        hh[(size_t)((bz << 10) + m) * ldh + l * 1024 + n] = (bf16_t)v;
      }
    }
}

// generic GEMM + bias -> f32 out: out[m][n] = A[m]:K . B[n]:K + bias[n]  (ldb == K)
__global__ __launch_bounds__(256) void k_lin(const bf16_t* __restrict__ A, int lda,
                                             const bf16_t* __restrict__ B, int K,
                                             const float* __restrict__ bias, float* __restrict__ out) {
  MM_PROLOGUE();
  const int m0 = blockIdx.y * 128, n0 = blockIdx.x * 128;
  mm_bf16(A, lda, B, K, K, m0, n0, As, Bs, acc);
  MM_EPI_SETUP(m0, n0);
#pragma unroll
  for (int mf = 0; mf < 4; ++mf)
#pragma unroll
    for (int nf = 0; nf < 4; ++nf) {
      const int n = nb + nf * 16 + fr;
#pragma unroll
      for (int r = 0; r < 4; ++r) {
        const int m = mb + mf * 16 + fq * 4 + r;
        out[(size_t)m * 512 + n] = acc[mf][nf][r] + bias[n];
      }
    }
}

// fallback: Who (+)= hh @ out_W[:, l*1024:+1024].T (bias folded at l==0)
__global__ __launch_bounds__(256) void k_who_acc(const bf16_t* __restrict__ hh, const bf16_t* __restrict__ Wl,
                                                 const float* __restrict__ Wb, float* __restrict__ Who, int l) {
  MM_PROLOGUE();
  const int m0 = blockIdx.y * 128, n0 = blockIdx.x * 128;
  mm_bf16(hh, 1024, Wl, 3072, 1024, m0, n0, As, Bs, acc);
  MM_EPI_SETUP(m0, n0);
#pragma unroll
  for (int mf = 0; mf < 4; ++mf)
#pragma unroll
    for (int nf = 0; nf < 4; ++nf) {
      const int n = nb + nf * 16 + fr;
#pragma unroll
      for (int r = 0; r < 4; ++r) {
        const int m = mb + mf * 16 + fq * 4 + r;
        const size_t idx = (size_t)m * 512 + n;
        Who[idx] = acc[mf][nf][r] + (l == 0 ? Wb[n] : Who[idx]);
      }
    }
}

// ---------------- fused casts f32 -> bf16 (5 segments) ----------------
__global__ __launch_bounds__(256) void k_cast5(const float* __restrict__ s0, bf16_t* __restrict__ d0, int c0,
                                               const float* __restrict__ s1, bf16_t* __restrict__ d1, int c1,
                                               const float* __restrict__ s2, bf16_t* __restrict__ d2, int c2,
                                               const float* __restrict__ s3, bf16_t* __restrict__ d3, int c3,
                                               const float* __restrict__ s4, bf16_t* __restrict__ d4, int c4) {
  int i = blockIdx.x * 256 + threadIdx.x;
  const float* src; bf16_t* dst; int j;
  if (i < c0)      { src = s0; dst = d0; j = i; }
  else if (i < c1) { src = s1; dst = d1; j = i - c0; }
  else if (i < c2) { src = s2; dst = d2; j = i - c1; }
  else if (i < c3) { src = s3; dst = d3; j = i - c2; }
  else if (i < c4) { src = s4; dst = d4; j = i - c3; }
  else return;
  float4 v = ((const float4*)src)[j];
  union { ushort4 u; bf16_t b[4]; } p;
  p.b[0] = (bf16_t)v.x; p.b[1] = (bf16_t)v.y; p.b[2] = (bf16_t)v.z; p.b[3] = (bf16_t)v.w;
  ((ushort4*)dst)[j] = p.u;
}

// ---------------- algebraic e1/e2 ----------------
__global__ __launch_bounds__(256) void k_wvec(const bf16_t* __restrict__ gatwb,
                                              const float* __restrict__ gWb,
                                              const float* __restrict__ ai, const float* __restrict__ aib,
                                              const float* __restrict__ aj, const float* __restrict__ ajb,
                                              float* __restrict__ wv, float* __restrict__ con) {
  __shared__ float sred[4][64];
  __shared__ float cred[256];
  const int v = blockIdx.y, l = v >> 1;
  const float* avec = ((v & 1) ? aj : ai) + (l << 10);
  const bf16_t* W = gatwb + ((size_t)(l << 10)) * 512;
  const int tid = threadIdx.x, hg = tid >> 6, cc = tid & 63;
  const int c = blockIdx.x * 64 + cc;
  float p = 0.f;
  for (int i = 0; i < 256; ++i) {
    const int h = hg * 256 + i;
    p = fmaf((float)W[(size_t)h * 512 + c], avec[h], p);
  }
  sred[hg][cc] = p;
  float cp = 0.f;
#pragma unroll
  for (int i = 0; i < 4; ++i) cp = fmaf(gWb[(l << 10) + tid + i * 256], avec[tid + i * 256], cp);
  cred[tid] = cp;
  __syncthreads();
  if (tid < 64) wv[v * 512 + blockIdx.x * 64 + tid] = sred[0][tid] + sred[1][tid] + sred[2][tid] + sred[3][tid];
  for (int s = 128; s > 0; s >>= 1) {
    if (tid < s) cred[tid] += cred[tid + s];
    __syncthreads();
  }
  if (tid == 0 && blockIdx.x == 0) con[v] = cred[0] + ((v & 1) ? ajb[l] : aib[l]);
}

__global__ __launch_bounds__(256) void k_e12v(const bf16_t* __restrict__ xb,
                                              const float* __restrict__ wv, const float* __restrict__ con,
                                              float* __restrict__ ev) {
  const int tid = threadIdx.x, lane = tid & 63, wid = tid >> 6;
  const int row = blockIdx.x * 4 + wid;
  bf16x8 xv = *(const bf16x8*)(xb + (size_t)row * 512 + lane * 8);
  float xf[8];
#pragma unroll
  for (int j = 0; j < 8; ++j) xf[j] = (float)xv[j];
  float s[6];
#pragma unroll
  for (int v = 0; v < 6; ++v) {
    const float* wp = wv + v * 512 + lane * 8;
    float a = 0.f;
#pragma unroll
    for (int j = 0; j < 8; ++j) a = fmaf(xf[j], wp[j], a);
    s[v] = a;
  }
#pragma unroll
  for (int v = 0; v < 6; ++v)
#pragma unroll
    for (int off = 32; off > 0; off >>= 1) s[v] += __shfl_xor(s[v], off);
  if (lane == 0) {
#pragma unroll
    for (int v = 0; v < 6; ++v) ev[v * 8192 + row] = s[v] + con[v];
  }
}

__global__ __launch_bounds__(256) void k_eo(const float* __restrict__ Who,
                                            const float* __restrict__ ai, const float* __restrict__ aib,
                                            const float* __restrict__ aj, const float* __restrict__ ajb,
                                            float* __restrict__ eo1, float* __restrict__ eo2) {
  const int wid = threadIdx.x >> 6, lane = threadIdx.x & 63;
  const int row = blockIdx.x * 4 + wid;
  const float* wr = Who + (size_t)row * 512;
  float s1 = 0.f, s2 = 0.f;
#pragma unroll
  for (int c = 0; c < 2; ++c) {
    const int idx = c * 256 + lane * 4;
    float4 w4 = *(const float4*)&wr[idx];
    float4 a4 = *(const float4*)&ai[idx];
    float4 b4 = *(const float4*)&aj[idx];
    s1 += w4.x * a4.x + w4.y * a4.y + w4.z * a4.z + w4.w * a4.w;
    s2 += w4.x * b4.x + w4.y * b4.y + w4.z * b4.z + w4.w * b4.w;
  }
#pragma unroll
  for (int off = 32; off > 0; off >>= 1) { s1 += __shfl_xor(s1, off); s2 += __shfl_xor(s2, off); }
  if (lane == 0) { eo1[row] = s1 + aib[0]; eo2[row] = s2 + ajb[0]; }
}

// ---------------- block reduce helpers ----------------
__device__ __forceinline__ float block_max(float v, float* red) {
#pragma unroll
  for (int off = 32; off > 0; off >>= 1) v = fmaxf(v, __shfl_xor(v, off));
  __syncthreads();
  if ((threadIdx.x & 63) == 0) red[threadIdx.x >> 6] = v;
  __syncthreads();
  return fmaxf(fmaxf(red[0], red[1]), fmaxf(red[2], red[3]));
}
__device__ __forceinline__ float block_sum(float v, float* red) {
#pragma unroll
  for (int off = 32; off > 0; off >>= 1) v += __shfl_xor(v, off);
  __syncthreads();
  if ((threadIdx.x & 63) == 0) red[threadIdx.x >> 6] = v;
  __syncthreads();
  return red[0] + red[1] + red[2] + red[3];
}

// ---------------- GAT attention rows; l = blockIdx.y (batched) or 0 ----------------
__global__ __launch_bounds__(256) void k_gat_att(const float* __restrict__ adj, const float* __restrict__ ev,
                                                 bf16_t* __restrict__ att) {
  __shared__ float red[4];
  const int row = blockIdx.x, l = blockIdx.y;
  const int b = row >> 10;
  const float* arow = adj + (size_t)row * 1024;
  const float e1v = ev[l * 16384 + row];
  const float* e2r = ev + l * 16384 + 8192 + (b << 10);
  bf16_t* aout = att + (size_t)l * 8388608 + (size_t)row * 1024;
  float s[4];
  float mx = -1e30f;
#pragma unroll
  for (int c = 0; c < 4; ++c) {
    const int m = c * 256 + threadIdx.x;
    float e = e1v + e2r[m];
    e = e > 0.f ? e : 0.2f * e;
    s[c] = arow[m] * e;
    mx = fmaxf(mx, s[c]);
  }
  mx = block_max(mx, red);
  float sum = 0.f;
#pragma unroll
  for (int c = 0; c < 4; ++c) { float p = __expf(s[c] - mx); s[c] = p; sum += p; }
  sum = block_sum(sum, red);
  const float inv = 1.f / sum;
#pragma unroll
  for (int c = 0; c < 4; ++c) aout[c * 256 + threadIdx.x] = (bf16_t)(s[c] * inv);
}

// ---------------- output-attention mask rows (double softmax) ----------------
__global__ __launch_bounds__(256) void k_mask(const float* __restrict__ adj, const float* __restrict__ eo1,
                                              const float* __restrict__ eo2, bf16_t* __restrict__ mask) {
  __shared__ float red[4];
  const int row = blockIdx.x;
  const int b = row >> 10;
  const float* arow = adj + (size_t)row * 1024;
  const float t1 = eo1[row];
  const float* eor = eo2 + (b << 10);
  float s[4];
  float mx = -1e30f;
#pragma unroll
  for (int c = 0; c < 4; ++c) {
    const int m = c * 256 + threadIdx.x;
    float e = t1 + eor[m];
    e = e > 0.f ? e : 0.2f * e;
    s[c] = arow[m] * e;
    mx = fmaxf(mx, s[c]);
  }
  mx = block_max(mx, red);
  float sum = 0.f;
#pragma unroll
  for (int c = 0; c < 4; ++c) { float p = __expf(s[c] - mx); s[c] = p; sum += p; }
  sum = block_sum(sum, red);
  const float inv = 1.f / sum;
  float mx2 = -1e30f;
#pragma unroll
  for (int c = 0; c < 4; ++c) { s[c] *= inv; mx2 = fmaxf(mx2, s[c]); }
  mx2 = block_max(mx2, red);
  float sum2 = 0.f;
#pragma unroll
  for (int c = 0; c < 4; ++c) { float p = __expf(s[c] - mx2); s[c] = p; sum2 += p; }
  sum2 = block_sum(sum2, red);
  const float inv2 = 1.f / sum2;
#pragma unroll
  for (int c = 0; c < 4; ++c) mask[(size_t)row * 1024 + c * 256 + threadIdx.x] = (bf16_t)(s[c] * inv2);
}

// ---------------- mask transpose ----------------
__global__ __launch_bounds__(256) void k_mtr(const bf16_t* __restrict__ in, bf16_t* __restrict__ out) {
  __shared__ bf16_t T[64][72];
  const int q0 = blockIdx.x * 64, k0 = blockIdx.y * 64, b = blockIdx.z;
  const bf16_t* src = in + ((size_t)b << 20);
  bf16_t* dst = out + ((size_t)b << 20);
  const int r = threadIdx.x >> 2, c = (threadIdx.x & 3) * 16;
  bf16x8 a0 = *(const bf16x8*)(src + (size_t)(q0 + r) * 1024 + k0 + c);
  bf16x8 a1 = *(const bf16x8*)(src + (size_t)(q0 + r) * 1024 + k0 + c + 8);
  *(bf16x8*)&T[r][c] = a0;
  *(bf16x8*)&T[r][c + 8] = a1;
  __syncthreads();
  union { bf16x8 v[2]; bf16_t e[16]; } o;
#pragma unroll
  for (int j = 0; j < 16; ++j) o.e[j] = T[c + j][r];
  *(bf16x8*)(dst + (size_t)(k0 + r) * 1024 + q0 + c) = o.v[0];
  *(bf16x8*)(dst + (size_t)(k0 + r) * 1024 + q0 + c + 8) = o.v[1];
}

// ---------------- MFMA flash attention (XOR-swizzled K/V LDS) ----------------
// Ks/Vs: 64 rows x 8 slots of 8 bf16; element addr = row*64 + ((slot ^ (row&7))<<3).
__device__ __forceinline__ int swz(int row, int slot) { return row * 64 + ((slot ^ (row & 7)) << 3); }

__global__ __launch_bounds__(256) void k_flash(const bf16_t* __restrict__ qg, const bf16_t* __restrict__ kg,
                                               const bf16_t* __restrict__ vTg, const bf16_t* __restrict__ maskT,
                                               bf16_t* __restrict__ aout) {
  __shared__ __align__(16) bf16_t Ks[4096];
  __shared__ __align__(16) bf16_t Vs[4096];
  __shared__ __align__(16) bf16_t PL[4][16][72];
  const int tid = threadIdx.x, lane = tid & 63, w = tid >> 6;
  const int fr = lane & 15, fq = lane >> 4;
  const int n0 = blockIdx.x * 64, hh = blockIdx.y, bb = blockIdx.z;
  const size_t bh = ((size_t)bb * 8 + hh) << 16;
  const bf16_t* q = qg + bh;
  const bf16_t* kk = kg + bh;
  const bf16_t* vT = vTg + bh;
  const bf16_t* mT = maskT + ((size_t)bb << 20);

  bf16x8 qf[2];
#pragma unroll
  for (int ks = 0; ks < 2; ++ks)
    qf[ks] = *(const bf16x8*)(q + (size_t)(n0 + w * 16 + fr) * 64 + ks * 32 + fq * 8);

  f32x4 o[4];
#pragma unroll
  for (int nf = 0; nf < 4; ++nf) o[nf] = (f32x4)0.0f;
  float psum[4] = {0.f, 0.f, 0.f, 0.f};

  const int srow = tid >> 2, sslot = (tid & 3) * 2;
  const int ws0 = swz(srow, sslot), ws1 = swz(srow, sslot + 1);
  const int scol = (tid & 3) * 16;

  for (int c = 0; c < 16; ++c) {
    const int k0 = c * 64;
    bf16x8 kv0 = *(const bf16x8*)(kk + (size_t)(k0 + srow) * 64 + scol);
    bf16x8 kv1 = *(const bf16x8*)(kk + (size_t)(k0 + srow) * 64 + scol + 8);
    bf16x8 vv0 = *(const bf16x8*)(vT + (size_t)srow * 1024 + k0 + scol);
    bf16x8 vv1 = *(const bf16x8*)(vT + (size_t)srow * 1024 + k0 + scol + 8);
    union { ushort4 u; bf16_t h[4]; } mfr[4];
#pragma unroll
    for (int nf = 0; nf < 4; ++nf)
      mfr[nf].u = *(const ushort4*)(mT + (size_t)(k0 + nf * 16 + fr) * 1024 + n0 + w * 16 + fq * 4);
    __syncthreads();
    *(bf16x8*)&Ks[ws0] = kv0; *(bf16x8*)&Ks[ws1] = kv1;
    *(bf16x8*)&Vs[ws0] = vv0; *(bf16x8*)&Vs[ws1] = vv1;
    __syncthreads();

    f32x4 s[4];
#pragma unroll
    for (int nf = 0; nf < 4; ++nf) s[nf] = (f32x4)0.0f;
#pragma unroll
    for (int ks = 0; ks < 2; ++ks) {
      bf16x8 kf[4];
#pragma unroll
      for (int nf = 0; nf < 4; ++nf)
        kf[nf] = *(const bf16x8*)&Ks[swz(nf * 16 + fr, ks * 4 + fq)];
#pragma unroll
      for (int nf = 0; nf < 4; ++nf)
        s[nf] = __builtin_amdgcn_mfma_f32_16x16x32_bf16(qf[ks], kf[nf], s[nf], 0, 0, 0);
    }

#pragma unroll
    for (int nf = 0; nf < 4; ++nf)
#pragma unroll
      for (int r = 0; r < 4; ++r) {
        const float p = __expf(s[nf][r] * (float)mfr[nf].h[r]);
        psum[r] += p;
        PL[w][fq * 4 + r][nf * 16 + fr] = (bf16_t)p;
      }

#pragma unroll
    for (int ks = 0; ks < 2; ++ks) {
      bf16x8 pf = *(const bf16x8*)&PL[w][fr][ks * 32 + fq * 8];
      bf16x8 vf[4];
#pragma unroll
      for (int nfo = 0; nfo < 4; ++nfo)
        vf[nfo] = *(const bf16x8*)&Vs[swz(nfo * 16 + fr, ks * 4 + fq)];
#pragma unroll
      for (int nfo = 0; nfo < 4; ++nfo)
        o[nfo] = __builtin_amdgcn_mfma_f32_16x16x32_bf16(pf, vf[nfo], o[nfo], 0, 0, 0);
    }
  }

#pragma unroll
  for (int r = 0; r < 4; ++r) {
    psum[r] += __shfl_xor(psum[r], 1);
    psum[r] += __shfl_xor(psum[r], 2);
    psum[r] += __shfl_xor(psum[r], 4);
    psum[r] += __shfl_xor(psum[r], 8);
  }
#pragma unroll
  for (int r = 0; r < 4; ++r) {
    const int tok = n0 + w * 16 + fq * 4 + r;
    const float inv = 1.f / psum[r];
#pragma unroll
    for (int nfo = 0; nfo < 4; ++nfo)
      aout[((size_t)(bb << 10) + tok) * 512 + hh * 64 + nfo * 16 + fr] = (bf16_t)(o[nfo][r] * inv);
  }
}

// ---------------- launcher ----------------
extern "C" void kernel_launch(void* const* d_in, const int* in_sizes, int n_in,
                              void* d_out, int out_size, void* d_ws, size_t ws_size,
                              hipStream_t stream) {
  (void)in_sizes; (void)n_in; (void)out_size;
  const float* x        = (const float*)d_in[0];
  const float* adj      = (const float*)d_in[1];
  const float* qkv_w    = (const float*)d_in[2];
  const float* proj_w   = (const float*)d_in[3];
  const float* proj_b   = (const float*)d_in[4];
  const float* gat_W    = (const float*)d_in[5];
  const float* gat_Wb   = (const float*)d_in[6];
  const float* gat_ai   = (const float*)d_in[7];
  const float* gat_ai_b = (const float*)d_in[8];
  const float* gat_aj   = (const float*)d_in[9];
  const float* gat_aj_b = (const float*)d_in[10];
  const float* out_W    = (const float*)d_in[11];
  const float* out_Wb   = (const float*)d_in[12];
  const float* out_ai   = (const float*)d_in[13];
  const float* out_ai_b = (const float*)d_in[14];
  const float* out_aj   = (const float*)d_in[15];
  const float* out_aj_b = (const float*)d_in[16];

  char* p = (char*)d_ws;
  auto alloc = [&](size_t bytes) { char* r = p; p += (bytes + 255) & ~(size_t)255; return r; };
  // common allocations
  bf16_t* xb     = (bf16_t*)alloc(8192ull * 512 * 2);
  bf16_t* qkvwb  = (bf16_t*)alloc(1536ull * 512 * 2);
  bf16_t* gatwb  = (bf16_t*)alloc(3072ull * 512 * 2);
  bf16_t* outwb  = (bf16_t*)alloc(512ull * 3072 * 2);
  bf16_t* projwb = (bf16_t*)alloc(512ull * 512 * 2);
  bf16_t* qb     = (bf16_t*)alloc(8ull * 8 * 1024 * 64 * 2);
  bf16_t* kb     = (bf16_t*)alloc(8ull * 8 * 1024 * 64 * 2);
  bf16_t* vT     = (bf16_t*)alloc(8ull * 8 * 64 * 1024 * 2);
  float*  Who    = (float*)alloc(8192ull * 512 * 4);
  float*  wv     = (float*)alloc(6 * 512 * 4);
  float*  con    = (float*)alloc(256);
  float*  ev     = (float*)alloc(6 * 8192 * 4);
  float*  eo1    = (float*)alloc(8192 * 4);
  float*  eo2    = (float*)alloc(8192 * 4);

  const bool big = ws_size >= 211000000ull;   // batched path needs ~210 MB

  const dim3 blk(256);
  k_cast5<<<8192, blk, 0, stream>>>(x, xb, 1048576, qkv_w, qkvwb, 1245184, gat_W, gatwb, 1638400,
                                    out_W, outwb, 2031616, proj_w, projwb, 2097152);
  k_wvec<<<dim3(8, 6), blk, 0, stream>>>(gatwb, gat_Wb, gat_ai, gat_ai_b, gat_aj, gat_aj_b, wv, con);
  k_e12v<<<2048, blk, 0, stream>>>(xb, wv, con, ev);
  k_qkv<<<dim3(12, 64), blk, 0, stream>>>(xb, qkvwb, qb, kb, vT);

  if (big) {
    bf16_t* WhT3 = (bf16_t*)alloc(3ull * 8 * 1024 * 1024 * 2);   // 48 MB
    bf16_t* att3 = (bf16_t*)alloc(3ull * 8 * 1024 * 1024 * 2);   // 48 MB
    bf16_t* hh3  = (bf16_t*)alloc(8192ull * 3072 * 2);           // 48 MB [m][3*1024]
    bf16_t* mask  = att3;                      // att3[0] dead after hhat
    bf16_t* maskT = att3 + 8388608;            // att3[1]
    bf16_t* aoutb = att3 + 2 * 8388608;        // att3[2]

    k_wh<<<dim3(8, 64, 3), blk, 0, stream>>>(xb, gatwb, gat_Wb, WhT3);
    k_gat_att<<<dim3(8192, 3), blk, 0, stream>>>(adj, ev, att3);
    k_hhat<<<dim3(8, 8, 24), blk, 0, stream>>>(att3, WhT3, hh3, 3072);
    k_lin<<<dim3(4, 64), blk, 0, stream>>>(hh3, 3072, outwb, 3072, out_Wb, Who);
    k_eo<<<2048, blk, 0, stream>>>(Who, out_ai, out_ai_b, out_aj, out_aj_b, eo1, eo2);
    k_mask<<<8192, blk, 0, stream>>>(adj, eo1, eo2, mask);
    k_mtr<<<dim3(16, 16, 8), blk, 0, stream>>>(mask, maskT);
    k_flash<<<dim3(16, 8, 8), blk, 0, stream>>>(qb, kb, vT, maskT, aoutb);
    k_lin<<<dim3(4, 64), blk, 0, stream>>>(aoutb, 512, projwb, 512, proj_b, (float*)d_out);
  } else {
    bf16_t* WhT   = (bf16_t*)alloc(8ull * 1024 * 1024 * 2);
    bf16_t* att   = (bf16_t*)alloc(8ull * 1024 * 1024 * 2);
    bf16_t* hh    = (bf16_t*)alloc(8192ull * 1024 * 2);
    bf16_t* aoutb = (bf16_t*)alloc(8192ull * 512 * 2);
    bf16_t* maskT = (bf16_t*)alloc(8ull * 1024 * 1024 * 2);
    bf16_t* mask  = att;

    for (int l = 0; l < 3; ++l) {
      k_wh<<<dim3(8, 64, 1), blk, 0, stream>>>(xb, gatwb + (size_t)l * 524288, gat_Wb + l * 1024, WhT);
      k_gat_att<<<dim3(8192, 1), blk, 0, stream>>>(adj, ev + (size_t)l * 16384, att);
      k_hhat<<<dim3(8, 8, 8), blk, 0, stream>>>(att, WhT, hh, 1024);
      k_who_acc<<<dim3(4, 64), blk, 0, stream>>>(hh, outwb + l * 1024, out_Wb, Who, l);
    }
    k_eo<<<2048, blk, 0, stream>>>(Who, out_ai, out_ai_b, out_aj, out_aj_b, eo1, eo2);
    k_mask<<<8192, blk, 0, stream>>>(adj, eo1, eo2, mask);
    k_mtr<<<dim3(16, 16, 8), blk, 0, stream>>>(mask, maskT);
    k_flash<<<dim3(16, 8, 8), blk, 0, stream>>>(qb, kb, vT, maskT, aoutb);
    k_lin<<<dim3(4, 64), blk, 0, stream>>>(aoutb, 512, projwb, 512, proj_b, (float*)d_out);
  }
}

// Round 8
// 367.944 us; speedup vs baseline: 5.4571x; 1.0419x over previous
//
#include <hip/hip_runtime.h>
#include <math.h>
#include <stdint.h>

#define SCALEQ 0.125f

typedef __bf16 bf16_t;
typedef __bf16 bf16x8 __attribute__((ext_vector_type(8)));
typedef float f32x4 __attribute__((ext_vector_type(4)));

// global -> LDS async copy, 16B per lane. LDS dest is wave-uniform base + lane*16.
#define GLOAD_LDS16(gsrc, ldst)                                                   \
  __builtin_amdgcn_global_load_lds(                                               \
      (const __attribute__((address_space(1))) void*)(uintptr_t)(const void*)(gsrc), \
      (__attribute__((address_space(3))) void*)(uintptr_t)(void*)(ldst), 16, 0, 0)

// XCD-chunked bijective block swizzle (grid total must be %8==0):
// hardware assigns XCD = lin%8 round-robin; remap so each XCD gets a
// contiguous chunk of the work space -> shared operand panels stay in its L2.
__device__ __forceinline__ int3 xswz3() {
  const int nx = gridDim.x, ny = gridDim.y;
  int lin = (blockIdx.z * ny + blockIdx.y) * nx + blockIdx.x;
  const int n = nx * ny * gridDim.z;
  int work = (lin & 7) * (n >> 3) + (lin >> 3);
  int3 r;
  r.x = work % nx; work /= nx;
  r.y = work % ny; r.z = work / ny;
  return r;
}

// ---------------- bf16 MFMA GEMM core (128x128 tile, 4 waves, BK=64) ----------------
__device__ __forceinline__ void mm_bf16(const bf16_t* __restrict__ A, int lda,
                                        const bf16_t* __restrict__ B, int ldb,
                                        int K, int m0, int n0,
                                        bf16_t* As, bf16_t* Bs, f32x4 (&acc)[4][4]) {
  const int tid = threadIdx.x, lane = tid & 63, w = tid >> 6;
  const int wr = (w >> 1) * 64, wc = (w & 1) * 64;
  const int fr = lane & 15, fq = lane >> 4;
  for (int kt = 0; kt < K; kt += 64) {
    __syncthreads();
#pragma unroll
    for (int t = 0; t < 4; ++t) {
      const int rl = t * 32 + w * 8 + (lane >> 3);
      const int c8 = (lane & 7) * 8;
      GLOAD_LDS16(A + (size_t)(m0 + rl) * lda + kt + c8, As + (t * 32 + w * 8) * 64);
      GLOAD_LDS16(B + (size_t)(n0 + rl) * ldb + kt + c8, Bs + (t * 32 + w * 8) * 64);
    }
    __syncthreads();
#pragma unroll
    for (int ks = 0; ks < 2; ++ks) {
      bf16x8 af[4], bfv[4];
#pragma unroll
      for (int mf = 0; mf < 4; ++mf)
        af[mf] = *(const bf16x8*)(As + (wr + mf * 16 + fr) * 64 + ks * 32 + fq * 8);
#pragma unroll
      for (int nf = 0; nf < 4; ++nf)
        bfv[nf] = *(const bf16x8*)(Bs + (wc + nf * 16 + fr) * 64 + ks * 32 + fq * 8);
#pragma unroll
      for (int mf = 0; mf < 4; ++mf)
#pragma unroll
        for (int nf = 0; nf < 4; ++nf)
          acc[mf][nf] = __builtin_amdgcn_mfma_f32_16x16x32_bf16(af[mf], bfv[nf], acc[mf][nf], 0, 0, 0);
    }
  }
}

#define MM_PROLOGUE()                                  \
  __shared__ __align__(16) bf16_t As[128 * 64];        \
  __shared__ __align__(16) bf16_t Bs[128 * 64];        \
  f32x4 acc[4][4];                                     \
  _Pragma("unroll") for (int i_ = 0; i_ < 4; ++i_)     \
  _Pragma("unroll") for (int j_ = 0; j_ < 4; ++j_) acc[i_][j_] = (f32x4)0.0f;

#define MM_EPI_SETUP(M0, N0)                                   \
  const int lane = threadIdx.x & 63, w = threadIdx.x >> 6;     \
  const int fr = lane & 15, fq = lane >> 4;                    \
  const int mb = (M0) + (w >> 1) * 64, nb = (N0) + (w & 1) * 64;

// ---------------- GEMM kernels ----------------
// qkv: q,k -> bf16 [b,h,tok,64] (q pre-scaled); v -> bf16 transposed [b,h,64,tok]
__global__ __launch_bounds__(256) void k_qkv(const bf16_t* __restrict__ xb, const bf16_t* __restrict__ wb,
                                             bf16_t* __restrict__ qb, bf16_t* __restrict__ kb,
                                             bf16_t* __restrict__ vT) {
  MM_PROLOGUE();
  const int3 bi = xswz3();
  const int m0 = bi.y * 128, n0 = bi.x * 128;
  mm_bf16(xb, 512, wb, 512, 512, m0, n0, As, Bs, acc);
  MM_EPI_SETUP(m0, n0);
#pragma unroll
  for (int mf = 0; mf < 4; ++mf)
#pragma unroll
    for (int nf = 0; nf < 4; ++nf) {
      const int n = nb + nf * 16 + fr;
      const int which = n >> 9, hd = (n >> 6) & 7, d = n & 63;
      const int m_ = mb + mf * 16 + fq * 4;
      const int b = m_ >> 10, tok0 = m_ & 1023;
      if (which == 2) {
        union { ushort4 u; bf16_t q[4]; } pk;
#pragma unroll
        for (int r = 0; r < 4; ++r) pk.q[r] = (bf16_t)acc[mf][nf][r];
        *(ushort4*)(vT + (((size_t)b * 8 + hd) * 64 + d) * 1024 + tok0) = pk.u;
      } else {
        bf16_t* dst = which ? kb : qb;
        const float sc = which ? 1.f : SCALEQ;
#pragma unroll
        for (int r = 0; r < 4; ++r)
          dst[(((size_t)b * 8 + hd) * 1024 + tok0 + r) * 64 + d] = (bf16_t)(acc[mf][nf][r] * sc);
      }
    }
}

// Wh_l^T (per batch): WhT[l][b][h][m], bf16. l = z (batched) or 0 (pre-offset bases).
__global__ __launch_bounds__(256) void k_wh(const bf16_t* __restrict__ xb, const bf16_t* __restrict__ gatw,
                                            const float* __restrict__ gWb, bf16_t* __restrict__ WhT) {
  MM_PROLOGUE();
  const int3 bi = xswz3();
  const int m0 = bi.y * 128, n0 = bi.x * 128, l = bi.z;
  const bf16_t* Wl = gatw + (size_t)l * 524288;
  const float* Wb = gWb + l * 1024;
  bf16_t* out = WhT + (size_t)l * 8388608;
  mm_bf16(xb, 512, Wl, 512, 512, m0, n0, As, Bs, acc);
  MM_EPI_SETUP(m0, n0);
#pragma unroll
  for (int mf = 0; mf < 4; ++mf)
#pragma unroll
    for (int nf = 0; nf < 4; ++nf) {
      const int h = nb + nf * 16 + fr;
      const float bias = Wb[h];
      const int m_ = mb + mf * 16 + fq * 4;
      const int b = m_ >> 10, ml = m_ & 1023;
      union { ushort4 u; bf16_t q[4]; } pk;
#pragma unroll
      for (int r = 0; r < 4; ++r) pk.q[r] = (bf16_t)(acc[mf][nf][r] + bias);
      *(ushort4*)(out + (((size_t)b << 10) + h) * 1024 + ml) = pk.u;
    }
}

// hh = elu(att_lb @ Wh_lb); z -> (l = z>>3, b = z&7). Writes hh[(b*1024+m)*ldh + l*1024 + n].
__global__ __launch_bounds__(256) void k_hhat(const bf16_t* __restrict__ att, const bf16_t* __restrict__ WhT,
                                              bf16_t* __restrict__ hh, int ldh) {
  MM_PROLOGUE();
  const int3 bi = xswz3();
  const int m0 = bi.y * 128, n0 = bi.x * 128;
  const int l = bi.z >> 3, bz = bi.z & 7;
  const size_t off = ((size_t)(l * 8 + bz)) << 20;
  mm_bf16(att + off, 1024, WhT + off, 1024, 1024, m0, n0, As, Bs, acc);
  MM_EPI_SETUP(m0, n0);
#pragma unroll
  for (int mf = 0; mf < 4; ++mf)
#pragma unroll
    for (int nf = 0; nf < 4; ++nf) {
      const int n = nb + nf * 16 + fr;
#pragma unroll
      for (int r = 0; r < 4; ++r) {
        const int m = mb + mf * 16 + fq * 4 + r;
        float v = acc[mf][nf][r];
        v = v > 0.f ? v : (__expf(v) - 1.f);
        hh[(size_t)((bz << 10) + m) * ldh + l * 1024 + n] = (bf16_t)v;
      }
    }
}

// generic GEMM + bias -> f32 out: out[m][n] = A[m]:K . B[n]:K + bias[n]  (ldb == K)
__global__ __launch_bounds__(256) void k_lin(const bf16_t* __restrict__ A, int lda,
                                             const bf16_t* __restrict__ B, int K,
                                             const float* __restrict__ bias, float* __restrict__ out) {
  MM_PROLOGUE();
  const int3 bi = xswz3();
  const int m0 = bi.y * 128, n0 = bi.x * 128;
  mm_bf16(A, lda, B, K, K, m0, n0, As, Bs, acc);
  MM_EPI_SETUP(m0, n0);
#pragma unroll
  for (int mf = 0; mf < 4; ++mf)
#pragma unroll
    for (int nf = 0; nf < 4; ++nf) {
      const int n = nb + nf * 16 + fr;
#pragma unroll
      for (int r = 0; r < 4; ++r) {
        const int m = mb + mf * 16 + fq * 4 + r;
        out[(size_t)m * 512 + n] = acc[mf][nf][r] + bias[n];
      }
    }
}

// fallback: Who (+)= hh @ out_W[:, l*1024:+1024].T (bias folded at l==0)
__global__ __launch_bounds__(256) void k_who_acc(const bf16_t* __restrict__ hh, const bf16_t* __restrict__ Wl,
                                                 const float* __restrict__ Wb, float* __restrict__ Who, int l) {
  MM_PROLOGUE();
  const int m0 = blockIdx.y * 128, n0 = blockIdx.x * 128;
  mm_bf16(hh, 1024, Wl, 3072, 1024, m0, n0, As, Bs, acc);
  MM_EPI_SETUP(m0, n0);
#pragma unroll
  for (int mf = 0; mf < 4; ++mf)
#pragma unroll
    for (int nf = 0; nf < 4; ++nf) {
      const int n = nb + nf * 16 + fr;
#pragma unroll
      for (int r = 0; r < 4; ++r) {
        const int m = mb + mf * 16 + fq * 4 + r;
        const size_t idx = (size_t)m * 512 + n;
        Who[idx] = acc[mf][nf][r] + (l == 0 ? Wb[n] : Who[idx]);
      }
    }
}

// ---------------- fused casts f32 -> bf16 (5 segments) ----------------
__global__ __launch_bounds__(256) void k_cast5(const float* __restrict__ s0, bf16_t* __restrict__ d0, int c0,
                                               const float* __restrict__ s1, bf16_t* __restrict__ d1, int c1,
                                               const float* __restrict__ s2, bf16_t* __restrict__ d2, int c2,
                                               const float* __restrict__ s3, bf16_t* __restrict__ d3, int c3,
                                               const float* __restrict__ s4, bf16_t* __restrict__ d4, int c4) {
  int i = blockIdx.x * 256 + threadIdx.x;
  const float* src; bf16_t* dst; int j;
  if (i < c0)      { src = s0; dst = d0; j = i; }
  else if (i < c1) { src = s1; dst = d1; j = i - c0; }
  else if (i < c2) { src = s2; dst = d2; j = i - c1; }
  else if (i < c3) { src = s3; dst = d3; j = i - c2; }
  else if (i < c4) { src = s4; dst = d4; j = i - c3; }
  else return;
  float4 v = ((const float4*)src)[j];
  union { ushort4 u; bf16_t b[4]; } p;
  p.b[0] = (bf16_t)v.x; p.b[1] = (bf16_t)v.y; p.b[2] = (bf16_t)v.z; p.b[3] = (bf16_t)v.w;
  ((ushort4*)dst)[j] = p.u;
}

// ---------------- algebraic e1/e2 ----------------
__global__ __launch_bounds__(256) void k_wvec(const bf16_t* __restrict__ gatwb,
                                              const float* __restrict__ gWb,
                                              const float* __restrict__ ai, const float* __restrict__ aib,
                                              const float* __restrict__ aj, const float* __restrict__ ajb,
                                              float* __restrict__ wv, float* __restrict__ con) {
  __shared__ float sred[4][64];
  __shared__ float cred[256];
  const int v = blockIdx.y, l = v >> 1;
  const float* avec = ((v & 1) ? aj : ai) + (l << 10);
  const bf16_t* W = gatwb + ((size_t)(l << 10)) * 512;
  const int tid = threadIdx.x, hg = tid >> 6, cc = tid & 63;
  const int c = blockIdx.x * 64 + cc;
  float p = 0.f;
  for (int i = 0; i < 256; ++i) {
    const int h = hg * 256 + i;
    p = fmaf((float)W[(size_t)h * 512 + c], avec[h], p);
  }
  sred[hg][cc] = p;
  float cp = 0.f;
#pragma unroll
  for (int i = 0; i < 4; ++i) cp = fmaf(gWb[(l << 10) + tid + i * 256], avec[tid + i * 256], cp);
  cred[tid] = cp;
  __syncthreads();
  if (tid < 64) wv[v * 512 + blockIdx.x * 64 + tid] = sred[0][tid] + sred[1][tid] + sred[2][tid] + sred[3][tid];
  for (int s = 128; s > 0; s >>= 1) {
    if (tid < s) cred[tid] += cred[tid + s];
    __syncthreads();
  }
  if (tid == 0 && blockIdx.x == 0) con[v] = cred[0] + ((v & 1) ? ajb[l] : aib[l]);
}

__global__ __launch_bounds__(256) void k_e12v(const bf16_t* __restrict__ xb,
                                              const float* __restrict__ wv, const float* __restrict__ con,
                                              float* __restrict__ ev) {
  const int tid = threadIdx.x, lane = tid & 63, wid = tid >> 6;
  const int row = blockIdx.x * 4 + wid;
  bf16x8 xv = *(const bf16x8*)(xb + (size_t)row * 512 + lane * 8);
  float xf[8];
#pragma unroll
  for (int j = 0; j < 8; ++j) xf[j] = (float)xv[j];
  float s[6];
#pragma unroll
  for (int v = 0; v < 6; ++v) {
    const float* wp = wv + v * 512 + lane * 8;
    float a = 0.f;
#pragma unroll
    for (int j = 0; j < 8; ++j) a = fmaf(xf[j], wp[j], a);
    s[v] = a;
  }
#pragma unroll
  for (int v = 0; v < 6; ++v)
#pragma unroll
    for (int off = 32; off > 0; off >>= 1) s[v] += __shfl_xor(s[v], off);
  if (lane == 0) {
#pragma unroll
    for (int v = 0; v < 6; ++v) ev[v * 8192 + row] = s[v] + con[v];
  }
}

__global__ __launch_bounds__(256) void k_eo(const float* __restrict__ Who,
                                            const float* __restrict__ ai, const float* __restrict__ aib,
                                            const float* __restrict__ aj, const float* __restrict__ ajb,
                                            float* __restrict__ eo1, float* __restrict__ eo2) {
  const int wid = threadIdx.x >> 6, lane = threadIdx.x & 63;
  const int row = blockIdx.x * 4 + wid;
  const float* wr = Who + (size_t)row * 512;
  float s1 = 0.f, s2 = 0.f;
#pragma unroll
  for (int c = 0; c < 2; ++c) {
    const int idx = c * 256 + lane * 4;
    float4 w4 = *(const float4*)&wr[idx];
    float4 a4 = *(const float4*)&ai[idx];
    float4 b4 = *(const float4*)&aj[idx];
    s1 += w4.x * a4.x + w4.y * a4.y + w4.z * a4.z + w4.w * a4.w;
    s2 += w4.x * b4.x + w4.y * b4.y + w4.z * b4.z + w4.w * b4.w;
  }
#pragma unroll
  for (int off = 32; off > 0; off >>= 1) { s1 += __shfl_xor(s1, off); s2 += __shfl_xor(s2, off); }
  if (lane == 0) { eo1[row] = s1 + aib[0]; eo2[row] = s2 + ajb[0]; }
}

// ---------------- block reduce helpers ----------------
__device__ __forceinline__ float block_max(float v, float* red) {
#pragma unroll
  for (int off = 32; off > 0; off >>= 1) v = fmaxf(v, __shfl_xor(v, off));
  __syncthreads();
  if ((threadIdx.x & 63) == 0) red[threadIdx.x >> 6] = v;
  __syncthreads();
  return fmaxf(fmaxf(red[0], red[1]), fmaxf(red[2], red[3]));
}
__device__ __forceinline__ float block_sum(float v, float* red) {
#pragma unroll
  for (int off = 32; off > 0; off >>= 1) v += __shfl_xor(v, off);
  __syncthreads();
  if ((threadIdx.x & 63) == 0) red[threadIdx.x >> 6] = v;
  __syncthreads();
  return red[0] + red[1] + red[2] + red[3];
}

// ---------------- GAT attention rows: all 3 layers per block (adj read once) ----------------
__global__ __launch_bounds__(256) void k_gat_att3(const float* __restrict__ adj, const float* __restrict__ ev,
                                                  bf16_t* __restrict__ att) {
  __shared__ float red[4];
  const int row = blockIdx.x;
  const int b = row >> 10;
  const float* arow = adj + (size_t)row * 1024;
  float a[4];
#pragma unroll
  for (int c = 0; c < 4; ++c) a[c] = arow[c * 256 + threadIdx.x];
#pragma unroll
  for (int l = 0; l < 3; ++l) {
    const float e1v = ev[l * 16384 + row];
    const float* e2r = ev + l * 16384 + 8192 + (b << 10);
    bf16_t* aout = att + (size_t)l * 8388608 + (size_t)row * 1024;
    float s[4];
    float mx = -1e30f;
#pragma unroll
    for (int c = 0; c < 4; ++c) {
      float e = e1v + e2r[c * 256 + threadIdx.x];
      e = e > 0.f ? e : 0.2f * e;
      s[c] = a[c] * e;
      mx = fmaxf(mx, s[c]);
    }
    mx = block_max(mx, red);
    float sum = 0.f;
#pragma unroll
    for (int c = 0; c < 4; ++c) { float p = __expf(s[c] - mx); s[c] = p; sum += p; }
    sum = block_sum(sum, red);
    const float inv = 1.f / sum;
#pragma unroll
    for (int c = 0; c < 4; ++c) aout[c * 256 + threadIdx.x] = (bf16_t)(s[c] * inv);
  }
}

// fallback single-layer version
__global__ __launch_bounds__(256) void k_gat_att(const float* __restrict__ adj, const float* __restrict__ ev,
                                                 bf16_t* __restrict__ att) {
  __shared__ float red[4];
  const int row = blockIdx.x;
  const int b = row >> 10;
  const float* arow = adj + (size_t)row * 1024;
  const float e1v = ev[row];
  const float* e2r = ev + 8192 + (b << 10);
  float s[4];
  float mx = -1e30f;
#pragma unroll
  for (int c = 0; c < 4; ++c) {
    const int m = c * 256 + threadIdx.x;
    float e = e1v + e2r[m];
    e = e > 0.f ? e : 0.2f * e;
    s[c] = arow[m] * e;
    mx = fmaxf(mx, s[c]);
  }
  mx = block_max(mx, red);
  float sum = 0.f;
#pragma unroll
  for (int c = 0; c < 4; ++c) { float p = __expf(s[c] - mx); s[c] = p; sum += p; }
  sum = block_sum(sum, red);
  const float inv = 1.f / sum;
#pragma unroll
  for (int c = 0; c < 4; ++c) att[(size_t)row * 1024 + c * 256 + threadIdx.x] = (bf16_t)(s[c] * inv);
}

// ---------------- output-attention mask rows (double softmax) ----------------
__global__ __launch_bounds__(256) void k_mask(const float* __restrict__ adj, const float* __restrict__ eo1,
                                              const float* __restrict__ eo2, bf16_t* __restrict__ mask) {
  __shared__ float red[4];
  const int row = blockIdx.x;
  const int b = row >> 10;
  const float* arow = adj + (size_t)row * 1024;
  const float t1 = eo1[row];
  const float* eor = eo2 + (b << 10);
  float s[4];
  float mx = -1e30f;
#pragma unroll
  for (int c = 0; c < 4; ++c) {
    const int m = c * 256 + threadIdx.x;
    float e = t1 + eor[m];
    e = e > 0.f ? e : 0.2f * e;
    s[c] = arow[m] * e;
    mx = fmaxf(mx, s[c]);
  }
  mx = block_max(mx, red);
  float sum = 0.f;
#pragma unroll
  for (int c = 0; c < 4; ++c) { float p = __expf(s[c] - mx); s[c] = p; sum += p; }
  sum = block_sum(sum, red);
  const float inv = 1.f / sum;
  float mx2 = -1e30f;
#pragma unroll
  for (int c = 0; c < 4; ++c) { s[c] *= inv; mx2 = fmaxf(mx2, s[c]); }
  mx2 = block_max(mx2, red);
  float sum2 = 0.f;
#pragma unroll
  for (int c = 0; c < 4; ++c) { float p = __expf(s[c] - mx2); s[c] = p; sum2 += p; }
  sum2 = block_sum(sum2, red);
  const float inv2 = 1.f / sum2;
#pragma unroll
  for (int c = 0; c < 4; ++c) mask[(size_t)row * 1024 + c * 256 + threadIdx.x] = (bf16_t)(s[c] * inv2);
}

// ---------------- mask transpose ----------------
__global__ __launch_bounds__(256) void k_mtr(const bf16_t* __restrict__ in, bf16_t* __restrict__ out) {
  __shared__ bf16_t T[64][72];
  const int q0 = blockIdx.x * 64, k0 = blockIdx.y * 64, b = blockIdx.z;
  const bf16_t* src = in + ((size_t)b << 20);
  bf16_t* dst = out + ((size_t)b << 20);
  const int r = threadIdx.x >> 2, c = (threadIdx.x & 3) * 16;
  bf16x8 a0 = *(const bf16x8*)(src + (size_t)(q0 + r) * 1024 + k0 + c);
  bf16x8 a1 = *(const bf16x8*)(src + (size_t)(q0 + r) * 1024 + k0 + c + 8);
  *(bf16x8*)&T[r][c] = a0;
  *(bf16x8*)&T[r][c + 8] = a1;
  __syncthreads();
  union { bf16x8 v[2]; bf16_t e[16]; } o;
#pragma unroll
  for (int j = 0; j < 16; ++j) o.e[j] = T[c + j][r];
  *(bf16x8*)(dst + (size_t)(k0 + r) * 1024 + q0 + c) = o.v[0];
  *(bf16x8*)(dst + (size_t)(k0 + r) * 1024 + q0 + c + 8) = o.v[1];
}

// ---------------- MFMA flash attention (XOR-swizzled K/V LDS) ----------------
__device__ __forceinline__ int swz(int row, int slot) { return row * 64 + ((slot ^ (row & 7)) << 3); }

__global__ __launch_bounds__(256) void k_flash(const bf16_t* __restrict__ qg, const bf16_t* __restrict__ kg,
                                               const bf16_t* __restrict__ vTg, const bf16_t* __restrict__ maskT,
                                               bf16_t* __restrict__ aout) {
  __shared__ __align__(16) bf16_t Ks[4096];
  __shared__ __align__(16) bf16_t Vs[4096];
  __shared__ __align__(16) bf16_t PL[4][16][72];
  const int tid = threadIdx.x, lane = tid & 63, w = tid >> 6;
  const int fr = lane & 15, fq = lane >> 4;
  const int3 bi = xswz3();
  const int n0 = bi.x * 64, hh = bi.y, bb = bi.z;
  const size_t bh = ((size_t)bb * 8 + hh) << 16;
  const bf16_t* q = qg + bh;
  const bf16_t* kk = kg + bh;
  const bf16_t* vT = vTg + bh;
  const bf16_t* mT = maskT + ((size_t)bb << 20);

  bf16x8 qf[2];
#pragma unroll
  for (int ks = 0; ks < 2; ++ks)
    qf[ks] = *(const bf16x8*)(q + (size_t)(n0 + w * 16 + fr) * 64 + ks * 32 + fq * 8);

  f32x4 o[4];
#pragma unroll
  for (int nf = 0; nf < 4; ++nf) o[nf] = (f32x4)0.0f;
  float psum[4] = {0.f, 0.f, 0.f, 0.f};

  const int srow = tid >> 2, sslot = (tid & 3) * 2;
  const int ws0 = swz(srow, sslot), ws1 = swz(srow, sslot + 1);
  const int scol = (tid & 3) * 16;

  for (int c = 0; c < 16; ++c) {
    const int k0 = c * 64;
    bf16x8 kv0 = *(const bf16x8*)(kk + (size_t)(k0 + srow) * 64 + scol);
    bf16x8 kv1 = *(const bf16x8*)(kk + (size_t)(k0 + srow) * 64 + scol + 8);
    bf16x8 vv0 = *(const bf16x8*)(vT + (size_t)srow * 1024 + k0 + scol);
    bf16x8 vv1 = *(const bf16x8*)(vT + (size_t)srow * 1024 + k0 + scol + 8);
    union { ushort4 u; bf16_t h[4]; } mfr[4];
#pragma unroll
    for (int nf = 0; nf < 4; ++nf)
      mfr[nf].u = *(const ushort4*)(mT + (size_t)(k0 + nf * 16 + fr) * 1024 + n0 + w * 16 + fq * 4);
    __syncthreads();
    *(bf16x8*)&Ks[ws0] = kv0; *(bf16x8*)&Ks[ws1] = kv1;
    *(bf16x8*)&Vs[ws0] = vv0; *(bf16x8*)&Vs[ws1] = vv1;
    __syncthreads();

    f32x4 s[4];
#pragma unroll
    for (int nf = 0; nf < 4; ++nf) s[nf] = (f32x4)0.0f;
#pragma unroll
    for (int ks = 0; ks < 2; ++ks) {
      bf16x8 kf[4];
#pragma unroll
      for (int nf = 0; nf < 4; ++nf)
        kf[nf] = *(const bf16x8*)&Ks[swz(nf * 16 + fr, ks * 4 + fq)];
#pragma unroll
      for (int nf = 0; nf < 4; ++nf)
        s[nf] = __builtin_amdgcn_mfma_f32_16x16x32_bf16(qf[ks], kf[nf], s[nf], 0, 0, 0);
    }

#pragma unroll
    for (int nf = 0; nf < 4; ++nf)
#pragma unroll
      for (int r = 0; r < 4; ++r) {
        const float p = __expf(s[nf][r] * (float)mfr[nf].h[r]);
        psum[r] += p;
        PL[w][fq * 4 + r][nf * 16 + fr] = (bf16_t)p;
      }

#pragma unroll
    for (int ks = 0; ks < 2; ++ks) {
      bf16x8 pf = *(const bf16x8*)&PL[w][fr][ks * 32 + fq * 8];
      bf16x8 vf[4];
#pragma unroll
      for (int nfo = 0; nfo < 4; ++nfo)
        vf[nfo] = *(const bf16x8*)&Vs[swz(nfo * 16 + fr, ks * 4 + fq)];
#pragma unroll
      for (int nfo = 0; nfo < 4; ++nfo)
        o[nfo] = __builtin_amdgcn_mfma_f32_16x16x32_bf16(pf, vf[nfo], o[nfo], 0, 0, 0);
    }
  }

#pragma unroll
  for (int r = 0; r < 4; ++r) {
    psum[r] += __shfl_xor(psum[r], 1);
    psum[r] += __shfl_xor(psum[r], 2);
    psum[r] += __shfl_xor(psum[r], 4);
    psum[r] += __shfl_xor(psum[r], 8);
  }
#pragma unroll
  for (int r = 0; r < 4; ++r) {
    const int tok = n0 + w * 16 + fq * 4 + r;
    const float inv = 1.f / psum[r];
#pragma unroll
    for (int nfo = 0; nfo < 4; ++nfo)
      aout[((size_t)(bb << 10) + tok) * 512 + hh * 64 + nfo * 16 + fr] = (bf16_t)(o[nfo][r] * inv);
  }
}

// ---------------- launcher ----------------
extern "C" void kernel_launch(void* const* d_in, const int* in_sizes, int n_in,
                              void* d_out, int out_size, void* d_ws, size_t ws_size,
                              hipStream_t stream) {
  (void)in_sizes; (void)n_in; (void)out_size;
  const float* x        = (const float*)d_in[0];
  const float* adj      = (const float*)d_in[1];
  const float* qkv_w    = (const float*)d_in[2];
  const float* proj_w   = (const float*)d_in[3];
  const float* proj_b   = (const float*)d_in[4];
  const float* gat_W    = (const float*)d_in[5];
  const float* gat_Wb   = (const float*)d_in[6];
  const float* gat_ai   = (const float*)d_in[7];
  const float* gat_ai_b = (const float*)d_in[8];
  const float* gat_aj   = (const float*)d_in[9];
  const float* gat_aj_b = (const float*)d_in[10];
  const float* out_W    = (const float*)d_in[11];
  const float* out_Wb   = (const float*)d_in[12];
  const float* out_ai   = (const float*)d_in[13];
  const float* out_ai_b = (const float*)d_in[14];
  const float* out_aj   = (const float*)d_in[15];
  const float* out_aj_b = (const float*)d_in[16];

  char* p = (char*)d_ws;
  auto alloc = [&](size_t bytes) { char* r = p; p += (bytes + 255) & ~(size_t)255; return r; };
  bf16_t* xb     = (bf16_t*)alloc(8192ull * 512 * 2);
  bf16_t* qkvwb  = (bf16_t*)alloc(1536ull * 512 * 2);
  bf16_t* gatwb  = (bf16_t*)alloc(3072ull * 512 * 2);
  bf16_t* outwb  = (bf16_t*)alloc(512ull * 3072 * 2);
  bf16_t* projwb = (bf16_t*)alloc(512ull * 512 * 2);
  bf16_t* qb     = (bf16_t*)alloc(8ull * 8 * 1024 * 64 * 2);
  bf16_t* kb     = (bf16_t*)alloc(8ull * 8 * 1024 * 64 * 2);
  bf16_t* vT     = (bf16_t*)alloc(8ull * 8 * 64 * 1024 * 2);
  float*  Who    = (float*)alloc(8192ull * 512 * 4);
  float*  wv     = (float*)alloc(6 * 512 * 4);
  float*  con    = (float*)alloc(256);
  float*  ev     = (float*)alloc(6 * 8192 * 4);
  float*  eo1    = (float*)alloc(8192 * 4);
  float*  eo2    = (float*)alloc(8192 * 4);

  const bool big = ws_size >= 211000000ull;

  const dim3 blk(256);
  k_cast5<<<8192, blk, 0, stream>>>(x, xb, 1048576, qkv_w, qkvwb, 1245184, gat_W, gatwb, 1638400,
                                    out_W, outwb, 2031616, proj_w, projwb, 2097152);
  k_wvec<<<dim3(8, 6), blk, 0, stream>>>(gatwb, gat_Wb, gat_ai, gat_ai_b, gat_aj, gat_aj_b, wv, con);
  k_e12v<<<2048, blk, 0, stream>>>(xb, wv, con, ev);
  k_qkv<<<dim3(12, 64), blk, 0, stream>>>(xb, qkvwb, qb, kb, vT);

  if (big) {
    bf16_t* WhT3 = (bf16_t*)alloc(3ull * 8 * 1024 * 1024 * 2);
    bf16_t* att3 = (bf16_t*)alloc(3ull * 8 * 1024 * 1024 * 2);
    bf16_t* hh3  = (bf16_t*)alloc(8192ull * 3072 * 2);
    bf16_t* mask  = att3;
    bf16_t* maskT = att3 + 8388608;
    bf16_t* aoutb = att3 + 2 * 8388608;

    k_wh<<<dim3(8, 64, 3), blk, 0, stream>>>(xb, gatwb, gat_Wb, WhT3);
    k_gat_att3<<<8192, blk, 0, stream>>>(adj, ev, att3);
    k_hhat<<<dim3(8, 8, 24), blk, 0, stream>>>(att3, WhT3, hh3, 3072);
    k_lin<<<dim3(4, 64), blk, 0, stream>>>(hh3, 3072, outwb, 3072, out_Wb, Who);
    k_eo<<<2048, blk, 0, stream>>>(Who, out_ai, out_ai_b, out_aj, out_aj_b, eo1, eo2);
    k_mask<<<8192, blk, 0, stream>>>(adj, eo1, eo2, mask);
    k_mtr<<<dim3(16, 16, 8), blk, 0, stream>>>(mask, maskT);
    k_flash<<<dim3(16, 8, 8), blk, 0, stream>>>(qb, kb, vT, maskT, aoutb);
    k_lin<<<dim3(4, 64), blk, 0, stream>>>(aoutb, 512, projwb, 512, proj_b, (float*)d_out);
  } else {
    bf16_t* WhT   = (bf16_t*)alloc(8ull * 1024 * 1024 * 2);
    bf16_t* att   = (bf16_t*)alloc(8ull * 1024 * 1024 * 2);
    bf16_t* hh    = (bf16_t*)alloc(8192ull * 1024 * 2);
    bf16_t* aoutb = (bf16_t*)alloc(8192ull * 512 * 2);
    bf16_t* maskT = (bf16_t*)alloc(8ull * 1024 * 1024 * 2);
    bf16_t* mask  = att;

    for (int l = 0; l < 3; ++l) {
      k_wh<<<dim3(8, 64, 1), blk, 0, stream>>>(xb, gatwb + (size_t)l * 524288, gat_Wb + l * 1024, WhT);
      k_gat_att<<<8192, blk, 0, stream>>>(adj, ev + (size_t)l * 16384, att);
      k_hhat<<<dim3(8, 8, 8), blk, 0, stream>>>(att, WhT, hh, 1024);
      k_who_acc<<<dim3(4, 64), blk, 0, stream>>>(hh, outwb + l * 1024, out_Wb, Who, l);
    }
    k_eo<<<2048, blk, 0, stream>>>(Who, out_ai, out_ai_b, out_aj, out_aj_b, eo1, eo2);
    k_mask<<<8192, blk, 0, stream>>>(adj, eo1, eo2, mask);
    k_mtr<<<dim3(16, 16, 8), blk, 0, stream>>>(mask, maskT);
    k_flash<<<dim3(16, 8, 8), blk, 0, stream>>>(qb, kb, vT, maskT, aoutb);
    k_lin<<<dim3(4, 64), blk, 0, stream>>>(aoutb, 512, projwb, 512, proj_b, (float*)d_out);
  }
}

// Round 9
// 327.360 us; speedup vs baseline: 6.1336x; 1.1240x over previous
//
#include <hip/hip_runtime.h>
#include <math.h>
#include <stdint.h>

#define SCALEQ 0.125f

typedef __bf16 bf16_t;
typedef __bf16 bf16x8 __attribute__((ext_vector_type(8)));
typedef float f32x4 __attribute__((ext_vector_type(4)));

// global -> LDS async copy, 16B per lane. LDS dest is wave-uniform base + lane*16.
#define GLOAD_LDS16(gsrc, ldst)                                                   \
  __builtin_amdgcn_global_load_lds(                                               \
      (const __attribute__((address_space(1))) void*)(uintptr_t)(const void*)(gsrc), \
      (__attribute__((address_space(3))) void*)(uintptr_t)(void*)(ldst), 16, 0, 0)

// XCD-chunked bijective block swizzle (grid total must be %8==0).
__device__ __forceinline__ int3 xswz3() {
  const int nx = gridDim.x, ny = gridDim.y;
  int lin = (blockIdx.z * ny + blockIdx.y) * nx + blockIdx.x;
  const int n = nx * ny * gridDim.z;
  int work = (lin & 7) * (n >> 3) + (lin >> 3);
  int3 r;
  r.x = work % nx; work /= nx;
  r.y = work % ny; r.z = work / ny;
  return r;
}

// ---------------- bf16 MFMA GEMM core (128x128 tile, 4 waves, BK=64) ----------------
// LDS rows of 64 bf16 (128B). XOR swizzle (rule #21): linear LDS dest,
// per-lane global SOURCE chunk permuted by (row&7); reads apply the same XOR.
// Reduces the 16-way ds_read_b128 row-stride conflict to 8-way.
__device__ __forceinline__ void mm_bf16(const bf16_t* __restrict__ A, int lda,
                                        const bf16_t* __restrict__ B, int ldb,
                                        int K, int m0, int n0,
                                        bf16_t* As, bf16_t* Bs, f32x4 (&acc)[4][4]) {
  const int tid = threadIdx.x, lane = tid & 63, w = tid >> 6;
  const int wr = (w >> 1) * 64, wc = (w & 1) * 64;
  const int fr = lane & 15, fq = lane >> 4;
  const int c8 = (((lane & 7) ^ ((lane >> 3) & 7)) * 8);   // swizzled source chunk
  for (int kt = 0; kt < K; kt += 64) {
    __syncthreads();
#pragma unroll
    for (int t = 0; t < 4; ++t) {
      const int rl = t * 32 + w * 8 + (lane >> 3);
      GLOAD_LDS16(A + (size_t)(m0 + rl) * lda + kt + c8, As + (t * 32 + w * 8) * 64);
      GLOAD_LDS16(B + (size_t)(n0 + rl) * ldb + kt + c8, Bs + (t * 32 + w * 8) * 64);
    }
    __syncthreads();
#pragma unroll
    for (int ks = 0; ks < 2; ++ks) {
      bf16x8 af[4], bfv[4];
      const int ch = (((ks * 4 + fq) ^ (fr & 7)) << 3);
#pragma unroll
      for (int mf = 0; mf < 4; ++mf)
        af[mf] = *(const bf16x8*)(As + (wr + mf * 16 + fr) * 64 + ch);
#pragma unroll
      for (int nf = 0; nf < 4; ++nf)
        bfv[nf] = *(const bf16x8*)(Bs + (wc + nf * 16 + fr) * 64 + ch);
#pragma unroll
      for (int mf = 0; mf < 4; ++mf)
#pragma unroll
        for (int nf = 0; nf < 4; ++nf)
          acc[mf][nf] = __builtin_amdgcn_mfma_f32_16x16x32_bf16(af[mf], bfv[nf], acc[mf][nf], 0, 0, 0);
    }
  }
}

#define MM_PROLOGUE()                                  \
  __shared__ __align__(16) bf16_t As[128 * 64];        \
  __shared__ __align__(16) bf16_t Bs[128 * 64];        \
  f32x4 acc[4][4];                                     \
  _Pragma("unroll") for (int i_ = 0; i_ < 4; ++i_)     \
  _Pragma("unroll") for (int j_ = 0; j_ < 4; ++j_) acc[i_][j_] = (f32x4)0.0f;

#define MM_EPI_SETUP(M0, N0)                                   \
  const int lane = threadIdx.x & 63, w = threadIdx.x >> 6;     \
  const int fr = lane & 15, fq = lane >> 4;                    \
  const int mb = (M0) + (w >> 1) * 64, nb = (N0) + (w & 1) * 64;

// ---------------- GEMM kernels ----------------
__global__ __launch_bounds__(256) void k_qkv(const bf16_t* __restrict__ xb, const bf16_t* __restrict__ wb,
                                             bf16_t* __restrict__ qb, bf16_t* __restrict__ kb,
                                             bf16_t* __restrict__ vT) {
  MM_PROLOGUE();
  const int3 bi = xswz3();
  const int m0 = bi.y * 128, n0 = bi.x * 128;
  mm_bf16(xb, 512, wb, 512, 512, m0, n0, As, Bs, acc);
  MM_EPI_SETUP(m0, n0);
#pragma unroll
  for (int mf = 0; mf < 4; ++mf)
#pragma unroll
    for (int nf = 0; nf < 4; ++nf) {
      const int n = nb + nf * 16 + fr;
      const int which = n >> 9, hd = (n >> 6) & 7, d = n & 63;
      const int m_ = mb + mf * 16 + fq * 4;
      const int b = m_ >> 10, tok0 = m_ & 1023;
      if (which == 2) {
        union { ushort4 u; bf16_t q[4]; } pk;
#pragma unroll
        for (int r = 0; r < 4; ++r) pk.q[r] = (bf16_t)acc[mf][nf][r];
        *(ushort4*)(vT + (((size_t)b * 8 + hd) * 64 + d) * 1024 + tok0) = pk.u;
      } else {
        bf16_t* dst = which ? kb : qb;
        const float sc = which ? 1.f : SCALEQ;
#pragma unroll
        for (int r = 0; r < 4; ++r)
          dst[(((size_t)b * 8 + hd) * 1024 + tok0 + r) * 64 + d] = (bf16_t)(acc[mf][nf][r] * sc);
      }
    }
}

__global__ __launch_bounds__(256) void k_wh(const bf16_t* __restrict__ xb, const bf16_t* __restrict__ gatw,
                                            const float* __restrict__ gWb, bf16_t* __restrict__ WhT) {
  MM_PROLOGUE();
  const int3 bi = xswz3();
  const int m0 = bi.y * 128, n0 = bi.x * 128, l = bi.z;
  const bf16_t* Wl = gatw + (size_t)l * 524288;
  const float* Wb = gWb + l * 1024;
  bf16_t* out = WhT + (size_t)l * 8388608;
  mm_bf16(xb, 512, Wl, 512, 512, m0, n0, As, Bs, acc);
  MM_EPI_SETUP(m0, n0);
#pragma unroll
  for (int mf = 0; mf < 4; ++mf)
#pragma unroll
    for (int nf = 0; nf < 4; ++nf) {
      const int h = nb + nf * 16 + fr;
      const float bias = Wb[h];
      const int m_ = mb + mf * 16 + fq * 4;
      const int b = m_ >> 10, ml = m_ & 1023;
      union { ushort4 u; bf16_t q[4]; } pk;
#pragma unroll
      for (int r = 0; r < 4; ++r) pk.q[r] = (bf16_t)(acc[mf][nf][r] + bias);
      *(ushort4*)(out + (((size_t)b << 10) + h) * 1024 + ml) = pk.u;
    }
}

__global__ __launch_bounds__(256) void k_hhat(const bf16_t* __restrict__ att, const bf16_t* __restrict__ WhT,
                                              bf16_t* __restrict__ hh, int ldh) {
  MM_PROLOGUE();
  const int3 bi = xswz3();
  const int m0 = bi.y * 128, n0 = bi.x * 128;
  const int l = bi.z >> 3, bz = bi.z & 7;
  const size_t off = ((size_t)(l * 8 + bz)) << 20;
  mm_bf16(att + off, 1024, WhT + off, 1024, 1024, m0, n0, As, Bs, acc);
  MM_EPI_SETUP(m0, n0);
#pragma unroll
  for (int mf = 0; mf < 4; ++mf)
#pragma unroll
    for (int nf = 0; nf < 4; ++nf) {
      const int n = nb + nf * 16 + fr;
#pragma unroll
      for (int r = 0; r < 4; ++r) {
        const int m = mb + mf * 16 + fq * 4 + r;
        float v = acc[mf][nf][r];
        v = v > 0.f ? v : (__expf(v) - 1.f);
        hh[(size_t)((bz << 10) + m) * ldh + l * 1024 + n] = (bf16_t)v;
      }
    }
}

__global__ __launch_bounds__(256) void k_lin(const bf16_t* __restrict__ A, int lda,
                                             const bf16_t* __restrict__ B, int K,
                                             const float* __restrict__ bias, float* __restrict__ out) {
  MM_PROLOGUE();
  const int3 bi = xswz3();
  const int m0 = bi.y * 128, n0 = bi.x * 128;
  mm_bf16(A, lda, B, K, K, m0, n0, As, Bs, acc);
  MM_EPI_SETUP(m0, n0);
#pragma unroll
  for (int mf = 0; mf < 4; ++mf)
#pragma unroll
    for (int nf = 0; nf < 4; ++nf) {
      const int n = nb + nf * 16 + fr;
#pragma unroll
      for (int r = 0; r < 4; ++r) {
        const int m = mb + mf * 16 + fq * 4 + r;
        out[(size_t)m * 512 + n] = acc[mf][nf][r] + bias[n];
      }
    }
}

// fallback: Who (+)= hh @ out_W[:, l*1024:+1024].T (bias folded at l==0)
__global__ __launch_bounds__(256) void k_who_acc(const bf16_t* __restrict__ hh, const bf16_t* __restrict__ Wl,
                                                 const float* __restrict__ Wb, float* __restrict__ Who, int l) {
  MM_PROLOGUE();
  const int m0 = blockIdx.y * 128, n0 = blockIdx.x * 128;
  mm_bf16(hh, 1024, Wl, 3072, 1024, m0, n0, As, Bs, acc);
  MM_EPI_SETUP(m0, n0);
#pragma unroll
  for (int mf = 0; mf < 4; ++mf)
#pragma unroll
    for (int nf = 0; nf < 4; ++nf) {
      const int n = nb + nf * 16 + fr;
#pragma unroll
      for (int r = 0; r < 4; ++r) {
        const int m = mb + mf * 16 + fq * 4 + r;
        const size_t idx = (size_t)m * 512 + n;
        Who[idx] = acc[mf][nf][r] + (l == 0 ? Wb[n] : Who[idx]);
      }
    }
}

// ---------------- fused casts f32 -> bf16 (5 segments) ----------------
__global__ __launch_bounds__(256) void k_cast5(const float* __restrict__ s0, bf16_t* __restrict__ d0, int c0,
                                               const float* __restrict__ s1, bf16_t* __restrict__ d1, int c1,
                                               const float* __restrict__ s2, bf16_t* __restrict__ d2, int c2,
                                               const float* __restrict__ s3, bf16_t* __restrict__ d3, int c3,
                                               const float* __restrict__ s4, bf16_t* __restrict__ d4, int c4) {
  int i = blockIdx.x * 256 + threadIdx.x;
  const float* src; bf16_t* dst; int j;
  if (i < c0)      { src = s0; dst = d0; j = i; }
  else if (i < c1) { src = s1; dst = d1; j = i - c0; }
  else if (i < c2) { src = s2; dst = d2; j = i - c1; }
  else if (i < c3) { src = s3; dst = d3; j = i - c2; }
  else if (i < c4) { src = s4; dst = d4; j = i - c3; }
  else return;
  float4 v = ((const float4*)src)[j];
  union { ushort4 u; bf16_t b[4]; } p;
  p.b[0] = (bf16_t)v.x; p.b[1] = (bf16_t)v.y; p.b[2] = (bf16_t)v.z; p.b[3] = (bf16_t)v.w;
  ((ushort4*)dst)[j] = p.u;
}

// ---------------- algebraic e1/e2 ----------------
__global__ __launch_bounds__(256) void k_wvec(const bf16_t* __restrict__ gatwb,
                                              const float* __restrict__ gWb,
                                              const float* __restrict__ ai, const float* __restrict__ aib,
                                              const float* __restrict__ aj, const float* __restrict__ ajb,
                                              float* __restrict__ wv, float* __restrict__ con) {
  __shared__ float sred[4][64];
  __shared__ float cred[256];
  const int v = blockIdx.y, l = v >> 1;
  const float* avec = ((v & 1) ? aj : ai) + (l << 10);
  const bf16_t* W = gatwb + ((size_t)(l << 10)) * 512;
  const int tid = threadIdx.x, hg = tid >> 6, cc = tid & 63;
  const int c = blockIdx.x * 64 + cc;
  float p = 0.f;
  for (int i = 0; i < 256; ++i) {
    const int h = hg * 256 + i;
    p = fmaf((float)W[(size_t)h * 512 + c], avec[h], p);
  }
  sred[hg][cc] = p;
  float cp = 0.f;
#pragma unroll
  for (int i = 0; i < 4; ++i) cp = fmaf(gWb[(l << 10) + tid + i * 256], avec[tid + i * 256], cp);
  cred[tid] = cp;
  __syncthreads();
  if (tid < 64) wv[v * 512 + blockIdx.x * 64 + tid] = sred[0][tid] + sred[1][tid] + sred[2][tid] + sred[3][tid];
  for (int s = 128; s > 0; s >>= 1) {
    if (tid < s) cred[tid] += cred[tid + s];
    __syncthreads();
  }
  if (tid == 0 && blockIdx.x == 0) con[v] = cred[0] + ((v & 1) ? ajb[l] : aib[l]);
}

__global__ __launch_bounds__(256) void k_e12v(const bf16_t* __restrict__ xb,
                                              const float* __restrict__ wv, const float* __restrict__ con,
                                              float* __restrict__ ev) {
  const int tid = threadIdx.x, lane = tid & 63, wid = tid >> 6;
  const int row = blockIdx.x * 4 + wid;
  bf16x8 xv = *(const bf16x8*)(xb + (size_t)row * 512 + lane * 8);
  float xf[8];
#pragma unroll
  for (int j = 0; j < 8; ++j) xf[j] = (float)xv[j];
  float s[6];
#pragma unroll
  for (int v = 0; v < 6; ++v) {
    const float* wp = wv + v * 512 + lane * 8;
    float a = 0.f;
#pragma unroll
    for (int j = 0; j < 8; ++j) a = fmaf(xf[j], wp[j], a);
    s[v] = a;
  }
#pragma unroll
  for (int v = 0; v < 6; ++v)
#pragma unroll
    for (int off = 32; off > 0; off >>= 1) s[v] += __shfl_xor(s[v], off);
  if (lane == 0) {
#pragma unroll
    for (int v = 0; v < 6; ++v) ev[v * 8192 + row] = s[v] + con[v];
  }
}

__global__ __launch_bounds__(256) void k_eo(const float* __restrict__ Who,
                                            const float* __restrict__ ai, const float* __restrict__ aib,
                                            const float* __restrict__ aj, const float* __restrict__ ajb,
                                            float* __restrict__ eo1, float* __restrict__ eo2) {
  const int wid = threadIdx.x >> 6, lane = threadIdx.x & 63;
  const int row = blockIdx.x * 4 + wid;
  const float* wr = Who + (size_t)row * 512;
  float s1 = 0.f, s2 = 0.f;
#pragma unroll
  for (int c = 0; c < 2; ++c) {
    const int idx = c * 256 + lane * 4;
    float4 w4 = *(const float4*)&wr[idx];
    float4 a4 = *(const float4*)&ai[idx];
    float4 b4 = *(const float4*)&aj[idx];
    s1 += w4.x * a4.x + w4.y * a4.y + w4.z * a4.z + w4.w * a4.w;
    s2 += w4.x * b4.x + w4.y * b4.y + w4.z * b4.z + w4.w * b4.w;
  }
#pragma unroll
  for (int off = 32; off > 0; off >>= 1) { s1 += __shfl_xor(s1, off); s2 += __shfl_xor(s2, off); }
  if (lane == 0) { eo1[row] = s1 + aib[0]; eo2[row] = s2 + ajb[0]; }
}

// ---------------- block reduce helpers (fallback kernels) ----------------
__device__ __forceinline__ float block_max(float v, float* red) {
#pragma unroll
  for (int off = 32; off > 0; off >>= 1) v = fmaxf(v, __shfl_xor(v, off));
  __syncthreads();
  if ((threadIdx.x & 63) == 0) red[threadIdx.x >> 6] = v;
  __syncthreads();
  return fmaxf(fmaxf(red[0], red[1]), fmaxf(red[2], red[3]));
}
__device__ __forceinline__ float block_sum(float v, float* red) {
#pragma unroll
  for (int off = 32; off > 0; off >>= 1) v += __shfl_xor(v, off);
  __syncthreads();
  if ((threadIdx.x & 63) == 0) red[threadIdx.x >> 6] = v;
  __syncthreads();
  return red[0] + red[1] + red[2] + red[3];
}

// ---------------- GAT attention rows: wave-per-row, all 3 layers, no barriers ----------------
__global__ __launch_bounds__(256) void k_gat_att3(const float* __restrict__ adj, const float* __restrict__ ev,
                                                  bf16_t* __restrict__ att) {
  const int lane = threadIdx.x & 63;
  const int row = blockIdx.x * 4 + (threadIdx.x >> 6);
  const int b = row >> 10;
  const float* arow = adj + (size_t)row * 1024;
  float a[4][4];
#pragma unroll
  for (int c = 0; c < 4; ++c) *(float4*)a[c] = *(const float4*)&arow[(c * 64 + lane) * 4];
#pragma unroll
  for (int l = 0; l < 3; ++l) {
    const float e1v = ev[l * 16384 + row];
    const float* e2r = ev + l * 16384 + 8192 + (b << 10);
    bf16_t* aout = att + (size_t)l * 8388608 + (size_t)row * 1024;
    float s[4][4];
    float mx = -1e30f;
#pragma unroll
    for (int c = 0; c < 4; ++c) {
      float4 e4 = *(const float4*)&e2r[(c * 64 + lane) * 4];
      float ee[4] = {e4.x, e4.y, e4.z, e4.w};
#pragma unroll
      for (int j = 0; j < 4; ++j) {
        float e = e1v + ee[j];
        e = e > 0.f ? e : 0.2f * e;
        s[c][j] = a[c][j] * e;
        mx = fmaxf(mx, s[c][j]);
      }
    }
#pragma unroll
    for (int off = 32; off > 0; off >>= 1) mx = fmaxf(mx, __shfl_xor(mx, off));
    float sum = 0.f;
#pragma unroll
    for (int c = 0; c < 4; ++c)
#pragma unroll
      for (int j = 0; j < 4; ++j) { float p = __expf(s[c][j] - mx); s[c][j] = p; sum += p; }
#pragma unroll
    for (int off = 32; off > 0; off >>= 1) sum += __shfl_xor(sum, off);
    const float inv = 1.f / sum;
#pragma unroll
    for (int c = 0; c < 4; ++c) {
      union { ushort4 u; bf16_t q[4]; } pk;
#pragma unroll
      for (int j = 0; j < 4; ++j) pk.q[j] = (bf16_t)(s[c][j] * inv);
      *(ushort4*)(aout + (c * 64 + lane) * 4) = pk.u;
    }
  }
}

// fallback single-layer version (block-per-row)
__global__ __launch_bounds__(256) void k_gat_att(const float* __restrict__ adj, const float* __restrict__ ev,
                                                 bf16_t* __restrict__ att) {
  __shared__ float red[4];
  const int row = blockIdx.x;
  const int b = row >> 10;
  const float* arow = adj + (size_t)row * 1024;
  const float e1v = ev[row];
  const float* e2r = ev + 8192 + (b << 10);
  float s[4];
  float mx = -1e30f;
#pragma unroll
  for (int c = 0; c < 4; ++c) {
    const int m = c * 256 + threadIdx.x;
    float e = e1v + e2r[m];
    e = e > 0.f ? e : 0.2f * e;
    s[c] = arow[m] * e;
    mx = fmaxf(mx, s[c]);
  }
  mx = block_max(mx, red);
  float sum = 0.f;
#pragma unroll
  for (int c = 0; c < 4; ++c) { float p = __expf(s[c] - mx); s[c] = p; sum += p; }
  sum = block_sum(sum, red);
  const float inv = 1.f / sum;
#pragma unroll
  for (int c = 0; c < 4; ++c) att[(size_t)row * 1024 + c * 256 + threadIdx.x] = (bf16_t)(s[c] * inv);
}

// ---------------- output-attention mask: wave-per-row double softmax ----------------
// max(softmax(row)) == 1/sum analytically -> second max reduction is free.
__global__ __launch_bounds__(256) void k_mask(const float* __restrict__ adj, const float* __restrict__ eo1,
                                              const float* __restrict__ eo2, bf16_t* __restrict__ mask) {
  const int lane = threadIdx.x & 63;
  const int row = blockIdx.x * 4 + (threadIdx.x >> 6);
  const int b = row >> 10;
  const float* arow = adj + (size_t)row * 1024;
  const float t1 = eo1[row];
  const float* eor = eo2 + (b << 10);
  float s[4][4];
  float mx = -1e30f;
#pragma unroll
  for (int c = 0; c < 4; ++c) {
    float4 a4 = *(const float4*)&arow[(c * 64 + lane) * 4];
    float4 e4 = *(const float4*)&eor[(c * 64 + lane) * 4];
    float aa[4] = {a4.x, a4.y, a4.z, a4.w};
    float ee[4] = {e4.x, e4.y, e4.z, e4.w};
#pragma unroll
    for (int j = 0; j < 4; ++j) {
      float e = t1 + ee[j];
      e = e > 0.f ? e : 0.2f * e;
      s[c][j] = aa[j] * e;
      mx = fmaxf(mx, s[c][j]);
    }
  }
#pragma unroll
  for (int off = 32; off > 0; off >>= 1) mx = fmaxf(mx, __shfl_xor(mx, off));
  float sum = 0.f;
#pragma unroll
  for (int c = 0; c < 4; ++c)
#pragma unroll
    for (int j = 0; j < 4; ++j) { float p = __expf(s[c][j] - mx); s[c][j] = p; sum += p; }
#pragma unroll
  for (int off = 32; off > 0; off >>= 1) sum += __shfl_xor(sum, off);
  const float inv = 1.f / sum;        // == max of first softmax
  float sum2 = 0.f;
#pragma unroll
  for (int c = 0; c < 4; ++c)
#pragma unroll
    for (int j = 0; j < 4; ++j) { float p = __expf(s[c][j] * inv - inv); s[c][j] = p; sum2 += p; }
#pragma unroll
  for (int off = 32; off > 0; off >>= 1) sum2 += __shfl_xor(sum2, off);
  const float inv2 = 1.f / sum2;
#pragma unroll
  for (int c = 0; c < 4; ++c) {
    union { ushort4 u; bf16_t q[4]; } pk;
#pragma unroll
    for (int j = 0; j < 4; ++j) pk.q[j] = (bf16_t)(s[c][j] * inv2);
    *(ushort4*)(mask + (size_t)row * 1024 + (c * 64 + lane) * 4) = pk.u;
  }
}

// ---------------- mask transpose ----------------
__global__ __launch_bounds__(256) void k_mtr(const bf16_t* __restrict__ in, bf16_t* __restrict__ out) {
  __shared__ bf16_t T[64][72];
  const int q0 = blockIdx.x * 64, k0 = blockIdx.y * 64, b = blockIdx.z;
  const bf16_t* src = in + ((size_t)b << 20);
  bf16_t* dst = out + ((size_t)b << 20);
  const int r = threadIdx.x >> 2, c = (threadIdx.x & 3) * 16;
  bf16x8 a0 = *(const bf16x8*)(src + (size_t)(q0 + r) * 1024 + k0 + c);
  bf16x8 a1 = *(const bf16x8*)(src + (size_t)(q0 + r) * 1024 + k0 + c + 8);
  *(bf16x8*)&T[r][c] = a0;
  *(bf16x8*)&T[r][c + 8] = a1;
  __syncthreads();
  union { bf16x8 v[2]; bf16_t e[16]; } o;
#pragma unroll
  for (int j = 0; j < 16; ++j) o.e[j] = T[c + j][r];
  *(bf16x8*)(dst + (size_t)(k0 + r) * 1024 + q0 + c) = o.v[0];
  *(bf16x8*)(dst + (size_t)(k0 + r) * 1024 + q0 + c + 8) = o.v[1];
}

// ---------------- MFMA flash attention (XOR-swizzled K/V + P LDS) ----------------
__device__ __forceinline__ int swz(int row, int slot) { return row * 64 + ((slot ^ (row & 7)) << 3); }

__global__ __launch_bounds__(256) void k_flash(const bf16_t* __restrict__ qg, const bf16_t* __restrict__ kg,
                                               const bf16_t* __restrict__ vTg, const bf16_t* __restrict__ maskT,
                                               bf16_t* __restrict__ aout) {
  __shared__ __align__(16) bf16_t Ks[4096];
  __shared__ __align__(16) bf16_t Vs[4096];
  __shared__ __align__(16) bf16_t PL[4][1024];   // per-wave 16x64, swizzled
  const int tid = threadIdx.x, lane = tid & 63, w = tid >> 6;
  const int fr = lane & 15, fq = lane >> 4;
  const int3 bi = xswz3();
  const int n0 = bi.x * 64, hh = bi.y, bb = bi.z;
  const size_t bh = ((size_t)bb * 8 + hh) << 16;
  const bf16_t* q = qg + bh;
  const bf16_t* kk = kg + bh;
  const bf16_t* vT = vTg + bh;
  const bf16_t* mT = maskT + ((size_t)bb << 20);
  bf16_t* PLw = &PL[w][0];

  bf16x8 qf[2];
#pragma unroll
  for (int ks = 0; ks < 2; ++ks)
    qf[ks] = *(const bf16x8*)(q + (size_t)(n0 + w * 16 + fr) * 64 + ks * 32 + fq * 8);

  f32x4 o[4];
#pragma unroll
  for (int nf = 0; nf < 4; ++nf) o[nf] = (f32x4)0.0f;
  float psum[4] = {0.f, 0.f, 0.f, 0.f};

  const int srow = tid >> 2, sslot = (tid & 3) * 2;
  const int ws0 = swz(srow, sslot), ws1 = swz(srow, sslot + 1);
  const int scol = (tid & 3) * 16;

  for (int c = 0; c < 16; ++c) {
    const int k0 = c * 64;
    bf16x8 kv0 = *(const bf16x8*)(kk + (size_t)(k0 + srow) * 64 + scol);
    bf16x8 kv1 = *(const bf16x8*)(kk + (size_t)(k0 + srow) * 64 + scol + 8);
    bf16x8 vv0 = *(const bf16x8*)(vT + (size_t)srow * 1024 + k0 + scol);
    bf16x8 vv1 = *(const bf16x8*)(vT + (size_t)srow * 1024 + k0 + scol + 8);
    union { ushort4 u; bf16_t h[4]; } mfr[4];
#pragma unroll
    for (int nf = 0; nf < 4; ++nf)
      mfr[nf].u = *(const ushort4*)(mT + (size_t)(k0 + nf * 16 + fr) * 1024 + n0 + w * 16 + fq * 4);
    __syncthreads();
    *(bf16x8*)&Ks[ws0] = kv0; *(bf16x8*)&Ks[ws1] = kv1;
    *(bf16x8*)&Vs[ws0] = vv0; *(bf16x8*)&Vs[ws1] = vv1;
    __syncthreads();

    f32x4 s[4];
#pragma unroll
    for (int nf = 0; nf < 4; ++nf) s[nf] = (f32x4)0.0f;
#pragma unroll
    for (int ks = 0; ks < 2; ++ks) {
      bf16x8 kf[4];
#pragma unroll
      for (int nf = 0; nf < 4; ++nf)
        kf[nf] = *(const bf16x8*)&Ks[swz(nf * 16 + fr, ks * 4 + fq)];
#pragma unroll
      for (int nf = 0; nf < 4; ++nf)
        s[nf] = __builtin_amdgcn_mfma_f32_16x16x32_bf16(qf[ks], kf[nf], s[nf], 0, 0, 0);
    }

#pragma unroll
    for (int nf = 0; nf < 4; ++nf)
#pragma unroll
      for (int r = 0; r < 4; ++r) {
        const float p = __expf(s[nf][r] * (float)mfr[nf].h[r]);
        psum[r] += p;
        const int pp = fq * 4 + r, e = nf * 16 + fr;
        PLw[pp * 64 + ((((e >> 3) ^ (pp & 7))) << 3) + (e & 7)] = (bf16_t)p;
      }

#pragma unroll
    for (int ks = 0; ks < 2; ++ks) {
      bf16x8 pf = *(const bf16x8*)&PLw[swz(fr, ks * 4 + fq)];
      bf16x8 vf[4];
#pragma unroll
      for (int nfo = 0; nfo < 4; ++nfo)
        vf[nfo] = *(const bf16x8*)&Vs[swz(nfo * 16 + fr, ks * 4 + fq)];
#pragma unroll
      for (int nfo = 0; nfo < 4; ++nfo)
        o[nfo] = __builtin_amdgcn_mfma_f32_16x16x32_bf16(pf, vf[nfo], o[nfo], 0, 0, 0);
    }
  }

#pragma unroll
  for (int r = 0; r < 4; ++r) {
    psum[r] += __shfl_xor(psum[r], 1);
    psum[r] += __shfl_xor(psum[r], 2);
    psum[r] += __shfl_xor(psum[r], 4);
    psum[r] += __shfl_xor(psum[r], 8);
  }
#pragma unroll
  for (int r = 0; r < 4; ++r) {
    const int tok = n0 + w * 16 + fq * 4 + r;
    const float inv = 1.f / psum[r];
#pragma unroll
    for (int nfo = 0; nfo < 4; ++nfo)
      aout[((size_t)(bb << 10) + tok) * 512 + hh * 64 + nfo * 16 + fr] = (bf16_t)(o[nfo][r] * inv);
  }
}

// ---------------- launcher ----------------
extern "C" void kernel_launch(void* const* d_in, const int* in_sizes, int n_in,
                              void* d_out, int out_size, void* d_ws, size_t ws_size,
                              hipStream_t stream) {
  (void)in_sizes; (void)n_in; (void)out_size;
  const float* x        = (const float*)d_in[0];
  const float* adj      = (const float*)d_in[1];
  const float* qkv_w    = (const float*)d_in[2];
  const float* proj_w   = (const float*)d_in[3];
  const float* proj_b   = (const float*)d_in[4];
  const float* gat_W    = (const float*)d_in[5];
  const float* gat_Wb   = (const float*)d_in[6];
  const float* gat_ai   = (const float*)d_in[7];
  const float* gat_ai_b = (const float*)d_in[8];
  const float* gat_aj   = (const float*)d_in[9];
  const float* gat_aj_b = (const float*)d_in[10];
  const float* out_W    = (const float*)d_in[11];
  const float* out_Wb   = (const float*)d_in[12];
  const float* out_ai   = (const float*)d_in[13];
  const float* out_ai_b = (const float*)d_in[14];
  const float* out_aj   = (const float*)d_in[15];
  const float* out_aj_b = (const float*)d_in[16];

  char* p = (char*)d_ws;
  auto alloc = [&](size_t bytes) { char* r = p; p += (bytes + 255) & ~(size_t)255; return r; };
  bf16_t* xb     = (bf16_t*)alloc(8192ull * 512 * 2);
  bf16_t* qkvwb  = (bf16_t*)alloc(1536ull * 512 * 2);
  bf16_t* gatwb  = (bf16_t*)alloc(3072ull * 512 * 2);
  bf16_t* outwb  = (bf16_t*)alloc(512ull * 3072 * 2);
  bf16_t* projwb = (bf16_t*)alloc(512ull * 512 * 2);
  bf16_t* qb     = (bf16_t*)alloc(8ull * 8 * 1024 * 64 * 2);
  bf16_t* kb     = (bf16_t*)alloc(8ull * 8 * 1024 * 64 * 2);
  bf16_t* vT     = (bf16_t*)alloc(8ull * 8 * 64 * 1024 * 2);
  float*  Who    = (float*)alloc(8192ull * 512 * 4);
  float*  wv     = (float*)alloc(6 * 512 * 4);
  float*  con    = (float*)alloc(256);
  float*  ev     = (float*)alloc(6 * 8192 * 4);
  float*  eo1    = (float*)alloc(8192 * 4);
  float*  eo2    = (float*)alloc(8192 * 4);

  const bool big = ws_size >= 211000000ull;

  const dim3 blk(256);
  k_cast5<<<8192, blk, 0, stream>>>(x, xb, 1048576, qkv_w, qkvwb, 1245184, gat_W, gatwb, 1638400,
                                    out_W, outwb, 2031616, proj_w, projwb, 2097152);
  k_wvec<<<dim3(8, 6), blk, 0, stream>>>(gatwb, gat_Wb, gat_ai, gat_ai_b, gat_aj, gat_aj_b, wv, con);
  k_e12v<<<2048, blk, 0, stream>>>(xb, wv, con, ev);
  k_qkv<<<dim3(12, 64), blk, 0, stream>>>(xb, qkvwb, qb, kb, vT);

  if (big) {
    bf16_t* WhT3 = (bf16_t*)alloc(3ull * 8 * 1024 * 1024 * 2);
    bf16_t* att3 = (bf16_t*)alloc(3ull * 8 * 1024 * 1024 * 2);
    bf16_t* hh3  = (bf16_t*)alloc(8192ull * 3072 * 2);
    bf16_t* mask  = att3;
    bf16_t* maskT = att3 + 8388608;
    bf16_t* aoutb = att3 + 2 * 8388608;

    k_wh<<<dim3(8, 64, 3), blk, 0, stream>>>(xb, gatwb, gat_Wb, WhT3);
    k_gat_att3<<<2048, blk, 0, stream>>>(adj, ev, att3);
    k_hhat<<<dim3(8, 8, 24), blk, 0, stream>>>(att3, WhT3, hh3, 3072);
    k_lin<<<dim3(4, 64), blk, 0, stream>>>(hh3, 3072, outwb, 3072, out_Wb, Who);
    k_eo<<<2048, blk, 0, stream>>>(Who, out_ai, out_ai_b, out_aj, out_aj_b, eo1, eo2);
    k_mask<<<2048, blk, 0, stream>>>(adj, eo1, eo2, mask);
    k_mtr<<<dim3(16, 16, 8), blk, 0, stream>>>(mask, maskT);
    k_flash<<<dim3(16, 8, 8), blk, 0, stream>>>(qb, kb, vT, maskT, aoutb);
    k_lin<<<dim3(4, 64), blk, 0, stream>>>(aoutb, 512, projwb, 512, proj_b, (float*)d_out);
  } else {
    bf16_t* WhT   = (bf16_t*)alloc(8ull * 1024 * 1024 * 2);
    bf16_t* att   = (bf16_t*)alloc(8ull * 1024 * 1024 * 2);
    bf16_t* hh    = (bf16_t*)alloc(8192ull * 1024 * 2);
    bf16_t* aoutb = (bf16_t*)alloc(8192ull * 512 * 2);
    bf16_t* maskT = (bf16_t*)alloc(8ull * 1024 * 1024 * 2);
    bf16_t* mask  = att;

    for (int l = 0; l < 3; ++l) {
      k_wh<<<dim3(8, 64, 1), blk, 0, stream>>>(xb, gatwb + (size_t)l * 524288, gat_Wb + l * 1024, WhT);
      k_gat_att<<<8192, blk, 0, stream>>>(adj, ev + (size_t)l * 16384, att);
      k_hhat<<<dim3(8, 8, 8), blk, 0, stream>>>(att, WhT, hh, 1024);
      k_who_acc<<<dim3(4, 64), blk, 0, stream>>>(hh, outwb + l * 1024, out_Wb, Who, l);
    }
    k_eo<<<2048, blk, 0, stream>>>(Who, out_ai, out_ai_b, out_aj, out_aj_b, eo1, eo2);
    k_mask<<<2048, blk, 0, stream>>>(adj, eo1, eo2, mask);
    k_mtr<<<dim3(16, 16, 8), blk, 0, stream>>>(mask, maskT);
    k_flash<<<dim3(16, 8, 8), blk, 0, stream>>>(qb, kb, vT, maskT, aoutb);
    k_lin<<<dim3(4, 64), blk, 0, stream>>>(aoutb, 512, projwb, 512, proj_b, (float*)d_out);
  }
}

// Round 10
// 279.925 us; speedup vs baseline: 7.1729x; 1.1695x over previous
//
#include <hip/hip_runtime.h>
#include <math.h>
#include <stdint.h>

#define SCALEQ 0.125f

typedef __bf16 bf16_t;
typedef __bf16 bf16x8 __attribute__((ext_vector_type(8)));
typedef float f32x4 __attribute__((ext_vector_type(4)));

// global -> LDS async copy, 16B per lane. LDS dest is wave-uniform base + lane*16.
#define GLOAD_LDS16(gsrc, ldst)                                                   \
  __builtin_amdgcn_global_load_lds(                                               \
      (const __attribute__((address_space(1))) void*)(uintptr_t)(const void*)(gsrc), \
      (__attribute__((address_space(3))) void*)(uintptr_t)(void*)(ldst), 16, 0, 0)

// XCD-chunked bijective block swizzle (grid total must be %8==0).
__device__ __forceinline__ int3 xswz3() {
  const int nx = gridDim.x, ny = gridDim.y;
  int lin = (blockIdx.z * ny + blockIdx.y) * nx + blockIdx.x;
  const int n = nx * ny * gridDim.z;
  int work = (lin & 7) * (n >> 3) + (lin >> 3);
  int3 r;
  r.x = work % nx; work /= nx;
  r.y = work % ny; r.z = work / ny;
  return r;
}

// ---------------- bf16 MFMA GEMM core (128x128 tile, 4 waves, BK=64) ----------------
// Rule-#21 XOR swizzle: linear LDS dest, per-lane global SOURCE chunk permuted,
// reads apply the same involution. 16-way -> 8-way ds_read_b128 conflicts.
__device__ __forceinline__ void mm_bf16(const bf16_t* __restrict__ A, int lda,
                                        const bf16_t* __restrict__ B, int ldb,
                                        int K, int m0, int n0,
                                        bf16_t* As, bf16_t* Bs, f32x4 (&acc)[4][4]) {
  const int tid = threadIdx.x, lane = tid & 63, w = tid >> 6;
  const int wr = (w >> 1) * 64, wc = (w & 1) * 64;
  const int fr = lane & 15, fq = lane >> 4;
  const int c8 = (((lane & 7) ^ ((lane >> 3) & 7)) * 8);   // swizzled source chunk
  for (int kt = 0; kt < K; kt += 64) {
    __syncthreads();
#pragma unroll
    for (int t = 0; t < 4; ++t) {
      const int rl = t * 32 + w * 8 + (lane >> 3);
      GLOAD_LDS16(A + (size_t)(m0 + rl) * lda + kt + c8, As + (t * 32 + w * 8) * 64);
      GLOAD_LDS16(B + (size_t)(n0 + rl) * ldb + kt + c8, Bs + (t * 32 + w * 8) * 64);
    }
    __syncthreads();
#pragma unroll
    for (int ks = 0; ks < 2; ++ks) {
      bf16x8 af[4], bfv[4];
      const int ch = (((ks * 4 + fq) ^ (fr & 7)) << 3);
#pragma unroll
      for (int mf = 0; mf < 4; ++mf)
        af[mf] = *(const bf16x8*)(As + (wr + mf * 16 + fr) * 64 + ch);
#pragma unroll
      for (int nf = 0; nf < 4; ++nf)
        bfv[nf] = *(const bf16x8*)(Bs + (wc + nf * 16 + fr) * 64 + ch);
#pragma unroll
      for (int mf = 0; mf < 4; ++mf)
#pragma unroll
        for (int nf = 0; nf < 4; ++nf)
          acc[mf][nf] = __builtin_amdgcn_mfma_f32_16x16x32_bf16(af[mf], bfv[nf], acc[mf][nf], 0, 0, 0);
    }
  }
}

#define MM_PROLOGUE()                                  \
  __shared__ __align__(16) bf16_t As[128 * 64];        \
  __shared__ __align__(16) bf16_t Bs[128 * 64];        \
  f32x4 acc[4][4];                                     \
  _Pragma("unroll") for (int i_ = 0; i_ < 4; ++i_)     \
  _Pragma("unroll") for (int j_ = 0; j_ < 4; ++j_) acc[i_][j_] = (f32x4)0.0f;

#define MM_EPI_SETUP(M0, N0)                                   \
  const int lane = threadIdx.x & 63, w = threadIdx.x >> 6;     \
  const int fr = lane & 15, fq = lane >> 4;                    \
  const int mb = (M0) + (w >> 1) * 64, nb = (N0) + (w & 1) * 64;

// ---------------- GEMM kernels ----------------
__global__ __launch_bounds__(256) void k_qkv(const bf16_t* __restrict__ xb, const bf16_t* __restrict__ wb,
                                             bf16_t* __restrict__ qb, bf16_t* __restrict__ kb,
                                             bf16_t* __restrict__ vT) {
  MM_PROLOGUE();
  const int3 bi = xswz3();
  const int m0 = bi.y * 128, n0 = bi.x * 128;
  mm_bf16(xb, 512, wb, 512, 512, m0, n0, As, Bs, acc);
  MM_EPI_SETUP(m0, n0);
#pragma unroll
  for (int mf = 0; mf < 4; ++mf)
#pragma unroll
    for (int nf = 0; nf < 4; ++nf) {
      const int n = nb + nf * 16 + fr;
      const int which = n >> 9, hd = (n >> 6) & 7, d = n & 63;
      const int m_ = mb + mf * 16 + fq * 4;
      const int b = m_ >> 10, tok0 = m_ & 1023;
      if (which == 2) {
        union { ushort4 u; bf16_t q[4]; } pk;
#pragma unroll
        for (int r = 0; r < 4; ++r) pk.q[r] = (bf16_t)acc[mf][nf][r];
        *(ushort4*)(vT + (((size_t)b * 8 + hd) * 64 + d) * 1024 + tok0) = pk.u;
      } else {
        bf16_t* dst = which ? kb : qb;
        const float sc = which ? 1.f : SCALEQ;
#pragma unroll
        for (int r = 0; r < 4; ++r)
          dst[(((size_t)b * 8 + hd) * 1024 + tok0 + r) * 64 + d] = (bf16_t)(acc[mf][nf][r] * sc);
      }
    }
}

__global__ __launch_bounds__(256) void k_wh(const bf16_t* __restrict__ xb, const bf16_t* __restrict__ gatw,
                                            const float* __restrict__ gWb, bf16_t* __restrict__ WhT) {
  MM_PROLOGUE();
  const int3 bi = xswz3();
  const int m0 = bi.y * 128, n0 = bi.x * 128, l = bi.z;
  const bf16_t* Wl = gatw + (size_t)l * 524288;
  const float* Wb = gWb + l * 1024;
  bf16_t* out = WhT + (size_t)l * 8388608;
  mm_bf16(xb, 512, Wl, 512, 512, m0, n0, As, Bs, acc);
  MM_EPI_SETUP(m0, n0);
#pragma unroll
  for (int mf = 0; mf < 4; ++mf)
#pragma unroll
    for (int nf = 0; nf < 4; ++nf) {
      const int h = nb + nf * 16 + fr;
      const float bias = Wb[h];
      const int m_ = mb + mf * 16 + fq * 4;
      const int b = m_ >> 10, ml = m_ & 1023;
      union { ushort4 u; bf16_t q[4]; } pk;
#pragma unroll
      for (int r = 0; r < 4; ++r) pk.q[r] = (bf16_t)(acc[mf][nf][r] + bias);
      *(ushort4*)(out + (((size_t)b << 10) + h) * 1024 + ml) = pk.u;
    }
}

// hh = elu(att_lb @ Wh_lb). Fused mode (wvo != nullptr): instead of writing hh,
// accumulate eo1/eo2 row-dots with wv7/wv8 (f32 pre-rounding elu values).
__global__ __launch_bounds__(256) void k_hhat(const bf16_t* __restrict__ att, const bf16_t* __restrict__ WhT,
                                              bf16_t* __restrict__ hh, int ldh,
                                              const float* __restrict__ wvo,
                                              float* __restrict__ eo1, float* __restrict__ eo2) {
  MM_PROLOGUE();
  const int3 bi = xswz3();
  const int m0 = bi.y * 128, n0 = bi.x * 128;
  const int l = bi.z >> 3, bz = bi.z & 7;
  const size_t off = ((size_t)(l * 8 + bz)) << 20;
  mm_bf16(att + off, 1024, WhT + off, 1024, 1024, m0, n0, As, Bs, acc);
  MM_EPI_SETUP(m0, n0);
  if (wvo != nullptr) {
    float w1[4], w2[4];
#pragma unroll
    for (int nf = 0; nf < 4; ++nf) {
      const int n = nb + nf * 16 + fr;
      w1[nf] = wvo[l * 1024 + n];
      w2[nf] = wvo[3072 + l * 1024 + n];
    }
#pragma unroll
    for (int mf = 0; mf < 4; ++mf)
#pragma unroll
      for (int r = 0; r < 4; ++r) {
        float s1 = 0.f, s2 = 0.f;
#pragma unroll
        for (int nf = 0; nf < 4; ++nf) {
          float v = acc[mf][nf][r];
          v = v > 0.f ? v : (__expf(v) - 1.f);
          s1 = fmaf(v, w1[nf], s1);
          s2 = fmaf(v, w2[nf], s2);
        }
        s1 += __shfl_xor(s1, 1); s1 += __shfl_xor(s1, 2); s1 += __shfl_xor(s1, 4); s1 += __shfl_xor(s1, 8);
        s2 += __shfl_xor(s2, 1); s2 += __shfl_xor(s2, 2); s2 += __shfl_xor(s2, 4); s2 += __shfl_xor(s2, 8);
        if (fr == 0) {
          const int m = (bz << 10) + mb + mf * 16 + fq * 4 + r;
          atomicAdd(&eo1[m], s1);
          atomicAdd(&eo2[m], s2);
        }
      }
  } else {
#pragma unroll
    for (int mf = 0; mf < 4; ++mf)
#pragma unroll
      for (int nf = 0; nf < 4; ++nf) {
        const int n = nb + nf * 16 + fr;
#pragma unroll
        for (int r = 0; r < 4; ++r) {
          const int m = mb + mf * 16 + fq * 4 + r;
          float v = acc[mf][nf][r];
          v = v > 0.f ? v : (__expf(v) - 1.f);
          hh[(size_t)((bz << 10) + m) * ldh + l * 1024 + n] = (bf16_t)v;
        }
      }
  }
}

__global__ __launch_bounds__(256) void k_lin(const bf16_t* __restrict__ A, int lda,
                                             const bf16_t* __restrict__ B, int K,
                                             const float* __restrict__ bias, float* __restrict__ out) {
  MM_PROLOGUE();
  const int3 bi = xswz3();
  const int m0 = bi.y * 128, n0 = bi.x * 128;
  mm_bf16(A, lda, B, K, K, m0, n0, As, Bs, acc);
  MM_EPI_SETUP(m0, n0);
#pragma unroll
  for (int mf = 0; mf < 4; ++mf)
#pragma unroll
    for (int nf = 0; nf < 4; ++nf) {
      const int n = nb + nf * 16 + fr;
#pragma unroll
      for (int r = 0; r < 4; ++r) {
        const int m = mb + mf * 16 + fq * 4 + r;
        out[(size_t)m * 512 + n] = acc[mf][nf][r] + bias[n];
      }
    }
}

// fallback: Who (+)= hh @ out_W[:, l*1024:+1024].T (bias folded at l==0)
__global__ __launch_bounds__(256) void k_who_acc(const bf16_t* __restrict__ hh, const bf16_t* __restrict__ Wl,
                                                 const float* __restrict__ Wb, float* __restrict__ Who, int l) {
  MM_PROLOGUE();
  const int m0 = blockIdx.y * 128, n0 = blockIdx.x * 128;
  mm_bf16(hh, 1024, Wl, 3072, 1024, m0, n0, As, Bs, acc);
  MM_EPI_SETUP(m0, n0);
#pragma unroll
  for (int mf = 0; mf < 4; ++mf)
#pragma unroll
    for (int nf = 0; nf < 4; ++nf) {
      const int n = nb + nf * 16 + fr;
#pragma unroll
      for (int r = 0; r < 4; ++r) {
        const int m = mb + mf * 16 + fq * 4 + r;
        const size_t idx = (size_t)m * 512 + n;
        Who[idx] = acc[mf][nf][r] + (l == 0 ? Wb[n] : Who[idx]);
      }
    }
}

// ---------------- fused casts f32 -> bf16 (5 segments) ----------------
__global__ __launch_bounds__(256) void k_cast5(const float* __restrict__ s0, bf16_t* __restrict__ d0, int c0,
                                               const float* __restrict__ s1, bf16_t* __restrict__ d1, int c1,
                                               const float* __restrict__ s2, bf16_t* __restrict__ d2, int c2,
                                               const float* __restrict__ s3, bf16_t* __restrict__ d3, int c3,
                                               const float* __restrict__ s4, bf16_t* __restrict__ d4, int c4) {
  int i = blockIdx.x * 256 + threadIdx.x;
  const float* src; bf16_t* dst; int j;
  if (i < c0)      { src = s0; dst = d0; j = i; }
  else if (i < c1) { src = s1; dst = d1; j = i - c0; }
  else if (i < c2) { src = s2; dst = d2; j = i - c1; }
  else if (i < c3) { src = s3; dst = d3; j = i - c2; }
  else if (i < c4) { src = s4; dst = d4; j = i - c3; }
  else return;
  float4 v = ((const float4*)src)[j];
  union { ushort4 u; bf16_t b[4]; } p;
  p.b[0] = (bf16_t)v.x; p.b[1] = (bf16_t)v.y; p.b[2] = (bf16_t)v.z; p.b[3] = (bf16_t)v.w;
  ((ushort4*)dst)[j] = p.u;
}

// ---------------- algebraic e1/e2 (gat layers) ----------------
__global__ __launch_bounds__(256) void k_wvec(const bf16_t* __restrict__ gatwb,
                                              const float* __restrict__ gWb,
                                              const float* __restrict__ ai, const float* __restrict__ aib,
                                              const float* __restrict__ aj, const float* __restrict__ ajb,
                                              float* __restrict__ wv, float* __restrict__ con) {
  __shared__ float sred[4][64];
  __shared__ float cred[256];
  const int v = blockIdx.y, l = v >> 1;
  const float* avec = ((v & 1) ? aj : ai) + (l << 10);
  const bf16_t* W = gatwb + ((size_t)(l << 10)) * 512;
  const int tid = threadIdx.x, hg = tid >> 6, cc = tid & 63;
  const int c = blockIdx.x * 64 + cc;
  float p = 0.f;
  for (int i = 0; i < 256; ++i) {
    const int h = hg * 256 + i;
    p = fmaf((float)W[(size_t)h * 512 + c], avec[h], p);
  }
  sred[hg][cc] = p;
  float cp = 0.f;
#pragma unroll
  for (int i = 0; i < 4; ++i) cp = fmaf(gWb[(l << 10) + tid + i * 256], avec[tid + i * 256], cp);
  cred[tid] = cp;
  __syncthreads();
  if (tid < 64) wv[v * 512 + blockIdx.x * 64 + tid] = sred[0][tid] + sred[1][tid] + sred[2][tid] + sred[3][tid];
  for (int s = 128; s > 0; s >>= 1) {
    if (tid < s) cred[tid] += cred[tid + s];
    __syncthreads();
  }
  if (tid == 0 && blockIdx.x == 0) con[v] = cred[0] + ((v & 1) ? ajb[l] : aib[l]);
}

// out-attention vectors: wvo[v][c] = sum_d out_W[d][c]*avec[d] (v=0:ai, 1:aj),
// conO[v] = dot(out_Wb, avec). wvo/conO must be zeroed beforehand.
__global__ __launch_bounds__(256) void k_wvec_o(const float* __restrict__ W, const float* __restrict__ Wb,
                                                const float* __restrict__ ai, const float* __restrict__ aj,
                                                float* __restrict__ wvo, float* __restrict__ conO) {
  const int c = blockIdx.x * 256 + threadIdx.x;     // 0..3071
  const int d0 = blockIdx.y * 64;                   // 8 chunks of 64
  float s1 = 0.f, s2 = 0.f;
  for (int t = 0; t < 64; ++t) {
    const float w = W[(size_t)(d0 + t) * 3072 + c];
    s1 = fmaf(w, ai[d0 + t], s1);
    s2 = fmaf(w, aj[d0 + t], s2);
  }
  atomicAdd(&wvo[c], s1);
  atomicAdd(&wvo[3072 + c], s2);
  if (blockIdx.x == 0 && threadIdx.x < 64) {
    const int d = d0 + threadIdx.x;
    float c1 = Wb[d] * ai[d], c2 = Wb[d] * aj[d];
#pragma unroll
    for (int off = 32; off > 0; off >>= 1) { c1 += __shfl_xor(c1, off); c2 += __shfl_xor(c2, off); }
    if (threadIdx.x == 0) { atomicAdd(&conO[0], c1); atomicAdd(&conO[1], c2); }
  }
}

__global__ __launch_bounds__(256) void k_e12v(const bf16_t* __restrict__ xb,
                                              const float* __restrict__ wv, const float* __restrict__ con,
                                              float* __restrict__ ev) {
  const int tid = threadIdx.x, lane = tid & 63, wid = tid >> 6;
  const int row = blockIdx.x * 4 + wid;
  bf16x8 xv = *(const bf16x8*)(xb + (size_t)row * 512 + lane * 8);
  float xf[8];
#pragma unroll
  for (int j = 0; j < 8; ++j) xf[j] = (float)xv[j];
  float s[6];
#pragma unroll
  for (int v = 0; v < 6; ++v) {
    const float* wp = wv + v * 512 + lane * 8;
    float a = 0.f;
#pragma unroll
    for (int j = 0; j < 8; ++j) a = fmaf(xf[j], wp[j], a);
    s[v] = a;
  }
#pragma unroll
  for (int v = 0; v < 6; ++v)
#pragma unroll
    for (int off = 32; off > 0; off >>= 1) s[v] += __shfl_xor(s[v], off);
  if (lane == 0) {
#pragma unroll
    for (int v = 0; v < 6; ++v) ev[v * 8192 + row] = s[v] + con[v];
  }
}

// fallback: raw row-dots (biases/constants added in k_mask via conO)
__global__ __launch_bounds__(256) void k_eo(const float* __restrict__ Who,
                                            const float* __restrict__ ai, const float* __restrict__ aj,
                                            float* __restrict__ eo1, float* __restrict__ eo2) {
  const int wid = threadIdx.x >> 6, lane = threadIdx.x & 63;
  const int row = blockIdx.x * 4 + wid;
  const float* wr = Who + (size_t)row * 512;
  float s1 = 0.f, s2 = 0.f;
#pragma unroll
  for (int c = 0; c < 2; ++c) {
    const int idx = c * 256 + lane * 4;
    float4 w4 = *(const float4*)&wr[idx];
    float4 a4 = *(const float4*)&ai[idx];
    float4 b4 = *(const float4*)&aj[idx];
    s1 += w4.x * a4.x + w4.y * a4.y + w4.z * a4.z + w4.w * a4.w;
    s2 += w4.x * b4.x + w4.y * b4.y + w4.z * b4.z + w4.w * b4.w;
  }
#pragma unroll
  for (int off = 32; off > 0; off >>= 1) { s1 += __shfl_xor(s1, off); s2 += __shfl_xor(s2, off); }
  if (lane == 0) { eo1[row] = s1; eo2[row] = s2; }
}

// ---------------- block reduce helpers (fallback kernels) ----------------
__device__ __forceinline__ float block_max(float v, float* red) {
#pragma unroll
  for (int off = 32; off > 0; off >>= 1) v = fmaxf(v, __shfl_xor(v, off));
  __syncthreads();
  if ((threadIdx.x & 63) == 0) red[threadIdx.x >> 6] = v;
  __syncthreads();
  return fmaxf(fmaxf(red[0], red[1]), fmaxf(red[2], red[3]));
}
__device__ __forceinline__ float block_sum(float v, float* red) {
#pragma unroll
  for (int off = 32; off > 0; off >>= 1) v += __shfl_xor(v, off);
  __syncthreads();
  if ((threadIdx.x & 63) == 0) red[threadIdx.x >> 6] = v;
  __syncthreads();
  return red[0] + red[1] + red[2] + red[3];
}

// ---------------- GAT attention rows: wave-per-row, all 3 layers, no barriers ----------------
__global__ __launch_bounds__(256) void k_gat_att3(const float* __restrict__ adj, const float* __restrict__ ev,
                                                  bf16_t* __restrict__ att) {
  const int lane = threadIdx.x & 63;
  const int row = blockIdx.x * 4 + (threadIdx.x >> 6);
  const int b = row >> 10;
  const float* arow = adj + (size_t)row * 1024;
  float a[4][4];
#pragma unroll
  for (int c = 0; c < 4; ++c) *(float4*)a[c] = *(const float4*)&arow[(c * 64 + lane) * 4];
#pragma unroll
  for (int l = 0; l < 3; ++l) {
    const float e1v = ev[l * 16384 + row];
    const float* e2r = ev + l * 16384 + 8192 + (b << 10);
    bf16_t* aout = att + (size_t)l * 8388608 + (size_t)row * 1024;
    float s[4][4];
    float mx = -1e30f;
#pragma unroll
    for (int c = 0; c < 4; ++c) {
      float4 e4 = *(const float4*)&e2r[(c * 64 + lane) * 4];
      float ee[4] = {e4.x, e4.y, e4.z, e4.w};
#pragma unroll
      for (int j = 0; j < 4; ++j) {
        float e = e1v + ee[j];
        e = e > 0.f ? e : 0.2f * e;
        s[c][j] = a[c][j] * e;
        mx = fmaxf(mx, s[c][j]);
      }
    }
#pragma unroll
    for (int off = 32; off > 0; off >>= 1) mx = fmaxf(mx, __shfl_xor(mx, off));
    float sum = 0.f;
#pragma unroll
    for (int c = 0; c < 4; ++c)
#pragma unroll
      for (int j = 0; j < 4; ++j) { float p = __expf(s[c][j] - mx); s[c][j] = p; sum += p; }
#pragma unroll
    for (int off = 32; off > 0; off >>= 1) sum += __shfl_xor(sum, off);
    const float inv = 1.f / sum;
#pragma unroll
    for (int c = 0; c < 4; ++c) {
      union { ushort4 u; bf16_t q[4]; } pk;
#pragma unroll
      for (int j = 0; j < 4; ++j) pk.q[j] = (bf16_t)(s[c][j] * inv);
      *(ushort4*)(aout + (c * 64 + lane) * 4) = pk.u;
    }
  }
}

// fallback single-layer version (block-per-row)
__global__ __launch_bounds__(256) void k_gat_att(const float* __restrict__ adj, const float* __restrict__ ev,
                                                 bf16_t* __restrict__ att) {
  __shared__ float red[4];
  const int row = blockIdx.x;
  const int b = row >> 10;
  const float* arow = adj + (size_t)row * 1024;
  const float e1v = ev[row];
  const float* e2r = ev + 8192 + (b << 10);
  float s[4];
  float mx = -1e30f;
#pragma unroll
  for (int c = 0; c < 4; ++c) {
    const int m = c * 256 + threadIdx.x;
    float e = e1v + e2r[m];
    e = e > 0.f ? e : 0.2f * e;
    s[c] = arow[m] * e;
    mx = fmaxf(mx, s[c]);
  }
  mx = block_max(mx, red);
  float sum = 0.f;
#pragma unroll
  for (int c = 0; c < 4; ++c) { float p = __expf(s[c] - mx); s[c] = p; sum += p; }
  sum = block_sum(sum, red);
  const float inv = 1.f / sum;
#pragma unroll
  for (int c = 0; c < 4; ++c) att[(size_t)row * 1024 + c * 256 + threadIdx.x] = (bf16_t)(s[c] * inv);
}

// ---------------- output-attention mask: wave-per-row double softmax ----------------
// eo1/eo2 are raw row sums; constants conO + biases added here.
__global__ __launch_bounds__(256) void k_mask(const float* __restrict__ adj, const float* __restrict__ eo1,
                                              const float* __restrict__ eo2, const float* __restrict__ conO,
                                              const float* __restrict__ aib, const float* __restrict__ ajb,
                                              bf16_t* __restrict__ mask) {
  const int lane = threadIdx.x & 63;
  const int row = blockIdx.x * 4 + (threadIdx.x >> 6);
  const int b = row >> 10;
  const float* arow = adj + (size_t)row * 1024;
  const float t1 = eo1[row] + conO[0] + aib[0];
  const float c2 = conO[1] + ajb[0];
  const float* eor = eo2 + (b << 10);
  float s[4][4];
  float mx = -1e30f;
#pragma unroll
  for (int c = 0; c < 4; ++c) {
    float4 a4 = *(const float4*)&arow[(c * 64 + lane) * 4];
    float4 e4 = *(const float4*)&eor[(c * 64 + lane) * 4];
    float aa[4] = {a4.x, a4.y, a4.z, a4.w};
    float ee[4] = {e4.x, e4.y, e4.z, e4.w};
#pragma unroll
    for (int j = 0; j < 4; ++j) {
      float e = t1 + ee[j] + c2;
      e = e > 0.f ? e : 0.2f * e;
      s[c][j] = aa[j] * e;
      mx = fmaxf(mx, s[c][j]);
    }
  }
#pragma unroll
  for (int off = 32; off > 0; off >>= 1) mx = fmaxf(mx, __shfl_xor(mx, off));
  float sum = 0.f;
#pragma unroll
  for (int c = 0; c < 4; ++c)
#pragma unroll
    for (int j = 0; j < 4; ++j) { float p = __expf(s[c][j] - mx); s[c][j] = p; sum += p; }
#pragma unroll
  for (int off = 32; off > 0; off >>= 1) sum += __shfl_xor(sum, off);
  const float inv = 1.f / sum;        // == max of first softmax
  float sum2 = 0.f;
#pragma unroll
  for (int c = 0; c < 4; ++c)
#pragma unroll
    for (int j = 0; j < 4; ++j) { float p = __expf(s[c][j] * inv - inv); s[c][j] = p; sum2 += p; }
#pragma unroll
  for (int off = 32; off > 0; off >>= 1) sum2 += __shfl_xor(sum2, off);
  const float inv2 = 1.f / sum2;
#pragma unroll
  for (int c = 0; c < 4; ++c) {
    union { ushort4 u; bf16_t q[4]; } pk;
#pragma unroll
    for (int j = 0; j < 4; ++j) pk.q[j] = (bf16_t)(s[c][j] * inv2);
    *(ushort4*)(mask + (size_t)row * 1024 + (c * 64 + lane) * 4) = pk.u;
  }
}

// ---------------- mask transpose ----------------
__global__ __launch_bounds__(256) void k_mtr(const bf16_t* __restrict__ in, bf16_t* __restrict__ out) {
  __shared__ bf16_t T[64][72];
  const int q0 = blockIdx.x * 64, k0 = blockIdx.y * 64, b = blockIdx.z;
  const bf16_t* src = in + ((size_t)b << 20);
  bf16_t* dst = out + ((size_t)b << 20);
  const int r = threadIdx.x >> 2, c = (threadIdx.x & 3) * 16;
  bf16x8 a0 = *(const bf16x8*)(src + (size_t)(q0 + r) * 1024 + k0 + c);
  bf16x8 a1 = *(const bf16x8*)(src + (size_t)(q0 + r) * 1024 + k0 + c + 8);
  *(bf16x8*)&T[r][c] = a0;
  *(bf16x8*)&T[r][c + 8] = a1;
  __syncthreads();
  union { bf16x8 v[2]; bf16_t e[16]; } o;
#pragma unroll
  for (int j = 0; j < 16; ++j) o.e[j] = T[c + j][r];
  *(bf16x8*)(dst + (size_t)(k0 + r) * 1024 + q0 + c) = o.v[0];
  *(bf16x8*)(dst + (size_t)(k0 + r) * 1024 + q0 + c + 8) = o.v[1];
}

// ---------------- MFMA flash attention (XOR-swizzled K/V + P LDS) ----------------
__device__ __forceinline__ int swz(int row, int slot) { return row * 64 + ((slot ^ (row & 7)) << 3); }

__global__ __launch_bounds__(256) void k_flash(const bf16_t* __restrict__ qg, const bf16_t* __restrict__ kg,
                                               const bf16_t* __restrict__ vTg, const bf16_t* __restrict__ maskT,
                                               bf16_t* __restrict__ aout) {
  __shared__ __align__(16) bf16_t Ks[4096];
  __shared__ __align__(16) bf16_t Vs[4096];
  __shared__ __align__(16) bf16_t PL[4][1024];   // per-wave 16x64, swizzled
  const int tid = threadIdx.x, lane = tid & 63, w = tid >> 6;
  const int fr = lane & 15, fq = lane >> 4;
  const int3 bi = xswz3();
  const int n0 = bi.x * 64, hh = bi.y, bb = bi.z;
  const size_t bh = ((size_t)bb * 8 + hh) << 16;
  const bf16_t* q = qg + bh;
  const bf16_t* kk = kg + bh;
  const bf16_t* vT = vTg + bh;
  const bf16_t* mT = maskT + ((size_t)bb << 20);
  bf16_t* PLw = &PL[w][0];

  bf16x8 qf[2];
#pragma unroll
  for (int ks = 0; ks < 2; ++ks)
    qf[ks] = *(const bf16x8*)(q + (size_t)(n0 + w * 16 + fr) * 64 + ks * 32 + fq * 8);

  f32x4 o[4];
#pragma unroll
  for (int nf = 0; nf < 4; ++nf) o[nf] = (f32x4)0.0f;
  float psum[4] = {0.f, 0.f, 0.f, 0.f};

  const int srow = tid >> 2, sslot = (tid & 3) * 2;
  const int ws0 = swz(srow, sslot), ws1 = swz(srow, sslot + 1);
  const int scol = (tid & 3) * 16;

  for (int c = 0; c < 16; ++c) {
    const int k0 = c * 64;
    bf16x8 kv0 = *(const bf16x8*)(kk + (size_t)(k0 + srow) * 64 + scol);
    bf16x8 kv1 = *(const bf16x8*)(kk + (size_t)(k0 + srow) * 64 + scol + 8);
    bf16x8 vv0 = *(const bf16x8*)(vT + (size_t)srow * 1024 + k0 + scol);
    bf16x8 vv1 = *(const bf16x8*)(vT + (size_t)srow * 1024 + k0 + scol + 8);
    union { ushort4 u; bf16_t h[4]; } mfr[4];
#pragma unroll
    for (int nf = 0; nf < 4; ++nf)
      mfr[nf].u = *(const ushort4*)(mT + (size_t)(k0 + nf * 16 + fr) * 1024 + n0 + w * 16 + fq * 4);
    __syncthreads();
    *(bf16x8*)&Ks[ws0] = kv0; *(bf16x8*)&Ks[ws1] = kv1;
    *(bf16x8*)&Vs[ws0] = vv0; *(bf16x8*)&Vs[ws1] = vv1;
    __syncthreads();

    f32x4 s[4];
#pragma unroll
    for (int nf = 0; nf < 4; ++nf) s[nf] = (f32x4)0.0f;
#pragma unroll
    for (int ks = 0; ks < 2; ++ks) {
      bf16x8 kf[4];
#pragma unroll
      for (int nf = 0; nf < 4; ++nf)
        kf[nf] = *(const bf16x8*)&Ks[swz(nf * 16 + fr, ks * 4 + fq)];
#pragma unroll
      for (int nf = 0; nf < 4; ++nf)
        s[nf] = __builtin_amdgcn_mfma_f32_16x16x32_bf16(qf[ks], kf[nf], s[nf], 0, 0, 0);
    }

#pragma unroll
    for (int nf = 0; nf < 4; ++nf)
#pragma unroll
      for (int r = 0; r < 4; ++r) {
        const float p = __expf(s[nf][r] * (float)mfr[nf].h[r]);
        psum[r] += p;
        const int pp = fq * 4 + r, e = nf * 16 + fr;
        PLw[pp * 64 + ((((e >> 3) ^ (pp & 7))) << 3) + (e & 7)] = (bf16_t)p;
      }

#pragma unroll
    for (int ks = 0; ks < 2; ++ks) {
      bf16x8 pf = *(const bf16x8*)&PLw[swz(fr, ks * 4 + fq)];
      bf16x8 vf[4];
#pragma unroll
      for (int nfo = 0; nfo < 4; ++nfo)
        vf[nfo] = *(const bf16x8*)&Vs[swz(nfo * 16 + fr, ks * 4 + fq)];
#pragma unroll
      for (int nfo = 0; nfo < 4; ++nfo)
        o[nfo] = __builtin_amdgcn_mfma_f32_16x16x32_bf16(pf, vf[nfo], o[nfo], 0, 0, 0);
    }
  }

#pragma unroll
  for (int r = 0; r < 4; ++r) {
    psum[r] += __shfl_xor(psum[r], 1);
    psum[r] += __shfl_xor(psum[r], 2);
    psum[r] += __shfl_xor(psum[r], 4);
    psum[r] += __shfl_xor(psum[r], 8);
  }
#pragma unroll
  for (int r = 0; r < 4; ++r) {
    const int tok = n0 + w * 16 + fq * 4 + r;
    const float inv = 1.f / psum[r];
#pragma unroll
    for (int nfo = 0; nfo < 4; ++nfo)
      aout[((size_t)(bb << 10) + tok) * 512 + hh * 64 + nfo * 16 + fr] = (bf16_t)(o[nfo][r] * inv);
  }
}

// ---------------- launcher ----------------
extern "C" void kernel_launch(void* const* d_in, const int* in_sizes, int n_in,
                              void* d_out, int out_size, void* d_ws, size_t ws_size,
                              hipStream_t stream) {
  (void)in_sizes; (void)n_in; (void)out_size;
  const float* x        = (const float*)d_in[0];
  const float* adj      = (const float*)d_in[1];
  const float* qkv_w    = (const float*)d_in[2];
  const float* proj_w   = (const float*)d_in[3];
  const float* proj_b   = (const float*)d_in[4];
  const float* gat_W    = (const float*)d_in[5];
  const float* gat_Wb   = (const float*)d_in[6];
  const float* gat_ai   = (const float*)d_in[7];
  const float* gat_ai_b = (const float*)d_in[8];
  const float* gat_aj   = (const float*)d_in[9];
  const float* gat_aj_b = (const float*)d_in[10];
  const float* out_W    = (const float*)d_in[11];
  const float* out_Wb   = (const float*)d_in[12];
  const float* out_ai   = (const float*)d_in[13];
  const float* out_ai_b = (const float*)d_in[14];
  const float* out_aj   = (const float*)d_in[15];
  const float* out_aj_b = (const float*)d_in[16];

  char* p = (char*)d_ws;
  auto alloc = [&](size_t bytes) { char* r = p; p += (bytes + 255) & ~(size_t)255; return r; };
  bf16_t* xb     = (bf16_t*)alloc(8192ull * 512 * 2);
  bf16_t* qkvwb  = (bf16_t*)alloc(1536ull * 512 * 2);
  bf16_t* gatwb  = (bf16_t*)alloc(3072ull * 512 * 2);
  bf16_t* outwb  = (bf16_t*)alloc(512ull * 3072 * 2);
  bf16_t* projwb = (bf16_t*)alloc(512ull * 512 * 2);
  bf16_t* qb     = (bf16_t*)alloc(8ull * 8 * 1024 * 64 * 2);
  bf16_t* kb     = (bf16_t*)alloc(8ull * 8 * 1024 * 64 * 2);
  bf16_t* vT     = (bf16_t*)alloc(8ull * 8 * 64 * 1024 * 2);
  float*  Who    = (float*)alloc(8192ull * 512 * 4);   // fallback only (dummy hh in big path)
  float*  wv     = (float*)alloc(6 * 512 * 4);
  float*  con    = (float*)alloc(256);
  float*  ev     = (float*)alloc(6 * 8192 * 4);
  // contiguous zero-init region: eo1, eo2, wvo, conO
  float*  eo1    = (float*)alloc(8192 * 4);
  float*  eo2    = (float*)alloc(8192 * 4);
  float*  wvo    = (float*)alloc(2 * 3072 * 4);
  float*  conO   = (float*)alloc(256);
  const size_t zspan = (size_t)((char*)conO - (char*)eo1) + 256;

  const bool big = ws_size >= 211000000ull;

  const dim3 blk(256);
  k_cast5<<<8192, blk, 0, stream>>>(x, xb, 1048576, qkv_w, qkvwb, 1245184, gat_W, gatwb, 1638400,
                                    out_W, outwb, 2031616, proj_w, projwb, 2097152);
  hipMemsetAsync(eo1, 0, zspan, stream);
  k_wvec<<<dim3(8, 6), blk, 0, stream>>>(gatwb, gat_Wb, gat_ai, gat_ai_b, gat_aj, gat_aj_b, wv, con);
  k_wvec_o<<<dim3(12, 8), blk, 0, stream>>>(out_W, out_Wb, out_ai, out_aj, wvo, conO);
  k_e12v<<<2048, blk, 0, stream>>>(xb, wv, con, ev);
  k_qkv<<<dim3(12, 64), blk, 0, stream>>>(xb, qkvwb, qb, kb, vT);

  if (big) {
    bf16_t* WhT3 = (bf16_t*)alloc(3ull * 8 * 1024 * 1024 * 2);
    bf16_t* att3 = (bf16_t*)alloc(3ull * 8 * 1024 * 1024 * 2);
    bf16_t* mask  = att3;
    bf16_t* maskT = att3 + 8388608;
    bf16_t* aoutb = att3 + 2 * 8388608;

    k_wh<<<dim3(8, 64, 3), blk, 0, stream>>>(xb, gatwb, gat_Wb, WhT3);
    k_gat_att3<<<2048, blk, 0, stream>>>(adj, ev, att3);
    k_hhat<<<dim3(8, 8, 24), blk, 0, stream>>>(att3, WhT3, (bf16_t*)Who, 3072, wvo, eo1, eo2);
    k_mask<<<2048, blk, 0, stream>>>(adj, eo1, eo2, conO, out_ai_b, out_aj_b, mask);
    k_mtr<<<dim3(16, 16, 8), blk, 0, stream>>>(mask, maskT);
    k_flash<<<dim3(16, 8, 8), blk, 0, stream>>>(qb, kb, vT, maskT, aoutb);
    k_lin<<<dim3(4, 64), blk, 0, stream>>>(aoutb, 512, projwb, 512, proj_b, (float*)d_out);
  } else {
    bf16_t* WhT   = (bf16_t*)alloc(8ull * 1024 * 1024 * 2);
    bf16_t* att   = (bf16_t*)alloc(8ull * 1024 * 1024 * 2);
    bf16_t* hh    = (bf16_t*)alloc(8192ull * 1024 * 2);
    bf16_t* aoutb = (bf16_t*)alloc(8192ull * 512 * 2);
    bf16_t* maskT = (bf16_t*)alloc(8ull * 1024 * 1024 * 2);
    bf16_t* mask  = att;

    for (int l = 0; l < 3; ++l) {
      k_wh<<<dim3(8, 64, 1), blk, 0, stream>>>(xb, gatwb + (size_t)l * 524288, gat_Wb + l * 1024, WhT);
      k_gat_att<<<8192, blk, 0, stream>>>(adj, ev + (size_t)l * 16384, att);
      k_hhat<<<dim3(8, 8, 8), blk, 0, stream>>>(att, WhT, hh, 1024, nullptr, eo1, eo2);
      k_who_acc<<<dim3(4, 64), blk, 0, stream>>>(hh, outwb + l * 1024, out_Wb, Who, l);
    }
    k_eo<<<2048, blk, 0, stream>>>(Who, out_ai, out_aj, eo1, eo2);
    // conO already zeroed; add out_Wb contribution via wvec_o's conO (computed above)
    k_mask<<<2048, blk, 0, stream>>>(adj, eo1, eo2, conO, out_ai_b, out_aj_b, mask);
    k_mtr<<<dim3(16, 16, 8), blk, 0, stream>>>(mask, maskT);
    k_flash<<<dim3(16, 8, 8), blk, 0, stream>>>(qb, kb, vT, maskT, aoutb);
    k_lin<<<dim3(4, 64), blk, 0, stream>>>(aoutb, 512, projwb, 512, proj_b, (float*)d_out);
  }
}

// Round 11
// 278.793 us; speedup vs baseline: 7.2021x; 1.0041x over previous
//
#include <hip/hip_runtime.h>
#include <math.h>
#include <stdint.h>

#define SCALEQ 0.125f

typedef __bf16 bf16_t;
typedef __bf16 bf16x8 __attribute__((ext_vector_type(8)));
typedef float f32x4 __attribute__((ext_vector_type(4)));

// global -> LDS async copy, 16B per lane. LDS dest is wave-uniform base + lane*16.
#define GLOAD_LDS16(gsrc, ldst)                                                   \
  __builtin_amdgcn_global_load_lds(                                               \
      (const __attribute__((address_space(1))) void*)(uintptr_t)(const void*)(gsrc), \
      (__attribute__((address_space(3))) void*)(uintptr_t)(void*)(ldst), 16, 0, 0)

// XCD-chunked bijective block swizzle (grid total must be %8==0).
__device__ __forceinline__ int3 xswz3() {
  const int nx = gridDim.x, ny = gridDim.y;
  int lin = (blockIdx.z * ny + blockIdx.y) * nx + blockIdx.x;
  const int n = nx * ny * gridDim.z;
  int work = (lin & 7) * (n >> 3) + (lin >> 3);
  int3 r;
  r.x = work % nx; work /= nx;
  r.y = work % ny; r.z = work / ny;
  return r;
}

// ---------------- bf16 MFMA GEMM core (128x128 tile, 4 waves, BK=64) ----------------
// Rule-#21 XOR swizzle: linear LDS dest, per-lane global SOURCE chunk permuted,
// reads apply the same involution. 16-way -> 8-way ds_read_b128 conflicts.
__device__ __forceinline__ void mm_bf16(const bf16_t* __restrict__ A, int lda,
                                        const bf16_t* __restrict__ B, int ldb,
                                        int K, int m0, int n0,
                                        bf16_t* As, bf16_t* Bs, f32x4 (&acc)[4][4]) {
  const int tid = threadIdx.x, lane = tid & 63, w = tid >> 6;
  const int wr = (w >> 1) * 64, wc = (w & 1) * 64;
  const int fr = lane & 15, fq = lane >> 4;
  const int c8 = (((lane & 7) ^ ((lane >> 3) & 7)) * 8);   // swizzled source chunk
  for (int kt = 0; kt < K; kt += 64) {
    __syncthreads();
#pragma unroll
    for (int t = 0; t < 4; ++t) {
      const int rl = t * 32 + w * 8 + (lane >> 3);
      GLOAD_LDS16(A + (size_t)(m0 + rl) * lda + kt + c8, As + (t * 32 + w * 8) * 64);
      GLOAD_LDS16(B + (size_t)(n0 + rl) * ldb + kt + c8, Bs + (t * 32 + w * 8) * 64);
    }
    __syncthreads();
#pragma unroll
    for (int ks = 0; ks < 2; ++ks) {
      bf16x8 af[4], bfv[4];
      const int ch = (((ks * 4 + fq) ^ (fr & 7)) << 3);
#pragma unroll
      for (int mf = 0; mf < 4; ++mf)
        af[mf] = *(const bf16x8*)(As + (wr + mf * 16 + fr) * 64 + ch);
#pragma unroll
      for (int nf = 0; nf < 4; ++nf)
        bfv[nf] = *(const bf16x8*)(Bs + (wc + nf * 16 + fr) * 64 + ch);
#pragma unroll
      for (int mf = 0; mf < 4; ++mf)
#pragma unroll
        for (int nf = 0; nf < 4; ++nf)
          acc[mf][nf] = __builtin_amdgcn_mfma_f32_16x16x32_bf16(af[mf], bfv[nf], acc[mf][nf], 0, 0, 0);
    }
  }
}

#define MM_PROLOGUE()                                  \
  __shared__ __align__(16) bf16_t As[128 * 64];        \
  __shared__ __align__(16) bf16_t Bs[128 * 64];        \
  f32x4 acc[4][4];                                     \
  _Pragma("unroll") for (int i_ = 0; i_ < 4; ++i_)     \
  _Pragma("unroll") for (int j_ = 0; j_ < 4; ++j_) acc[i_][j_] = (f32x4)0.0f;

#define MM_EPI_SETUP(M0, N0)                                   \
  const int lane = threadIdx.x & 63, w = threadIdx.x >> 6;     \
  const int fr = lane & 15, fq = lane >> 4;                    \
  const int mb = (M0) + (w >> 1) * 64, nb = (N0) + (w & 1) * 64;

// ---------------- GEMM kernels ----------------
__global__ __launch_bounds__(256) void k_qkv(const bf16_t* __restrict__ xb, const bf16_t* __restrict__ wb,
                                             bf16_t* __restrict__ qb, bf16_t* __restrict__ kb,
                                             bf16_t* __restrict__ vT) {
  MM_PROLOGUE();
  const int3 bi = xswz3();
  const int m0 = bi.y * 128, n0 = bi.x * 128;
  mm_bf16(xb, 512, wb, 512, 512, m0, n0, As, Bs, acc);
  MM_EPI_SETUP(m0, n0);
#pragma unroll
  for (int mf = 0; mf < 4; ++mf)
#pragma unroll
    for (int nf = 0; nf < 4; ++nf) {
      const int n = nb + nf * 16 + fr;
      const int which = n >> 9, hd = (n >> 6) & 7, d = n & 63;
      const int m_ = mb + mf * 16 + fq * 4;
      const int b = m_ >> 10, tok0 = m_ & 1023;
      if (which == 2) {
        union { ushort4 u; bf16_t q[4]; } pk;
#pragma unroll
        for (int r = 0; r < 4; ++r) pk.q[r] = (bf16_t)acc[mf][nf][r];
        *(ushort4*)(vT + (((size_t)b * 8 + hd) * 64 + d) * 1024 + tok0) = pk.u;
      } else {
        bf16_t* dst = which ? kb : qb;
        const float sc = which ? 1.f : SCALEQ;
#pragma unroll
        for (int r = 0; r < 4; ++r)
          dst[(((size_t)b * 8 + hd) * 1024 + tok0 + r) * 64 + d] = (bf16_t)(acc[mf][nf][r] * sc);
      }
    }
}

__global__ __launch_bounds__(256) void k_wh(const bf16_t* __restrict__ xb, const bf16_t* __restrict__ gatw,
                                            const float* __restrict__ gWb, bf16_t* __restrict__ WhT) {
  MM_PROLOGUE();
  const int3 bi = xswz3();
  const int m0 = bi.y * 128, n0 = bi.x * 128, l = bi.z;
  const bf16_t* Wl = gatw + (size_t)l * 524288;
  const float* Wb = gWb + l * 1024;
  bf16_t* out = WhT + (size_t)l * 8388608;
  mm_bf16(xb, 512, Wl, 512, 512, m0, n0, As, Bs, acc);
  MM_EPI_SETUP(m0, n0);
#pragma unroll
  for (int mf = 0; mf < 4; ++mf)
#pragma unroll
    for (int nf = 0; nf < 4; ++nf) {
      const int h = nb + nf * 16 + fr;
      const float bias = Wb[h];
      const int m_ = mb + mf * 16 + fq * 4;
      const int b = m_ >> 10, ml = m_ & 1023;
      union { ushort4 u; bf16_t q[4]; } pk;
#pragma unroll
      for (int r = 0; r < 4; ++r) pk.q[r] = (bf16_t)(acc[mf][nf][r] + bias);
      *(ushort4*)(out + (((size_t)b << 10) + h) * 1024 + ml) = pk.u;
    }
}

// hh = elu(att_lb @ Wh_lb). Fused mode (wvo != nullptr): instead of writing hh,
// accumulate eo1/eo2 row-dots with wv7/wv8 (f32 pre-rounding elu values).
__global__ __launch_bounds__(256) void k_hhat(const bf16_t* __restrict__ att, const bf16_t* __restrict__ WhT,
                                              bf16_t* __restrict__ hh, int ldh,
                                              const float* __restrict__ wvo,
                                              float* __restrict__ eo1, float* __restrict__ eo2) {
  MM_PROLOGUE();
  const int3 bi = xswz3();
  const int m0 = bi.y * 128, n0 = bi.x * 128;
  const int l = bi.z >> 3, bz = bi.z & 7;
  const size_t off = ((size_t)(l * 8 + bz)) << 20;
  mm_bf16(att + off, 1024, WhT + off, 1024, 1024, m0, n0, As, Bs, acc);
  MM_EPI_SETUP(m0, n0);
  if (wvo != nullptr) {
    float w1[4], w2[4];
#pragma unroll
    for (int nf = 0; nf < 4; ++nf) {
      const int n = nb + nf * 16 + fr;
      w1[nf] = wvo[l * 1024 + n];
      w2[nf] = wvo[3072 + l * 1024 + n];
    }
#pragma unroll
    for (int mf = 0; mf < 4; ++mf)
#pragma unroll
      for (int r = 0; r < 4; ++r) {
        float s1 = 0.f, s2 = 0.f;
#pragma unroll
        for (int nf = 0; nf < 4; ++nf) {
          float v = acc[mf][nf][r];
          v = v > 0.f ? v : (__expf(v) - 1.f);
          s1 = fmaf(v, w1[nf], s1);
          s2 = fmaf(v, w2[nf], s2);
        }
        s1 += __shfl_xor(s1, 1); s1 += __shfl_xor(s1, 2); s1 += __shfl_xor(s1, 4); s1 += __shfl_xor(s1, 8);
        s2 += __shfl_xor(s2, 1); s2 += __shfl_xor(s2, 2); s2 += __shfl_xor(s2, 4); s2 += __shfl_xor(s2, 8);
        if (fr == 0) {
          const int m = (bz << 10) + mb + mf * 16 + fq * 4 + r;
          atomicAdd(&eo1[m], s1);
          atomicAdd(&eo2[m], s2);
        }
      }
  } else {
#pragma unroll
    for (int mf = 0; mf < 4; ++mf)
#pragma unroll
      for (int nf = 0; nf < 4; ++nf) {
        const int n = nb + nf * 16 + fr;
#pragma unroll
        for (int r = 0; r < 4; ++r) {
          const int m = mb + mf * 16 + fq * 4 + r;
          float v = acc[mf][nf][r];
          v = v > 0.f ? v : (__expf(v) - 1.f);
          hh[(size_t)((bz << 10) + m) * ldh + l * 1024 + n] = (bf16_t)v;
        }
      }
  }
}

__global__ __launch_bounds__(256) void k_lin(const bf16_t* __restrict__ A, int lda,
                                             const bf16_t* __restrict__ B, int K,
                                             const float* __restrict__ bias, float* __restrict__ out) {
  MM_PROLOGUE();
  const int3 bi = xswz3();
  const int m0 = bi.y * 128, n0 = bi.x * 128;
  mm_bf16(A, lda, B, K, K, m0, n0, As, Bs, acc);
  MM_EPI_SETUP(m0, n0);
#pragma unroll
  for (int mf = 0; mf < 4; ++mf)
#pragma unroll
    for (int nf = 0; nf < 4; ++nf) {
      const int n = nb + nf * 16 + fr;
#pragma unroll
      for (int r = 0; r < 4; ++r) {
        const int m = mb + mf * 16 + fq * 4 + r;
        out[(size_t)m * 512 + n] = acc[mf][nf][r] + bias[n];
      }
    }
}

// fallback: Who (+)= hh @ out_W[:, l*1024:+1024].T (bias folded at l==0)
__global__ __launch_bounds__(256) void k_who_acc(const bf16_t* __restrict__ hh, const bf16_t* __restrict__ Wl,
                                                 const float* __restrict__ Wb, float* __restrict__ Who, int l) {
  MM_PROLOGUE();
  const int m0 = blockIdx.y * 128, n0 = blockIdx.x * 128;
  mm_bf16(hh, 1024, Wl, 3072, 1024, m0, n0, As, Bs, acc);
  MM_EPI_SETUP(m0, n0);
#pragma unroll
  for (int mf = 0; mf < 4; ++mf)
#pragma unroll
    for (int nf = 0; nf < 4; ++nf) {
      const int n = nb + nf * 16 + fr;
#pragma unroll
      for (int r = 0; r < 4; ++r) {
        const int m = mb + mf * 16 + fq * 4 + r;
        const size_t idx = (size_t)m * 512 + n;
        Who[idx] = acc[mf][nf][r] + (l == 0 ? Wb[n] : Who[idx]);
      }
    }
}

// ---------------- fused casts f32 -> bf16 (5 segments) ----------------
__global__ __launch_bounds__(256) void k_cast5(const float* __restrict__ s0, bf16_t* __restrict__ d0, int c0,
                                               const float* __restrict__ s1, bf16_t* __restrict__ d1, int c1,
                                               const float* __restrict__ s2, bf16_t* __restrict__ d2, int c2,
                                               const float* __restrict__ s3, bf16_t* __restrict__ d3, int c3,
                                               const float* __restrict__ s4, bf16_t* __restrict__ d4, int c4) {
  int i = blockIdx.x * 256 + threadIdx.x;
  const float* src; bf16_t* dst; int j;
  if (i < c0)      { src = s0; dst = d0; j = i; }
  else if (i < c1) { src = s1; dst = d1; j = i - c0; }
  else if (i < c2) { src = s2; dst = d2; j = i - c1; }
  else if (i < c3) { src = s3; dst = d3; j = i - c2; }
  else if (i < c4) { src = s4; dst = d4; j = i - c3; }
  else return;
  float4 v = ((const float4*)src)[j];
  union { ushort4 u; bf16_t b[4]; } p;
  p.b[0] = (bf16_t)v.x; p.b[1] = (bf16_t)v.y; p.b[2] = (bf16_t)v.z; p.b[3] = (bf16_t)v.w;
  ((ushort4*)dst)[j] = p.u;
}

// ---------------- algebraic e1/e2 (gat layers) ----------------
__global__ __launch_bounds__(256) void k_wvec(const bf16_t* __restrict__ gatwb,
                                              const float* __restrict__ gWb,
                                              const float* __restrict__ ai, const float* __restrict__ aib,
                                              const float* __restrict__ aj, const float* __restrict__ ajb,
                                              float* __restrict__ wv, float* __restrict__ con) {
  __shared__ float sred[4][64];
  __shared__ float cred[256];
  const int v = blockIdx.y, l = v >> 1;
  const float* avec = ((v & 1) ? aj : ai) + (l << 10);
  const bf16_t* W = gatwb + ((size_t)(l << 10)) * 512;
  const int tid = threadIdx.x, hg = tid >> 6, cc = tid & 63;
  const int c = blockIdx.x * 64 + cc;
  float p = 0.f;
  for (int i = 0; i < 256; ++i) {
    const int h = hg * 256 + i;
    p = fmaf((float)W[(size_t)h * 512 + c], avec[h], p);
  }
  sred[hg][cc] = p;
  float cp = 0.f;
#pragma unroll
  for (int i = 0; i < 4; ++i) cp = fmaf(gWb[(l << 10) + tid + i * 256], avec[tid + i * 256], cp);
  cred[tid] = cp;
  __syncthreads();
  if (tid < 64) wv[v * 512 + blockIdx.x * 64 + tid] = sred[0][tid] + sred[1][tid] + sred[2][tid] + sred[3][tid];
  for (int s = 128; s > 0; s >>= 1) {
    if (tid < s) cred[tid] += cred[tid + s];
    __syncthreads();
  }
  if (tid == 0 && blockIdx.x == 0) con[v] = cred[0] + ((v & 1) ? ajb[l] : aib[l]);
}

// out-attention vectors: wvo[v][c] = sum_d out_W[d][c]*avec[d] (v=0:ai, 1:aj),
// conO[v] = dot(out_Wb, avec). wvo/conO must be zeroed beforehand.
__global__ __launch_bounds__(256) void k_wvec_o(const float* __restrict__ W, const float* __restrict__ Wb,
                                                const float* __restrict__ ai, const float* __restrict__ aj,
                                                float* __restrict__ wvo, float* __restrict__ conO) {
  const int c = blockIdx.x * 256 + threadIdx.x;     // 0..3071
  const int d0 = blockIdx.y * 64;                   // 8 chunks of 64
  float s1 = 0.f, s2 = 0.f;
  for (int t = 0; t < 64; ++t) {
    const float w = W[(size_t)(d0 + t) * 3072 + c];
    s1 = fmaf(w, ai[d0 + t], s1);
    s2 = fmaf(w, aj[d0 + t], s2);
  }
  atomicAdd(&wvo[c], s1);
  atomicAdd(&wvo[3072 + c], s2);
  if (blockIdx.x == 0 && threadIdx.x < 64) {
    const int d = d0 + threadIdx.x;
    float c1 = Wb[d] * ai[d], c2 = Wb[d] * aj[d];
#pragma unroll
    for (int off = 32; off > 0; off >>= 1) { c1 += __shfl_xor(c1, off); c2 += __shfl_xor(c2, off); }
    if (threadIdx.x == 0) { atomicAdd(&conO[0], c1); atomicAdd(&conO[1], c2); }
  }
}

__global__ __launch_bounds__(256) void k_e12v(const bf16_t* __restrict__ xb,
                                              const float* __restrict__ wv, const float* __restrict__ con,
                                              float* __restrict__ ev) {
  const int tid = threadIdx.x, lane = tid & 63, wid = tid >> 6;
  const int row = blockIdx.x * 4 + wid;
  bf16x8 xv = *(const bf16x8*)(xb + (size_t)row * 512 + lane * 8);
  float xf[8];
#pragma unroll
  for (int j = 0; j < 8; ++j) xf[j] = (float)xv[j];
  float s[6];
#pragma unroll
  for (int v = 0; v < 6; ++v) {
    const float* wp = wv + v * 512 + lane * 8;
    float a = 0.f;
#pragma unroll
    for (int j = 0; j < 8; ++j) a = fmaf(xf[j], wp[j], a);
    s[v] = a;
  }
#pragma unroll
  for (int v = 0; v < 6; ++v)
#pragma unroll
    for (int off = 32; off > 0; off >>= 1) s[v] += __shfl_xor(s[v], off);
  if (lane == 0) {
#pragma unroll
    for (int v = 0; v < 6; ++v) ev[v * 8192 + row] = s[v] + con[v];
  }
}

// fallback: raw row-dots (biases/constants added in k_mask via conO)
__global__ __launch_bounds__(256) void k_eo(const float* __restrict__ Who,
                                            const float* __restrict__ ai, const float* __restrict__ aj,
                                            float* __restrict__ eo1, float* __restrict__ eo2) {
  const int wid = threadIdx.x >> 6, lane = threadIdx.x & 63;
  const int row = blockIdx.x * 4 + wid;
  const float* wr = Who + (size_t)row * 512;
  float s1 = 0.f, s2 = 0.f;
#pragma unroll
  for (int c = 0; c < 2; ++c) {
    const int idx = c * 256 + lane * 4;
    float4 w4 = *(const float4*)&wr[idx];
    float4 a4 = *(const float4*)&ai[idx];
    float4 b4 = *(const float4*)&aj[idx];
    s1 += w4.x * a4.x + w4.y * a4.y + w4.z * a4.z + w4.w * a4.w;
    s2 += w4.x * b4.x + w4.y * b4.y + w4.z * b4.z + w4.w * b4.w;
  }
#pragma unroll
  for (int off = 32; off > 0; off >>= 1) { s1 += __shfl_xor(s1, off); s2 += __shfl_xor(s2, off); }
  if (lane == 0) { eo1[row] = s1; eo2[row] = s2; }
}

// ---------------- block reduce helpers (fallback kernels) ----------------
__device__ __forceinline__ float block_max(float v, float* red) {
#pragma unroll
  for (int off = 32; off > 0; off >>= 1) v = fmaxf(v, __shfl_xor(v, off));
  __syncthreads();
  if ((threadIdx.x & 63) == 0) red[threadIdx.x >> 6] = v;
  __syncthreads();
  return fmaxf(fmaxf(red[0], red[1]), fmaxf(red[2], red[3]));
}
__device__ __forceinline__ float block_sum(float v, float* red) {
#pragma unroll
  for (int off = 32; off > 0; off >>= 1) v += __shfl_xor(v, off);
  __syncthreads();
  if ((threadIdx.x & 63) == 0) red[threadIdx.x >> 6] = v;
  __syncthreads();
  return red[0] + red[1] + red[2] + red[3];
}

// ---------------- GAT attention rows: wave-per-row, all 3 layers, no barriers ----------------
__global__ __launch_bounds__(256) void k_gat_att3(const float* __restrict__ adj, const float* __restrict__ ev,
                                                  bf16_t* __restrict__ att) {
  const int lane = threadIdx.x & 63;
  const int row = blockIdx.x * 4 + (threadIdx.x >> 6);
  const int b = row >> 10;
  const float* arow = adj + (size_t)row * 1024;
  float a[4][4];
#pragma unroll
  for (int c = 0; c < 4; ++c) *(float4*)a[c] = *(const float4*)&arow[(c * 64 + lane) * 4];
#pragma unroll
  for (int l = 0; l < 3; ++l) {
    const float e1v = ev[l * 16384 + row];
    const float* e2r = ev + l * 16384 + 8192 + (b << 10);
    bf16_t* aout = att + (size_t)l * 8388608 + (size_t)row * 1024;
    float s[4][4];
    float mx = -1e30f;
#pragma unroll
    for (int c = 0; c < 4; ++c) {
      float4 e4 = *(const float4*)&e2r[(c * 64 + lane) * 4];
      float ee[4] = {e4.x, e4.y, e4.z, e4.w};
#pragma unroll
      for (int j = 0; j < 4; ++j) {
        float e = e1v + ee[j];
        e = e > 0.f ? e : 0.2f * e;
        s[c][j] = a[c][j] * e;
        mx = fmaxf(mx, s[c][j]);
      }
    }
#pragma unroll
    for (int off = 32; off > 0; off >>= 1) mx = fmaxf(mx, __shfl_xor(mx, off));
    float sum = 0.f;
#pragma unroll
    for (int c = 0; c < 4; ++c)
#pragma unroll
      for (int j = 0; j < 4; ++j) { float p = __expf(s[c][j] - mx); s[c][j] = p; sum += p; }
#pragma unroll
    for (int off = 32; off > 0; off >>= 1) sum += __shfl_xor(sum, off);
    const float inv = 1.f / sum;
#pragma unroll
    for (int c = 0; c < 4; ++c) {
      union { ushort4 u; bf16_t q[4]; } pk;
#pragma unroll
      for (int j = 0; j < 4; ++j) pk.q[j] = (bf16_t)(s[c][j] * inv);
      *(ushort4*)(aout + (c * 64 + lane) * 4) = pk.u;
    }
  }
}

// fallback single-layer version (block-per-row)
__global__ __launch_bounds__(256) void k_gat_att(const float* __restrict__ adj, const float* __restrict__ ev,
                                                 bf16_t* __restrict__ att) {
  __shared__ float red[4];
  const int row = blockIdx.x;
  const int b = row >> 10;
  const float* arow = adj + (size_t)row * 1024;
  const float e1v = ev[row];
  const float* e2r = ev + 8192 + (b << 10);
  float s[4];
  float mx = -1e30f;
#pragma unroll
  for (int c = 0; c < 4; ++c) {
    const int m = c * 256 + threadIdx.x;
    float e = e1v + e2r[m];
    e = e > 0.f ? e : 0.2f * e;
    s[c] = arow[m] * e;
    mx = fmaxf(mx, s[c]);
  }
  mx = block_max(mx, red);
  float sum = 0.f;
#pragma unroll
  for (int c = 0; c < 4; ++c) { float p = __expf(s[c] - mx); s[c] = p; sum += p; }
  sum = block_sum(sum, red);
  const float inv = 1.f / sum;
#pragma unroll
  for (int c = 0; c < 4; ++c) att[(size_t)row * 1024 + c * 256 + threadIdx.x] = (bf16_t)(s[c] * inv);
}

// ---------------- output-attention mask: wave-per-row double softmax ----------------
// eo1/eo2 are raw row sums; constants conO + biases added here.
__global__ __launch_bounds__(256) void k_mask(const float* __restrict__ adj, const float* __restrict__ eo1,
                                              const float* __restrict__ eo2, const float* __restrict__ conO,
                                              const float* __restrict__ aib, const float* __restrict__ ajb,
                                              bf16_t* __restrict__ mask) {
  const int lane = threadIdx.x & 63;
  const int row = blockIdx.x * 4 + (threadIdx.x >> 6);
  const int b = row >> 10;
  const float* arow = adj + (size_t)row * 1024;
  const float t1 = eo1[row] + conO[0] + aib[0];
  const float c2 = conO[1] + ajb[0];
  const float* eor = eo2 + (b << 10);
  float s[4][4];
  float mx = -1e30f;
#pragma unroll
  for (int c = 0; c < 4; ++c) {
    float4 a4 = *(const float4*)&arow[(c * 64 + lane) * 4];
    float4 e4 = *(const float4*)&eor[(c * 64 + lane) * 4];
    float aa[4] = {a4.x, a4.y, a4.z, a4.w};
    float ee[4] = {e4.x, e4.y, e4.z, e4.w};
#pragma unroll
    for (int j = 0; j < 4; ++j) {
      float e = t1 + ee[j] + c2;
      e = e > 0.f ? e : 0.2f * e;
      s[c][j] = aa[j] * e;
      mx = fmaxf(mx, s[c][j]);
    }
  }
#pragma unroll
  for (int off = 32; off > 0; off >>= 1) mx = fmaxf(mx, __shfl_xor(mx, off));
  float sum = 0.f;
#pragma unroll
  for (int c = 0; c < 4; ++c)
#pragma unroll
    for (int j = 0; j < 4; ++j) { float p = __expf(s[c][j] - mx); s[c][j] = p; sum += p; }
#pragma unroll
  for (int off = 32; off > 0; off >>= 1) sum += __shfl_xor(sum, off);
  const float inv = 1.f / sum;        // == max of first softmax
  float sum2 = 0.f;
#pragma unroll
  for (int c = 0; c < 4; ++c)
#pragma unroll
    for (int j = 0; j < 4; ++j) { float p = __expf(s[c][j] * inv - inv); s[c][j] = p; sum2 += p; }
#pragma unroll
  for (int off = 32; off > 0; off >>= 1) sum2 += __shfl_xor(sum2, off);
  const float inv2 = 1.f / sum2;
#pragma unroll
  for (int c = 0; c < 4; ++c) {
    union { ushort4 u; bf16_t q[4]; } pk;
#pragma unroll
    for (int j = 0; j < 4; ++j) pk.q[j] = (bf16_t)(s[c][j] * inv2);
    *(ushort4*)(mask + (size_t)row * 1024 + (c * 64 + lane) * 4) = pk.u;
  }
}

// ---------------- mask transpose ----------------
__global__ __launch_bounds__(256) void k_mtr(const bf16_t* __restrict__ in, bf16_t* __restrict__ out) {
  __shared__ bf16_t T[64][72];
  const int q0 = blockIdx.x * 64, k0 = blockIdx.y * 64, b = blockIdx.z;
  const bf16_t* src = in + ((size_t)b << 20);
  bf16_t* dst = out + ((size_t)b << 20);
  const int r = threadIdx.x >> 2, c = (threadIdx.x & 3) * 16;
  bf16x8 a0 = *(const bf16x8*)(src + (size_t)(q0 + r) * 1024 + k0 + c);
  bf16x8 a1 = *(const bf16x8*)(src + (size_t)(q0 + r) * 1024 + k0 + c + 8);
  *(bf16x8*)&T[r][c] = a0;
  *(bf16x8*)&T[r][c + 8] = a1;
  __syncthreads();
  union { bf16x8 v[2]; bf16_t e[16]; } o;
#pragma unroll
  for (int j = 0; j < 16; ++j) o.e[j] = T[c + j][r];
  *(bf16x8*)(dst + (size_t)(k0 + r) * 1024 + q0 + c) = o.v[0];
  *(bf16x8*)(dst + (size_t)(k0 + r) * 1024 + q0 + c + 8) = o.v[1];
}

// ---------------- MFMA flash attention (XOR-swizzled K/V + P LDS) ----------------
__device__ __forceinline__ int swz(int row, int slot) { return row * 64 + ((slot ^ (row & 7)) << 3); }

__global__ __launch_bounds__(256) void k_flash(const bf16_t* __restrict__ qg, const bf16_t* __restrict__ kg,
                                               const bf16_t* __restrict__ vTg, const bf16_t* __restrict__ maskT,
                                               bf16_t* __restrict__ aout) {
  __shared__ __align__(16) bf16_t Ks[4096];
  __shared__ __align__(16) bf16_t Vs[4096];
  __shared__ __align__(16) bf16_t PL[4][1024];   // per-wave 16x64, swizzled
  const int tid = threadIdx.x, lane = tid & 63, w = tid >> 6;
  const int fr = lane & 15, fq = lane >> 4;
  const int3 bi = xswz3();
  const int n0 = bi.x * 64, hh = bi.y, bb = bi.z;
  const size_t bh = ((size_t)bb * 8 + hh) << 16;
  const bf16_t* q = qg + bh;
  const bf16_t* kk = kg + bh;
  const bf16_t* vT = vTg + bh;
  const bf16_t* mT = maskT + ((size_t)bb << 20);
  bf16_t* PLw = &PL[w][0];

  bf16x8 qf[2];
#pragma unroll
  for (int ks = 0; ks < 2; ++ks)
    qf[ks] = *(const bf16x8*)(q + (size_t)(n0 + w * 16 + fr) * 64 + ks * 32 + fq * 8);

  f32x4 o[4];
#pragma unroll
  for (int nf = 0; nf < 4; ++nf) o[nf] = (f32x4)0.0f;
  float psum[4] = {0.f, 0.f, 0.f, 0.f};

  const int srow = tid >> 2, sslot = (tid & 3) * 2;
  const int ws0 = swz(srow, sslot), ws1 = swz(srow, sslot + 1);
  const int scol = (tid & 3) * 16;

  for (int c = 0; c < 16; ++c) {
    const int k0 = c * 64;
    bf16x8 kv0 = *(const bf16x8*)(kk + (size_t)(k0 + srow) * 64 + scol);
    bf16x8 kv1 = *(const bf16x8*)(kk + (size_t)(k0 + srow) * 64 + scol + 8);
    bf16x8 vv0 = *(const bf16x8*)(vT + (size_t)srow * 1024 + k0 + scol);
    bf16x8 vv1 = *(const bf16x8*)(vT + (size_t)srow * 1024 + k0 + scol + 8);
    union { ushort4 u; bf16_t h[4]; } mfr[4];
#pragma unroll
    for (int nf = 0; nf < 4; ++nf)
      mfr[nf].u = *(const ushort4*)(mT + (size_t)(k0 + nf * 16 + fr) * 1024 + n0 + w * 16 + fq * 4);
    __syncthreads();
    *(bf16x8*)&Ks[ws0] = kv0; *(bf16x8*)&Ks[ws1] = kv1;
    *(bf16x8*)&Vs[ws0] = vv0; *(bf16x8*)&Vs[ws1] = vv1;
    __syncthreads();

    f32x4 s[4];
#pragma unroll
    for (int nf = 0; nf < 4; ++nf) s[nf] = (f32x4)0.0f;
#pragma unroll
    for (int ks = 0; ks < 2; ++ks) {
      bf16x8 kf[4];
#pragma unroll
      for (int nf = 0; nf < 4; ++nf)
        kf[nf] = *(const bf16x8*)&Ks[swz(nf * 16 + fr, ks * 4 + fq)];
#pragma unroll
      for (int nf = 0; nf < 4; ++nf)
        s[nf] = __builtin_amdgcn_mfma_f32_16x16x32_bf16(qf[ks], kf[nf], s[nf], 0, 0, 0);
    }

#pragma unroll
    for (int nf = 0; nf < 4; ++nf)
#pragma unroll
      for (int r = 0; r < 4; ++r) {
        const float p = __expf(s[nf][r] * (float)mfr[nf].h[r]);
        psum[r] += p;
        const int pp = fq * 4 + r, e = nf * 16 + fr;
        PLw[pp * 64 + ((((e >> 3) ^ (pp & 7))) << 3) + (e & 7)] = (bf16_t)p;
      }

#pragma unroll
    for (int ks = 0; ks < 2; ++ks) {
      bf16x8 pf = *(const bf16x8*)&PLw[swz(fr, ks * 4 + fq)];
      bf16x8 vf[4];
#pragma unroll
      for (int nfo = 0; nfo < 4; ++nfo)
        vf[nfo] = *(const bf16x8*)&Vs[swz(nfo * 16 + fr, ks * 4 + fq)];
#pragma unroll
      for (int nfo = 0; nfo < 4; ++nfo)
        o[nfo] = __builtin_amdgcn_mfma_f32_16x16x32_bf16(pf, vf[nfo], o[nfo], 0, 0, 0);
    }
  }

#pragma unroll
  for (int r = 0; r < 4; ++r) {
    psum[r] += __shfl_xor(psum[r], 1);
    psum[r] += __shfl_xor(psum[r], 2);
    psum[r] += __shfl_xor(psum[r], 4);
    psum[r] += __shfl_xor(psum[r], 8);
  }
#pragma unroll
  for (int r = 0; r < 4; ++r) {
    const int tok = n0 + w * 16 + fq * 4 + r;
    const float inv = 1.f / psum[r];
#pragma unroll
    for (int nfo = 0; nfo < 4; ++nfo)
      aout[((size_t)(bb << 10) + tok) * 512 + hh * 64 + nfo * 16 + fr] = (bf16_t)(o[nfo][r] * inv);
  }
}

// ---------------- launcher ----------------
extern "C" void kernel_launch(void* const* d_in, const int* in_sizes, int n_in,
                              void* d_out, int out_size, void* d_ws, size_t ws_size,
                              hipStream_t stream) {
  (void)in_sizes; (void)n_in; (void)out_size;
  const float* x        = (const float*)d_in[0];
  const float* adj      = (const float*)d_in[1];
  const float* qkv_w    = (const float*)d_in[2];
  const float* proj_w   = (const float*)d_in[3];
  const float* proj_b   = (const float*)d_in[4];
  const float* gat_W    = (const float*)d_in[5];
  const float* gat_Wb   = (const float*)d_in[6];
  const float* gat_ai   = (const float*)d_in[7];
  const float* gat_ai_b = (const float*)d_in[8];
  const float* gat_aj   = (const float*)d_in[9];
  const float* gat_aj_b = (const float*)d_in[10];
  const float* out_W    = (const float*)d_in[11];
  const float* out_Wb   = (const float*)d_in[12];
  const float* out_ai   = (const float*)d_in[13];
  const float* out_ai_b = (const float*)d_in[14];
  const float* out_aj   = (const float*)d_in[15];
  const float* out_aj_b = (const float*)d_in[16];

  char* p = (char*)d_ws;
  auto alloc = [&](size_t bytes) { char* r = p; p += (bytes + 255) & ~(size_t)255; return r; };
  bf16_t* xb     = (bf16_t*)alloc(8192ull * 512 * 2);
  bf16_t* qkvwb  = (bf16_t*)alloc(1536ull * 512 * 2);
  bf16_t* gatwb  = (bf16_t*)alloc(3072ull * 512 * 2);
  bf16_t* outwb  = (bf16_t*)alloc(512ull * 3072 * 2);
  bf16_t* projwb = (bf16_t*)alloc(512ull * 512 * 2);
  bf16_t* qb     = (bf16_t*)alloc(8ull * 8 * 1024 * 64 * 2);
  bf16_t* kb     = (bf16_t*)alloc(8ull * 8 * 1024 * 64 * 2);
  bf16_t* vT     = (bf16_t*)alloc(8ull * 8 * 64 * 1024 * 2);
  float*  Who    = (float*)alloc(8192ull * 512 * 4);   // fallback only (dummy hh in big path)
  float*  wv     = (float*)alloc(6 * 512 * 4);
  float*  con    = (float*)alloc(256);
  float*  ev     = (float*)alloc(6 * 8192 * 4);
  // contiguous zero-init region: eo1, eo2, wvo, conO
  float*  eo1    = (float*)alloc(8192 * 4);
  float*  eo2    = (float*)alloc(8192 * 4);
  float*  wvo    = (float*)alloc(2 * 3072 * 4);
  float*  conO   = (float*)alloc(256);
  const size_t zspan = (size_t)((char*)conO - (char*)eo1) + 256;

  const bool big = ws_size >= 211000000ull;

  const dim3 blk(256);
  k_cast5<<<8192, blk, 0, stream>>>(x, xb, 1048576, qkv_w, qkvwb, 1245184, gat_W, gatwb, 1638400,
                                    out_W, outwb, 2031616, proj_w, projwb, 2097152);
  hipMemsetAsync(eo1, 0, zspan, stream);
  k_wvec<<<dim3(8, 6), blk, 0, stream>>>(gatwb, gat_Wb, gat_ai, gat_ai_b, gat_aj, gat_aj_b, wv, con);
  k_wvec_o<<<dim3(12, 8), blk, 0, stream>>>(out_W, out_Wb, out_ai, out_aj, wvo, conO);
  k_e12v<<<2048, blk, 0, stream>>>(xb, wv, con, ev);
  k_qkv<<<dim3(12, 64), blk, 0, stream>>>(xb, qkvwb, qb, kb, vT);

  if (big) {
    bf16_t* WhT3 = (bf16_t*)alloc(3ull * 8 * 1024 * 1024 * 2);
    bf16_t* att3 = (bf16_t*)alloc(3ull * 8 * 1024 * 1024 * 2);
    bf16_t* mask  = att3;
    bf16_t* maskT = att3 + 8388608;
    bf16_t* aoutb = att3 + 2 * 8388608;

    k_wh<<<dim3(8, 64, 3), blk, 0, stream>>>(xb, gatwb, gat_Wb, WhT3);
    k_gat_att3<<<2048, blk, 0, stream>>>(adj, ev, att3);
    k_hhat<<<dim3(8, 8, 24), blk, 0, stream>>>(att3, WhT3, (bf16_t*)Who, 3072, wvo, eo1, eo2);
    k_mask<<<2048, blk, 0, stream>>>(adj, eo1, eo2, conO, out_ai_b, out_aj_b, mask);
    k_mtr<<<dim3(16, 16, 8), blk, 0, stream>>>(mask, maskT);
    k_flash<<<dim3(16, 8, 8), blk, 0, stream>>>(qb, kb, vT, maskT, aoutb);
    k_lin<<<dim3(4, 64), blk, 0, stream>>>(aoutb, 512, projwb, 512, proj_b, (float*)d_out);
  } else {
    bf16_t* WhT   = (bf16_t*)alloc(8ull * 1024 * 1024 * 2);
    bf16_t* att   = (bf16_t*)alloc(8ull * 1024 * 1024 * 2);
    bf16_t* hh    = (bf16_t*)alloc(8192ull * 1024 * 2);
    bf16_t* aoutb = (bf16_t*)alloc(8192ull * 512 * 2);
    bf16_t* maskT = (bf16_t*)alloc(8ull * 1024 * 1024 * 2);
    bf16_t* mask  = att;

    for (int l = 0; l < 3; ++l) {
      k_wh<<<dim3(8, 64, 1), blk, 0, stream>>>(xb, gatwb + (size_t)l * 524288, gat_Wb + l * 1024, WhT);
      k_gat_att<<<8192, blk, 0, stream>>>(adj, ev + (size_t)l * 16384, att);
      k_hhat<<<dim3(8, 8, 8), blk, 0, stream>>>(att, WhT, hh, 1024, nullptr, eo1, eo2);
      k_who_acc<<<dim3(4, 64), blk, 0, stream>>>(hh, outwb + l * 1024, out_Wb, Who, l);
    }
    k_eo<<<2048, blk, 0, stream>>>(Who, out_ai, out_aj, eo1, eo2);
    // conO already zeroed; add out_Wb contribution via wvec_o's conO (computed above)
    k_mask<<<2048, blk, 0, stream>>>(adj, eo1, eo2, conO, out_ai_b, out_aj_b, mask);
    k_mtr<<<dim3(16, 16, 8), blk, 0, stream>>>(mask, maskT);
    k_flash<<<dim3(16, 8, 8), blk, 0, stream>>>(qb, kb, vT, maskT, aoutb);
    k_lin<<<dim3(4, 64), blk, 0, stream>>>(aoutb, 512, projwb, 512, proj_b, (float*)d_out);
  }
}